// Round 5
// baseline (617.277 us; speedup 1.0000x reference)
//
#include <hip/hip_runtime.h>

#define D 768
#define B 32
#define L 512
#define M 128
#define NNODES 3072
#define NEDGES 24576

using bf16x8 = __attribute__((ext_vector_type(8))) short;
using f32x4  = __attribute__((ext_vector_type(4))) float;

__device__ __forceinline__ float bf2f(unsigned short u) {
  union { unsigned int i; float f; } v; v.i = ((unsigned int)u) << 16; return v.f;
}
__device__ __forceinline__ unsigned short f2bf(float f) {
  union { float f; unsigned int i; } v; v.f = f;
  unsigned int x = v.i;
  return (unsigned short)((x + 0x7FFFu + ((x >> 16) & 1u)) >> 16);
}
__device__ __forceinline__ float ldf(const void* p, size_t i, int f32) {
  return f32 ? ((const float*)p)[i] : bf2f(((const unsigned short*)p)[i]);
}
__device__ __forceinline__ int ldi(const void* p, size_t i, int w64) {
  return w64 ? (int)((const long long*)p)[i] : ((const int*)p)[i];
}
__device__ __forceinline__ f32x4 mfma16(bf16x8 a, bf16x8 b, f32x4 c) {
  return __builtin_amdgcn_mfma_f32_16x16x32_bf16(a, b, c, 0, 0, 0);
}

// ---------- dtype detection: flags[0]=floats-are-fp32, flags[1]=ints-are-64bit ----------
__global__ void k_detect(const unsigned short* __restrict__ t,
                         const unsigned int* __restrict__ e, int* __restrict__ flags) {
  __shared__ int r0[256];
  __shared__ unsigned r1[256];
  int tid = threadIdx.x;
  int bad = 0;
  for (int i = tid; i < 8192; i += 256) {
    unsigned short u = t[2 * i];
    unsigned ex = (u >> 7) & 0xFF;
    if (ex >= 0xC0) bad = 1;
  }
  unsigned o = 0;
  for (int i = tid; i < NEDGES / 2; i += 256) o |= e[2 * i + 1];
  r0[tid] = bad; r1[tid] = o;
  __syncthreads();
  for (int s = 128; s > 0; s >>= 1) {
    if (tid < s) { r0[tid] |= r0[tid + s]; r1[tid] |= r1[tid + s]; }
    __syncthreads();
  }
  if (tid == 0) { flags[0] = r0[0]; flags[1] = (r1[0] == 0) ? 1 : 0; }
}

__global__ void k_cvt(const void* __restrict__ src, unsigned short* __restrict__ dst,
                      int n, const int* __restrict__ flags, int skip_if_bf16) {
  int f = flags[0];
  if (!f && skip_if_bf16) return;
  int i = blockIdx.x * 256 + threadIdx.x;
  if (i >= n) return;
  dst[i] = f ? f2bf(((const float*)src)[i]) : ((const unsigned short*)src)[i];
}

// ---------------- setup kernels ----------------

__global__ void k_init(int* cnt, int* cursor, int* gcnt, float* pooled) {
  int i = blockIdx.x * 256 + threadIdx.x;
  if (i < NNODES) { cnt[i] = 0; cursor[i] = 0; }
  if (i < B) gcnt[i] = 0;
  if (i < B * D) pooled[i] = 0.f;
}

__global__ void k_count(const void* __restrict__ edst, const void* __restrict__ batch,
                        const int* __restrict__ flags, int* __restrict__ cnt,
                        int* __restrict__ gcnt) {
  int w = flags[1];
  int i = blockIdx.x * 256 + threadIdx.x;
  if (i < NEDGES) atomicAdd(&cnt[ldi(edst, i, w)], 1);
  if (i < NNODES) atomicAdd(&gcnt[ldi(batch, i, w)], 1);
}

__global__ void k_scan(const int* __restrict__ cnt, int* __restrict__ rowstart) {
  __shared__ int a[NNODES], b[NNODES];
  int tid = threadIdx.x;
  for (int i = tid; i < NNODES; i += 1024) a[i] = cnt[i];
  __syncthreads();
  int* s = a; int* d = b;
  for (int off = 1; off < NNODES; off <<= 1) {
    for (int i = tid; i < NNODES; i += 1024)
      d[i] = s[i] + (i >= off ? s[i - off] : 0);
    __syncthreads();
    int* t = s; s = d; d = t;
  }
  for (int i = tid; i < NNODES; i += 1024) rowstart[i + 1] = s[i];
  if (tid == 0) rowstart[0] = 0;
}

__global__ void k_scatter(const void* __restrict__ esrc, const void* __restrict__ edst,
                          const int* __restrict__ flags, const int* __restrict__ rowstart,
                          int* __restrict__ cursor, int* __restrict__ csr) {
  int w = flags[1];
  int i = blockIdx.x * 256 + threadIdx.x;
  if (i < NEDGES) {
    int dd = ldi(edst, i, w);
    int pos = atomicAdd(&cursor[dd], 1);
    csr[rowstart[dd] + pos] = ldi(esrc, i, w);
  }
}

// transpose weights into bf16: z<3 -> WsT, z<6 -> WnT, z==6 -> awT
__global__ void k_transpose(const void* __restrict__ Ws, const void* __restrict__ Wn,
                            const void* __restrict__ Aw, const int* __restrict__ flags,
                            unsigned short* __restrict__ WsT,
                            unsigned short* __restrict__ WnT,
                            unsigned short* __restrict__ AwT) {
  __shared__ unsigned short tile[32][33];
  int f = flags[0];
  int z = blockIdx.z;
  const void* src; unsigned short* dst; size_t zoff;
  if (z < 3)      { src = Ws; zoff = (size_t)z * D * D;       dst = WsT + zoff; }
  else if (z < 6) { src = Wn; zoff = (size_t)(z - 3) * D * D; dst = WnT + zoff; }
  else            { src = Aw; zoff = 0;                       dst = AwT; }
  int k0 = blockIdx.x * 32, n0 = blockIdx.y * 32;
  int tx = threadIdx.x, ty = threadIdx.y;
#pragma unroll
  for (int j = 0; j < 4; ++j)
    tile[ty + j * 8][tx] = f2bf(ldf(src, zoff + (size_t)(k0 + ty + j * 8) * D + n0 + tx, f));
  __syncthreads();
#pragma unroll
  for (int j = 0; j < 4; ++j)
    dst[(size_t)(n0 + ty + j * 8) * D + k0 + tx] = tile[tx][ty + j * 8];
}

// ---------------- per-layer kernels ----------------

// msg[n] = mean over in-edges of x[src]; 192 threads, uint2 (4 bf16) per thread
__global__ __launch_bounds__(192) void k_msg(
    const unsigned short* __restrict__ x, const int* __restrict__ cnt,
    const int* __restrict__ rowstart, const int* __restrict__ csr,
    unsigned short* __restrict__ msg) {
  int n = blockIdx.x;
  int deg = cnt[n];
  int base = rowstart[n];
  float inv = 1.0f / (float)(deg > 1 ? deg : 1);
  int tid = threadIdx.x;
  float a0 = 0.f, a1 = 0.f, a2 = 0.f, a3 = 0.f;
  for (int e = 0; e < deg; ++e) {
    const uint2* xr = (const uint2*)(x + (size_t)csr[base + e] * D);
    uint2 v = xr[tid];
    a0 += bf2f((unsigned short)(v.x & 0xFFFFu));
    a1 += bf2f((unsigned short)(v.x >> 16));
    a2 += bf2f((unsigned short)(v.y & 0xFFFFu));
    a3 += bf2f((unsigned short)(v.y >> 16));
  }
  uint2 o;
  o.x = (unsigned)f2bf(a0 * inv) | ((unsigned)f2bf(a1 * inv) << 16);
  o.y = (unsigned)f2bf(a2 * inv) | ((unsigned)f2bf(a3 * inv) << 16);
  ((uint2*)(msg + (size_t)n * D))[tid] = o;
}

// Y = relu([X|MSG] @ [WsT;WnT]^T + bias), 3072x768, K=1536
// 32x32 per wave, 64x64 per block, grid 48x12, depth-1 register prefetch
__global__ __launch_bounds__(256) void k_gemm_gnn(
    const unsigned short* __restrict__ X, const unsigned short* __restrict__ MSG,
    const unsigned short* __restrict__ WsT, const unsigned short* __restrict__ WnT,
    const void* __restrict__ bias, size_t bias_off, const int* __restrict__ flags,
    unsigned short* __restrict__ Y) {
  int f = flags[0];
  int tid = threadIdx.x;
  int wave = tid >> 6, lane = tid & 63;
  int q = lane >> 4, t = lane & 15;
  int m0 = blockIdx.x * 64 + (wave >> 1) * 32;
  int n0 = blockIdx.y * 64 + (wave & 1) * 32;
  f32x4 acc[2][2];
#pragma unroll
  for (int mi = 0; mi < 2; ++mi)
#pragma unroll
    for (int ni = 0; ni < 2; ++ni)
      acc[mi][ni] = (f32x4){0.f, 0.f, 0.f, 0.f};

  // NOTE: 24 is not a power of 2 — must use explicit select, NOT (s & 23).
  auto ldA = [&](int s, int mi) -> bf16x8 {
    const unsigned short* Ab = (s < 24) ? X : MSG;
    int kk = ((s < 24) ? s : s - 24) * 32;
    return *(const bf16x8*)(Ab + (size_t)(m0 + mi * 16 + t) * D + kk + q * 8);
  };
  auto ldB = [&](int s, int ni) -> bf16x8 {
    const unsigned short* Wb = (s < 24) ? WsT : WnT;
    int kk = ((s < 24) ? s : s - 24) * 32;
    return *(const bf16x8*)(Wb + (size_t)(n0 + ni * 16 + t) * D + kk + q * 8);
  };

  bf16x8 ca0 = ldA(0, 0), ca1 = ldA(0, 1), cb0 = ldB(0, 0), cb1 = ldB(0, 1);
#pragma unroll
  for (int s = 0; s < 48; ++s) {
    bf16x8 na0, na1, nb0, nb1;
    if (s < 47) {
      int sn = s + 1;
      na0 = ldA(sn, 0); na1 = ldA(sn, 1); nb0 = ldB(sn, 0); nb1 = ldB(sn, 1);
    }
    acc[0][0] = mfma16(ca0, cb0, acc[0][0]);
    acc[0][1] = mfma16(ca0, cb1, acc[0][1]);
    acc[1][0] = mfma16(ca1, cb0, acc[1][0]);
    acc[1][1] = mfma16(ca1, cb1, acc[1][1]);
    ca0 = na0; ca1 = na1; cb0 = nb0; cb1 = nb1;
  }

#pragma unroll
  for (int ni = 0; ni < 2; ++ni) {
    int col = n0 + ni * 16 + t;
    float bv = ldf(bias, bias_off + col, f);
#pragma unroll
    for (int mi = 0; mi < 2; ++mi) {
#pragma unroll
      for (int r = 0; r < 4; ++r) {
        int row = m0 + mi * 16 + q * 4 + r;
        float v = acc[mi][ni][r] + bv;
        Y[(size_t)row * D + col] = f2bf(v > 0.f ? v : 0.f);
      }
    }
  }
}

// xp[b,m] = (m < nb) ? Y[pad_idx[b,m]] : 0; 192 threads, uint2 per thread
__global__ __launch_bounds__(192) void k_xp(
    const unsigned short* __restrict__ Xn, const void* __restrict__ pidx,
    const int* __restrict__ flags, const int* __restrict__ gcnt,
    unsigned short* __restrict__ xp) {
  int w = flags[1];
  int bm = blockIdx.x;
  int b = bm >> 7, m = bm & 127;
  int nb = gcnt[b];
  int tid = threadIdx.x;
  uint2* dst = (uint2*)(xp + (size_t)bm * D);
  if (m < nb) {
    const uint2* srcr = (const uint2*)(Xn + (size_t)ldi(pidx, bm, w) * D);
    dst[tid] = srcr[tid];
  } else {
    dst[tid] = (uint2){0u, 0u};
  }
}

// S[b] = xp[b] @ text[b]^T (128x512, K=768), fp32 out
// 32x32 per wave, 64x64 per block, grid (2,8,32), depth-1 register prefetch
__global__ __launch_bounds__(256) void k_scores(
    const unsigned short* __restrict__ xp, const unsigned short* __restrict__ traw,
    const unsigned short* __restrict__ tcvt, const int* __restrict__ flags,
    float* __restrict__ S) {
  const unsigned short* text = flags[0] ? tcvt : traw;
  int b = blockIdx.z;
  int tid = threadIdx.x;
  int wave = tid >> 6, lane = tid & 63;
  int q = lane >> 4, t = lane & 15;
  int m0 = blockIdx.x * 64 + (wave >> 1) * 32;
  int l0 = blockIdx.y * 64 + (wave & 1) * 32;
  const unsigned short* Xb = xp + (size_t)b * M * D;
  const unsigned short* Tb = text + (size_t)b * L * D;
  f32x4 acc[2][2];
#pragma unroll
  for (int mi = 0; mi < 2; ++mi)
#pragma unroll
    for (int ni = 0; ni < 2; ++ni)
      acc[mi][ni] = (f32x4){0.f, 0.f, 0.f, 0.f};

  auto ldA = [&](int s, int mi) -> bf16x8 {
    return *(const bf16x8*)(Xb + (size_t)(m0 + mi * 16 + t) * D + s * 32 + q * 8);
  };
  auto ldB = [&](int s, int ni) -> bf16x8 {
    return *(const bf16x8*)(Tb + (size_t)(l0 + ni * 16 + t) * D + s * 32 + q * 8);
  };

  bf16x8 ca0 = ldA(0, 0), ca1 = ldA(0, 1), cb0 = ldB(0, 0), cb1 = ldB(0, 1);
#pragma unroll
  for (int s = 0; s < 24; ++s) {
    bf16x8 na0, na1, nb0, nb1;
    if (s < 23) {
      int sn = s + 1;
      na0 = ldA(sn, 0); na1 = ldA(sn, 1); nb0 = ldB(sn, 0); nb1 = ldB(sn, 1);
    }
    acc[0][0] = mfma16(ca0, cb0, acc[0][0]);
    acc[0][1] = mfma16(ca0, cb1, acc[0][1]);
    acc[1][0] = mfma16(ca1, cb0, acc[1][0]);
    acc[1][1] = mfma16(ca1, cb1, acc[1][1]);
    ca0 = na0; ca1 = na1; cb0 = nb0; cb1 = nb1;
  }

  float* Sb = S + (size_t)b * M * L;
#pragma unroll
  for (int ni = 0; ni < 2; ++ni) {
    int col = l0 + ni * 16 + t;
#pragma unroll
    for (int mi = 0; mi < 2; ++mi) {
#pragma unroll
      for (int r = 0; r < 4; ++r) {
        int row = m0 + mi * 16 + q * 4 + r;
        Sb[(size_t)row * L + col] = acc[mi][ni][r];
      }
    }
  }
}

// per (b,m): row max + sum(exp) over l
__global__ __launch_bounds__(256) void k_rowstat(const float* __restrict__ S,
                                                 float* __restrict__ rmax, float* __restrict__ rsum) {
  __shared__ float red[4];
  int row = blockIdx.x, tid = threadIdx.x;
  int lane = tid & 63, wv = tid >> 6;
  const float* r = S + (size_t)row * L;
  float s0 = r[tid], s1 = r[tid + 256];
  float m = fmaxf(s0, s1);
#pragma unroll
  for (int o = 32; o > 0; o >>= 1) m = fmaxf(m, __shfl_down(m, o));
  if (lane == 0) red[wv] = m;
  __syncthreads();
  float bm = fmaxf(fmaxf(red[0], red[1]), fmaxf(red[2], red[3]));
  __syncthreads();
  float e = __expf(s0 - bm) + __expf(s1 - bm);
#pragma unroll
  for (int o = 32; o > 0; o >>= 1) e += __shfl_down(e, o);
  if (lane == 0) red[wv] = e;
  __syncthreads();
  if (tid == 0) { rmax[row] = bm; rsum[row] = red[0] + red[1] + red[2] + red[3]; }
}

// per (b,l): w = sum_m g2t, cmax/csum for t2g — 4 waves own 32-wide m-chunks, LSE-merged
__global__ __launch_bounds__(256) void k_colstat(
    const float* __restrict__ S, const float* __restrict__ rmax, const float* __restrict__ rsum,
    const int* __restrict__ gcnt, float* __restrict__ wv, float* __restrict__ cmaxv,
    float* __restrict__ csumv) {
  __shared__ float rm[M], ri[M];
  __shared__ float pw[4][64], pm[4][64], ps[4][64];
  int b = blockIdx.x, tid = threadIdx.x;
  int w = tid >> 6, lane = tid & 63;
  if (tid < M) { rm[tid] = rmax[b * M + tid]; ri[tid] = 1.f / rsum[b * M + tid]; }
  __syncthreads();
  int l = blockIdx.y * 64 + lane;
  int nb = gcnt[b];
  const float* Sb = S + (size_t)b * M * L;
  int m0 = w * 32;
  int m1 = min(m0 + 32, nb);
  float wp = 0.f, cm = -1e30f, cs = 0.f;
  for (int m = m0; m < m1; ++m) {
    float s = Sb[(size_t)m * L + l];
    wp += __expf(s - rm[m]) * ri[m];
    if (s > cm) { cs = cs * __expf(cm - s) + 1.f; cm = s; }
    else cs += __expf(s - cm);
  }
  pw[w][lane] = wp; pm[w][lane] = cm; ps[w][lane] = cs;
  __syncthreads();
  if (w == 0) {
    float W = 0.f, CM = -1e30f;
#pragma unroll
    for (int j = 0; j < 4; ++j) { W += pw[j][lane]; CM = fmaxf(CM, pm[j][lane]); }
    float CS = 0.f;
#pragma unroll
    for (int j = 0; j < 4; ++j) CS += ps[j][lane] * __expf(pm[j][lane] - CM);
    wv[b * L + l] = W; cmaxv[b * L + l] = CM; csumv[b * L + l] = CS;
  }
}

// per (b,m): t2gcol = sum_l t2g[b,l,m]
__global__ __launch_bounds__(256) void k_colsum(
    const float* __restrict__ S, const float* __restrict__ cmaxv, const float* __restrict__ csumv,
    const int* __restrict__ gcnt, float* __restrict__ t2gcol) {
  __shared__ float red[4];
  int bm = blockIdx.x, tid = threadIdx.x;
  int b = bm >> 7, m = bm & 127;
  int lane = tid & 63, wv_ = tid >> 6;
  int nb = gcnt[b];
  float acc = 0.f;
  if (m < nb) {
    const float* r = S + (size_t)bm * L;
    const float* cm = cmaxv + b * L;
    const float* cs = csumv + b * L;
    acc = __expf(r[tid] - cm[tid]) / cs[tid]
        + __expf(r[tid + 256] - cm[tid + 256]) / cs[tid + 256];
  }
#pragma unroll
  for (int o = 32; o > 0; o >>= 1) acc += __shfl_down(acc, o);
  if (lane == 0) red[wv_] = acc;
  __syncthreads();
  if (tid == 0) t2gcol[bm] = red[0] + red[1] + red[2] + red[3];
}

// pooled[b,d] += chunked GEMV terms / (nb+L); grid (B, 3, 10)
__global__ __launch_bounds__(256) void k_pooled(
    const float* __restrict__ wv, const float* __restrict__ t2gcol,
    const unsigned short* __restrict__ traw, const unsigned short* __restrict__ tcvt,
    const int* __restrict__ flags, const unsigned short* __restrict__ xp,
    const int* __restrict__ gcnt, float* __restrict__ pooled) {
  const unsigned short* text = flags[0] ? tcvt : traw;
  int b = blockIdx.x;
  int d = blockIdx.y * 256 + threadIdx.x;
  int c = blockIdx.z;
  float acc = 0.f;
  if (c < 8) {
    const unsigned short* Tb = text + (size_t)b * L * D;
    int l0 = c * 64;
    for (int l = l0; l < l0 + 64; ++l) acc += wv[b * L + l] * bf2f(Tb[(size_t)l * D + d]);
  } else {
    const unsigned short* Xb = xp + (size_t)b * M * D;
    int mm0 = (c - 8) * 64;
    for (int m = mm0; m < mm0 + 64; ++m) acc += t2gcol[b * M + m] * bf2f(Xb[(size_t)m * D + d]);
  }
  atomicAdd(&pooled[(size_t)b * D + d], acc / ((float)gcnt[b] + 512.f));
}

// ---------------- final-stage kernels ----------------

// xg[b,d] = mean over valid nodes (masked rows of xp are zero)
__global__ __launch_bounds__(256) void k_xg(const unsigned short* __restrict__ xp,
                                            const int* __restrict__ gcnt,
                                            unsigned short* __restrict__ xgb) {
  int b = blockIdx.x;
  int d = blockIdx.y * 256 + threadIdx.x;
  int nb = gcnt[b];
  float inv = 1.0f / (float)(nb > 1 ? nb : 1);
  const unsigned short* Xb = xp + (size_t)b * M * D;
  float s = 0.f;
  for (int m = 0; m < M; ++m) s += bf2f(Xb[(size_t)m * D + d]);
  xgb[(size_t)b * D + d] = f2bf(s * inv);
}

// gpre = xg @ atom_w (32x768, K=768) via MFMA; grid 12 blocks x 4 waves (16 cols each)
__global__ __launch_bounds__(256) void k_atom(const unsigned short* __restrict__ xgb,
                                              const unsigned short* __restrict__ awT,
                                              float* __restrict__ gpre) {
  int tid = threadIdx.x;
  int w = tid >> 6, lane = tid & 63;
  int q = lane >> 4, t = lane & 15;
  int nbase = blockIdx.x * 64 + w * 16;
  f32x4 acc[2];
  acc[0] = (f32x4){0.f, 0.f, 0.f, 0.f};
  acc[1] = (f32x4){0.f, 0.f, 0.f, 0.f};
  for (int kk = 0; kk < D; kk += 32) {
    bf16x8 a0 = *(const bf16x8*)(xgb + (size_t)t * D + kk + q * 8);
    bf16x8 a1 = *(const bf16x8*)(xgb + (size_t)(16 + t) * D + kk + q * 8);
    bf16x8 bv = *(const bf16x8*)(awT + (size_t)(nbase + t) * D + kk + q * 8);
    acc[0] = mfma16(a0, bv, acc[0]);
    acc[1] = mfma16(a1, bv, acc[1]);
  }
#pragma unroll
  for (int mi = 0; mi < 2; ++mi)
#pragma unroll
    for (int r = 0; r < 4; ++r) {
      int row = mi * 16 + q * 4 + r;
      gpre[(size_t)row * D + nbase + t] = acc[mi][r];
    }
}

__global__ __launch_bounds__(256) void k_final(
    const unsigned short* __restrict__ traw, const unsigned short* __restrict__ tcvt,
    const float* __restrict__ gpre, const float* __restrict__ pooled,
    const void* __restrict__ ab, const void* __restrict__ dmask,
    const void* __restrict__ gmask, const void* __restrict__ remb,
    const int* __restrict__ flags, void* __restrict__ out) {
  int f = flags[0];
  const unsigned short* text = f ? tcvt : traw;
  int b = blockIdx.x, tid = threadIdx.x;
  float dm = ldf(dmask, b, f);
  float gm = ldf(gmask, b, f);
  float dg = dm * gm;
  size_t base = (size_t)b * 2304;
#pragma unroll
  for (int j = 0; j < 3; ++j) {
    int d = tid + j * 256;
    float z = ldf(remb, d, f);
    float tv = bf2f(text[(size_t)b * L * D + d]);
    float o0 = tv * dm + (1.f - dm) * z;
    float gv = tanhf(gpre[(size_t)b * D + d] + ldf(ab, d, f));
    float o1 = gv * gm + (1.f - gm) * z;
    float p = pooled[(size_t)b * D + d] * (1.f / 3.f);
    float o2 = p * dg + (1.f - dg) * z;
    if (f) {
      float* of = (float*)out;
      of[base + d] = o0; of[base + 768 + d] = o1; of[base + 1536 + d] = o2;
    } else {
      unsigned short* ob = (unsigned short*)out;
      ob[base + d] = f2bf(o0); ob[base + 768 + d] = f2bf(o1); ob[base + 1536 + d] = f2bf(o2);
    }
  }
}

extern "C" void kernel_launch(void* const* d_in, const int* in_sizes, int n_in,
                              void* d_out, int out_size, void* d_ws, size_t ws_size,
                              hipStream_t stream) {
  const void* x_in  = d_in[0];
  const void* text  = d_in[1];
  const void* dmask = d_in[2];
  const void* gmask = d_in[3];
  const void* gws   = d_in[4];
  const void* gwn   = d_in[5];
  const void* gb    = d_in[6];
  const void* aw    = d_in[7];
  const void* ab    = d_in[8];
  const void* remb  = d_in[9];
  const void* batch = d_in[10];
  const void* pidx  = d_in[11];
  const void* esrc  = d_in[13];
  const void* edst  = d_in[14];

  char* wsp = (char*)d_ws;
  size_t off = 0;
  auto carve = [&](size_t bytes) -> void* {
    void* p = wsp + off;
    off += (bytes + 255) & ~(size_t)255;
    return p;
  };
  int* flags = (int*)carve(2 * 4);
  unsigned short* x0    = (unsigned short*)carve((size_t)NNODES * D * 2);
  unsigned short* xA    = (unsigned short*)carve((size_t)NNODES * D * 2);
  unsigned short* xB    = (unsigned short*)carve((size_t)NNODES * D * 2);
  unsigned short* msg   = (unsigned short*)carve((size_t)NNODES * D * 2);
  unsigned short* textb = (unsigned short*)carve((size_t)B * L * D * 2);
  unsigned short* WsT   = (unsigned short*)carve((size_t)3 * D * D * 2);
  unsigned short* WnT   = (unsigned short*)carve((size_t)3 * D * D * 2);
  unsigned short* AwT   = (unsigned short*)carve((size_t)D * D * 2);
  unsigned short* xp    = (unsigned short*)carve((size_t)B * M * D * 2);
  unsigned short* xgb   = (unsigned short*)carve((size_t)B * D * 2);
  float* gpre    = (float*)carve((size_t)B * D * 4);
  float* S       = (float*)carve((size_t)B * M * L * 4);
  float* rmax    = (float*)carve((size_t)B * M * 4);
  float* rsum    = (float*)carve((size_t)B * M * 4);
  float* wv      = (float*)carve((size_t)B * L * 4);
  float* cmaxv   = (float*)carve((size_t)B * L * 4);
  float* csumv   = (float*)carve((size_t)B * L * 4);
  float* t2gcol  = (float*)carve((size_t)B * M * 4);
  float* pooled  = (float*)carve((size_t)B * D * 4);
  int* cnt      = (int*)carve((size_t)NNODES * 4);
  int* rowstart = (int*)carve((size_t)(NNODES + 1) * 4);
  int* cursor   = (int*)carve((size_t)NNODES * 4);
  int* gcnt     = (int*)carve((size_t)B * 4);
  int* csr      = (int*)carve((size_t)NEDGES * 4);

  k_detect<<<1, 256, 0, stream>>>((const unsigned short*)text, (const unsigned int*)edst, flags);
  k_init<<<96, 256, 0, stream>>>(cnt, cursor, gcnt, pooled);
  k_cvt<<<(NNODES * D + 255) / 256, 256, 0, stream>>>(x_in, x0, NNODES * D, flags, 0);
  k_cvt<<<(B * L * D + 255) / 256, 256, 0, stream>>>(text, textb, B * L * D, flags, 1);
  k_transpose<<<dim3(24, 24, 7), dim3(32, 8), 0, stream>>>(gws, gwn, aw, flags, WsT, WnT, AwT);
  k_count<<<96, 256, 0, stream>>>(edst, batch, flags, cnt, gcnt);
  k_scan<<<1, 1024, 0, stream>>>(cnt, rowstart);
  k_scatter<<<96, 256, 0, stream>>>(esrc, edst, flags, rowstart, cursor, csr);

  const unsigned short* traw = (const unsigned short*)text;
  const unsigned short* xsrc = x0;
  unsigned short* xdst = xA;
  for (int i = 0; i < 3; ++i) {
    k_msg<<<NNODES, 192, 0, stream>>>(xsrc, cnt, rowstart, csr, msg);
    k_gemm_gnn<<<dim3(48, 12), 256, 0, stream>>>(xsrc, msg, WsT + (size_t)i * D * D,
                                                 WnT + (size_t)i * D * D, gb, (size_t)i * D,
                                                 flags, xdst);
    k_xp<<<B * M, 192, 0, stream>>>(xdst, pidx, flags, gcnt, xp);
    k_scores<<<dim3(2, 8, B), 256, 0, stream>>>(xp, traw, textb, flags, S);
    k_rowstat<<<B * M, 256, 0, stream>>>(S, rmax, rsum);
    k_colstat<<<dim3(B, 8), 256, 0, stream>>>(S, rmax, rsum, gcnt, wv, cmaxv, csumv);
    k_colsum<<<B * M, 256, 0, stream>>>(S, cmaxv, csumv, gcnt, t2gcol);
    k_pooled<<<dim3(B, 3, 10), 256, 0, stream>>>(wv, t2gcol, traw, textb, flags, xp, gcnt, pooled);
    xsrc = xdst;
    xdst = (i == 0) ? xB : xA;
  }
  k_xg<<<dim3(B, 3), 256, 0, stream>>>(xp, gcnt, xgb);
  k_atom<<<12, 256, 0, stream>>>(xgb, AwT, gpre);
  k_final<<<B, 256, 0, stream>>>(traw, textb, gpre, pooled, ab, dmask, gmask, remb,
                                 flags, d_out);
}

// Round 6
// 556.650 us; speedup vs baseline: 1.1089x; 1.1089x over previous
//
#include <hip/hip_runtime.h>

#define D 768
#define B 32
#define L 512
#define M 128
#define NNODES 3072
#define NEDGES 24576

using bf16x8 = __attribute__((ext_vector_type(8))) short;
using f32x4  = __attribute__((ext_vector_type(4))) float;

__device__ __forceinline__ float bf2f(unsigned short u) {
  union { unsigned int i; float f; } v; v.i = ((unsigned int)u) << 16; return v.f;
}
__device__ __forceinline__ unsigned short f2bf(float f) {
  union { float f; unsigned int i; } v; v.f = f;
  unsigned int x = v.i;
  return (unsigned short)((x + 0x7FFFu + ((x >> 16) & 1u)) >> 16);
}
__device__ __forceinline__ float ldf(const void* p, size_t i, int f32) {
  return f32 ? ((const float*)p)[i] : bf2f(((const unsigned short*)p)[i]);
}
__device__ __forceinline__ int ldi(const void* p, size_t i, int w64) {
  return w64 ? (int)((const long long*)p)[i] : ((const int*)p)[i];
}
__device__ __forceinline__ f32x4 mfma16(bf16x8 a, bf16x8 b, f32x4 c) {
  return __builtin_amdgcn_mfma_f32_16x16x32_bf16(a, b, c, 0, 0, 0);
}

// Packed fragment layout for a row-major [R x 768] bf16 matrix:
//   element (row, k) -> panel p=row/16, kk=k/32, lane=((k%32)/8)*16 + row%16, e=k%8
//   ushort offset = ((p*24 + kk) << 9) + lane*8 + e      (panel = 12288 ushorts = 24 KB)
// Fragment load for MFMA 16x16x32: uniform (p,kk) + laneId*8 -> 1 KB contiguous per wave.
__device__ __forceinline__ float pk_read(const unsigned short* P, int p, int l, int d) {
  // element (row p*16+l%..., ) generic scalar read: row index r in [0,16) is l
  return bf2f(P[(((size_t)(p * 24 + (d >> 5))) << 9) + ((((d & 31) >> 3) << 4) + l) * 8 + (d & 7)]);
}

// ---------- dtype detection: flags[0]=floats-are-fp32, flags[1]=ints-are-64bit ----------
__global__ void k_detect(const unsigned short* __restrict__ t,
                         const unsigned int* __restrict__ e, int* __restrict__ flags) {
  __shared__ int r0[256];
  __shared__ unsigned r1[256];
  int tid = threadIdx.x;
  int bad = 0;
  for (int i = tid; i < 8192; i += 256) {
    unsigned short u = t[2 * i];
    unsigned ex = (u >> 7) & 0xFF;
    if (ex >= 0xC0) bad = 1;
  }
  unsigned o = 0;
  for (int i = tid; i < NEDGES / 2; i += 256) o |= e[2 * i + 1];
  r0[tid] = bad; r1[tid] = o;
  __syncthreads();
  for (int s = 128; s > 0; s >>= 1) {
    if (tid < s) { r0[tid] |= r0[tid + s]; r1[tid] |= r1[tid + s]; }
    __syncthreads();
  }
  if (tid == 0) { flags[0] = r0[0]; flags[1] = (r1[0] == 0) ? 1 : 0; }
}

__global__ void k_cvt(const void* __restrict__ src, unsigned short* __restrict__ dst,
                      int n, const int* __restrict__ flags) {
  int f = flags[0];
  int i = blockIdx.x * 256 + threadIdx.x;
  if (i >= n) return;
  dst[i] = f ? f2bf(((const float*)src)[i]) : ((const unsigned short*)src)[i];
}

// pack row-major [panels*16 x 768] -> fragment-packed; raw: apply fp32 flag on src
__global__ __launch_bounds__(256) void k_pack(const void* __restrict__ src,
                                              unsigned short* __restrict__ dst,
                                              const int* __restrict__ flags, int raw) {
  __shared__ unsigned short buf[12288];
  int p = blockIdx.x, tid = threadIdx.x;
  int f = raw ? flags[0] : 0;
#pragma unroll
  for (int j = 0; j < 6; ++j) {
    int idx = j * 256 + tid;          // chunk of 8 elements within panel
    int r = idx / 96, c = idx % 96;
    size_t sbase = (size_t)(p * 16 + r) * 768 + c * 8;
    unsigned short v[8];
    if (f) {
      const float* sp = (const float*)src + sbase;
#pragma unroll
      for (int e = 0; e < 8; ++e) v[e] = f2bf(sp[e]);
    } else {
      const unsigned short* sp = (const unsigned short*)src + sbase;
#pragma unroll
      for (int e = 0; e < 8; ++e) v[e] = sp[e];
    }
    int lpos = (c >> 2) * 64 + (c & 3) * 16 + r;
#pragma unroll
    for (int e = 0; e < 8; ++e) buf[lpos * 8 + e] = v[e];
  }
  __syncthreads();
  uint4* d4 = (uint4*)(dst + (size_t)p * 12288);
  const uint4* b4 = (const uint4*)buf;
#pragma unroll
  for (int j = 0; j < 6; ++j) d4[j * 256 + tid] = b4[j * 256 + tid];
}

// ---------------- setup kernels ----------------

__global__ void k_init(int* cnt, int* cursor, int* gcnt, float* pooled) {
  int i = blockIdx.x * 256 + threadIdx.x;
  if (i < NNODES) { cnt[i] = 0; cursor[i] = 0; }
  if (i < B) gcnt[i] = 0;
  if (i < B * D) pooled[i] = 0.f;
}

__global__ void k_count(const void* __restrict__ edst, const void* __restrict__ batch,
                        const int* __restrict__ flags, int* __restrict__ cnt,
                        int* __restrict__ gcnt) {
  int w = flags[1];
  int i = blockIdx.x * 256 + threadIdx.x;
  if (i < NEDGES) atomicAdd(&cnt[ldi(edst, i, w)], 1);
  if (i < NNODES) atomicAdd(&gcnt[ldi(batch, i, w)], 1);
}

__global__ void k_scan(const int* __restrict__ cnt, int* __restrict__ rowstart) {
  __shared__ int a[NNODES], b[NNODES];
  int tid = threadIdx.x;
  for (int i = tid; i < NNODES; i += 1024) a[i] = cnt[i];
  __syncthreads();
  int* s = a; int* d = b;
  for (int off = 1; off < NNODES; off <<= 1) {
    for (int i = tid; i < NNODES; i += 1024)
      d[i] = s[i] + (i >= off ? s[i - off] : 0);
    __syncthreads();
    int* t = s; s = d; d = t;
  }
  for (int i = tid; i < NNODES; i += 1024) rowstart[i + 1] = s[i];
  if (tid == 0) rowstart[0] = 0;
}

__global__ void k_scatter(const void* __restrict__ esrc, const void* __restrict__ edst,
                          const int* __restrict__ flags, const int* __restrict__ rowstart,
                          int* __restrict__ cursor, int* __restrict__ csr) {
  int w = flags[1];
  int i = blockIdx.x * 256 + threadIdx.x;
  if (i < NEDGES) {
    int dd = ldi(edst, i, w);
    int pos = atomicAdd(&cursor[dd], 1);
    csr[rowstart[dd] + pos] = ldi(esrc, i, w);
  }
}

// transpose weights into bf16 rows: z<3 -> WsT, z<6 -> WnT, z==6 -> awT
__global__ void k_transpose(const void* __restrict__ Ws, const void* __restrict__ Wn,
                            const void* __restrict__ Aw, const int* __restrict__ flags,
                            unsigned short* __restrict__ WsT,
                            unsigned short* __restrict__ WnT,
                            unsigned short* __restrict__ AwT) {
  __shared__ unsigned short tile[32][33];
  int f = flags[0];
  int z = blockIdx.z;
  const void* src; unsigned short* dst; size_t zoff;
  if (z < 3)      { src = Ws; zoff = (size_t)z * D * D;       dst = WsT + zoff; }
  else if (z < 6) { src = Wn; zoff = (size_t)(z - 3) * D * D; dst = WnT + zoff; }
  else            { src = Aw; zoff = 0;                       dst = AwT; }
  int k0 = blockIdx.x * 32, n0 = blockIdx.y * 32;
  int tx = threadIdx.x, ty = threadIdx.y;
#pragma unroll
  for (int j = 0; j < 4; ++j)
    tile[ty + j * 8][tx] = f2bf(ldf(src, zoff + (size_t)(k0 + ty + j * 8) * D + n0 + tx, f));
  __syncthreads();
#pragma unroll
  for (int j = 0; j < 4; ++j)
    dst[(size_t)(n0 + ty + j * 8) * D + k0 + tx] = tile[tx][ty + j * 8];
}

// ---------------- per-layer kernels ----------------

// msg[n] = mean over in-edges of x[src]; rows out
__global__ __launch_bounds__(192) void k_msg(
    const unsigned short* __restrict__ x, const int* __restrict__ cnt,
    const int* __restrict__ rowstart, const int* __restrict__ csr,
    unsigned short* __restrict__ msg) {
  int n = blockIdx.x;
  int deg = cnt[n];
  int base = rowstart[n];
  float inv = 1.0f / (float)(deg > 1 ? deg : 1);
  int tid = threadIdx.x;
  float a0 = 0.f, a1 = 0.f, a2 = 0.f, a3 = 0.f;
  for (int e = 0; e < deg; ++e) {
    const uint2* xr = (const uint2*)(x + (size_t)csr[base + e] * D);
    uint2 v = xr[tid];
    a0 += bf2f((unsigned short)(v.x & 0xFFFFu));
    a1 += bf2f((unsigned short)(v.x >> 16));
    a2 += bf2f((unsigned short)(v.y & 0xFFFFu));
    a3 += bf2f((unsigned short)(v.y >> 16));
  }
  uint2 o;
  o.x = (unsigned)f2bf(a0 * inv) | ((unsigned)f2bf(a1 * inv) << 16);
  o.y = (unsigned)f2bf(a2 * inv) | ((unsigned)f2bf(a3 * inv) << 16);
  ((uint2*)(msg + (size_t)n * D))[tid] = o;
}

// Y = relu([X|MSG] @ [Ws;Wn]^T + bias); A/B operands fragment-packed; Y rows out
__global__ __launch_bounds__(256) void k_gemm_gnn(
    const unsigned short* __restrict__ Xpk, const unsigned short* __restrict__ Mpk,
    const unsigned short* __restrict__ WsPk, const unsigned short* __restrict__ WnPk,
    const void* __restrict__ bias, size_t bias_off, const int* __restrict__ flags,
    unsigned short* __restrict__ Y) {
  int f = flags[0];
  int tid = threadIdx.x;
  int wave = tid >> 6, lane = tid & 63;
  int q = lane >> 4, t = lane & 15;
  int m0 = blockIdx.x * 64 + (wave >> 1) * 32;
  int n0 = blockIdx.y * 64 + (wave & 1) * 32;
  int pa = m0 >> 4, pb = n0 >> 4;
  f32x4 acc[2][2];
#pragma unroll
  for (int mi = 0; mi < 2; ++mi)
#pragma unroll
    for (int ni = 0; ni < 2; ++ni)
      acc[mi][ni] = (f32x4){0.f, 0.f, 0.f, 0.f};

  auto ldA = [&](int s, int mi) -> bf16x8 {
    const unsigned short* P = (s < 24) ? Xpk : Mpk;
    int kk = (s < 24) ? s : s - 24;
    return *(const bf16x8*)(P + (((size_t)((pa + mi) * 24 + kk)) << 9) + (lane << 3));
  };
  auto ldB = [&](int s, int ni) -> bf16x8 {
    const unsigned short* P = (s < 24) ? WsPk : WnPk;
    int kk = (s < 24) ? s : s - 24;
    return *(const bf16x8*)(P + (((size_t)((pb + ni) * 24 + kk)) << 9) + (lane << 3));
  };

  bf16x8 ca0 = ldA(0, 0), ca1 = ldA(0, 1), cb0 = ldB(0, 0), cb1 = ldB(0, 1);
#pragma unroll
  for (int s = 0; s < 48; ++s) {
    bf16x8 na0, na1, nb0, nb1;
    if (s < 47) {
      int sn = s + 1;
      na0 = ldA(sn, 0); na1 = ldA(sn, 1); nb0 = ldB(sn, 0); nb1 = ldB(sn, 1);
    }
    acc[0][0] = mfma16(ca0, cb0, acc[0][0]);
    acc[0][1] = mfma16(ca0, cb1, acc[0][1]);
    acc[1][0] = mfma16(ca1, cb0, acc[1][0]);
    acc[1][1] = mfma16(ca1, cb1, acc[1][1]);
    ca0 = na0; ca1 = na1; cb0 = nb0; cb1 = nb1;
  }

#pragma unroll
  for (int ni = 0; ni < 2; ++ni) {
    int col = n0 + ni * 16 + t;
    float bv = ldf(bias, bias_off + col, f);
#pragma unroll
    for (int mi = 0; mi < 2; ++mi) {
#pragma unroll
      for (int r = 0; r < 4; ++r) {
        int row = m0 + mi * 16 + q * 4 + r;
        float v = acc[mi][ni][r] + bv;
        Y[(size_t)row * D + col] = f2bf(v > 0.f ? v : 0.f);
      }
    }
  }
}

// xp[b,m] = (m < nb) ? Y[pad_idx[b,m]] : 0; rows out
__global__ __launch_bounds__(192) void k_xp(
    const unsigned short* __restrict__ Xn, const void* __restrict__ pidx,
    const int* __restrict__ flags, const int* __restrict__ gcnt,
    unsigned short* __restrict__ xp) {
  int w = flags[1];
  int bm = blockIdx.x;
  int b = bm >> 7, m = bm & 127;
  int nb = gcnt[b];
  int tid = threadIdx.x;
  uint2* dst = (uint2*)(xp + (size_t)bm * D);
  if (m < nb) {
    const uint2* srcr = (const uint2*)(Xn + (size_t)ldi(pidx, bm, w) * D);
    dst[tid] = srcr[tid];
  } else {
    dst[tid] = (uint2){0u, 0u};
  }
}

// S[b] = xp[b] @ text[b]^T; both operands fragment-packed; fp32 S out
__global__ __launch_bounds__(256) void k_scores(
    const unsigned short* __restrict__ XpPk, const unsigned short* __restrict__ Tpk,
    float* __restrict__ S) {
  int b = blockIdx.z;
  int tid = threadIdx.x;
  int wave = tid >> 6, lane = tid & 63;
  int q = lane >> 4, t = lane & 15;
  int m0 = blockIdx.x * 64 + (wave >> 1) * 32;
  int l0 = blockIdx.y * 64 + (wave & 1) * 32;
  int pa = (b * M + m0) >> 4, pb = (b * L + l0) >> 4;
  f32x4 acc[2][2];
#pragma unroll
  for (int mi = 0; mi < 2; ++mi)
#pragma unroll
    for (int ni = 0; ni < 2; ++ni)
      acc[mi][ni] = (f32x4){0.f, 0.f, 0.f, 0.f};

  auto ldA = [&](int s, int mi) -> bf16x8 {
    return *(const bf16x8*)(XpPk + (((size_t)((pa + mi) * 24 + s)) << 9) + (lane << 3));
  };
  auto ldB = [&](int s, int ni) -> bf16x8 {
    return *(const bf16x8*)(Tpk + (((size_t)((pb + ni) * 24 + s)) << 9) + (lane << 3));
  };

  bf16x8 ca0 = ldA(0, 0), ca1 = ldA(0, 1), cb0 = ldB(0, 0), cb1 = ldB(0, 1);
#pragma unroll
  for (int s = 0; s < 24; ++s) {
    bf16x8 na0, na1, nb0, nb1;
    if (s < 23) {
      int sn = s + 1;
      na0 = ldA(sn, 0); na1 = ldA(sn, 1); nb0 = ldB(sn, 0); nb1 = ldB(sn, 1);
    }
    acc[0][0] = mfma16(ca0, cb0, acc[0][0]);
    acc[0][1] = mfma16(ca0, cb1, acc[0][1]);
    acc[1][0] = mfma16(ca1, cb0, acc[1][0]);
    acc[1][1] = mfma16(ca1, cb1, acc[1][1]);
    ca0 = na0; ca1 = na1; cb0 = nb0; cb1 = nb1;
  }

  float* Sb = S + (size_t)b * M * L;
#pragma unroll
  for (int ni = 0; ni < 2; ++ni) {
    int col = l0 + ni * 16 + t;
#pragma unroll
    for (int mi = 0; mi < 2; ++mi) {
#pragma unroll
      for (int r = 0; r < 4; ++r) {
        int row = m0 + mi * 16 + q * 4 + r;
        Sb[(size_t)row * L + col] = acc[mi][ni][r];
      }
    }
  }
}

// per (b,m): row max + sum(exp) over l
__global__ __launch_bounds__(256) void k_rowstat(const float* __restrict__ S,
                                                 float* __restrict__ rmax, float* __restrict__ rsum) {
  __shared__ float red[4];
  int row = blockIdx.x, tid = threadIdx.x;
  int lane = tid & 63, wv = tid >> 6;
  const float* r = S + (size_t)row * L;
  float s0 = r[tid], s1 = r[tid + 256];
  float m = fmaxf(s0, s1);
#pragma unroll
  for (int o = 32; o > 0; o >>= 1) m = fmaxf(m, __shfl_down(m, o));
  if (lane == 0) red[wv] = m;
  __syncthreads();
  float bm = fmaxf(fmaxf(red[0], red[1]), fmaxf(red[2], red[3]));
  __syncthreads();
  float e = __expf(s0 - bm) + __expf(s1 - bm);
#pragma unroll
  for (int o = 32; o > 0; o >>= 1) e += __shfl_down(e, o);
  if (lane == 0) red[wv] = e;
  __syncthreads();
  if (tid == 0) { rmax[row] = bm; rsum[row] = red[0] + red[1] + red[2] + red[3]; }
}

// per (b,l): w = sum_m g2t, cmax/csum for t2g — 4 waves own 32-wide m-chunks, LSE-merged
__global__ __launch_bounds__(256) void k_colstat(
    const float* __restrict__ S, const float* __restrict__ rmax, const float* __restrict__ rsum,
    const int* __restrict__ gcnt, float* __restrict__ wv, float* __restrict__ cmaxv,
    float* __restrict__ csumv) {
  __shared__ float rm[M], ri[M];
  __shared__ float pw[4][64], pm[4][64], ps[4][64];
  int b = blockIdx.x, tid = threadIdx.x;
  int w = tid >> 6, lane = tid & 63;
  if (tid < M) { rm[tid] = rmax[b * M + tid]; ri[tid] = 1.f / rsum[b * M + tid]; }
  __syncthreads();
  int l = blockIdx.y * 64 + lane;
  int nb = gcnt[b];
  const float* Sb = S + (size_t)b * M * L;
  int m0 = w * 32;
  int m1 = min(m0 + 32, nb);
  float wp = 0.f, cm = -1e30f, cs = 0.f;
  for (int m = m0; m < m1; ++m) {
    float s = Sb[(size_t)m * L + l];
    wp += __expf(s - rm[m]) * ri[m];
    if (s > cm) { cs = cs * __expf(cm - s) + 1.f; cm = s; }
    else cs += __expf(s - cm);
  }
  pw[w][lane] = wp; pm[w][lane] = cm; ps[w][lane] = cs;
  __syncthreads();
  if (w == 0) {
    float W = 0.f, CM = -1e30f;
#pragma unroll
    for (int j = 0; j < 4; ++j) { W += pw[j][lane]; CM = fmaxf(CM, pm[j][lane]); }
    float CS = 0.f;
#pragma unroll
    for (int j = 0; j < 4; ++j) CS += ps[j][lane] * __expf(pm[j][lane] - CM);
    wv[b * L + l] = W; cmaxv[b * L + l] = CM; csumv[b * L + l] = CS;
  }
}

// per (b,m): t2gcol = sum_l t2g[b,l,m]
__global__ __launch_bounds__(256) void k_colsum(
    const float* __restrict__ S, const float* __restrict__ cmaxv, const float* __restrict__ csumv,
    const int* __restrict__ gcnt, float* __restrict__ t2gcol) {
  __shared__ float red[4];
  int bm = blockIdx.x, tid = threadIdx.x;
  int b = bm >> 7, m = bm & 127;
  int lane = tid & 63, wv_ = tid >> 6;
  int nb = gcnt[b];
  float acc = 0.f;
  if (m < nb) {
    const float* r = S + (size_t)bm * L;
    const float* cm = cmaxv + b * L;
    const float* cs = csumv + b * L;
    acc = __expf(r[tid] - cm[tid]) / cs[tid]
        + __expf(r[tid + 256] - cm[tid + 256]) / cs[tid + 256];
  }
#pragma unroll
  for (int o = 32; o > 0; o >>= 1) acc += __shfl_down(acc, o);
  if (lane == 0) red[wv_] = acc;
  __syncthreads();
  if (tid == 0) t2gcol[bm] = red[0] + red[1] + red[2] + red[3];
}

// pooled[b,d] += chunked GEMV terms / (nb+L); grid (B, 3, 10); text from packed
__global__ __launch_bounds__(256) void k_pooled(
    const float* __restrict__ wv, const float* __restrict__ t2gcol,
    const unsigned short* __restrict__ Tpk, const unsigned short* __restrict__ xp,
    const int* __restrict__ gcnt, float* __restrict__ pooled) {
  int b = blockIdx.x;
  int d = blockIdx.y * 256 + threadIdx.x;
  int c = blockIdx.z;
  float acc = 0.f;
  if (c < 8) {
    int l0 = c * 64;
    for (int l = l0; l < l0 + 64; ++l) {
      int p = b * 32 + (l >> 4);
      acc += wv[b * L + l] * pk_read(Tpk, p, l & 15, d);
    }
  } else {
    const unsigned short* Xb = xp + (size_t)b * M * D;
    int mm0 = (c - 8) * 64;
    for (int m = mm0; m < mm0 + 64; ++m) acc += t2gcol[b * M + m] * bf2f(Xb[(size_t)m * D + d]);
  }
  atomicAdd(&pooled[(size_t)b * D + d], acc / ((float)gcnt[b] + 512.f));
}

// ---------------- final-stage kernels ----------------

__global__ __launch_bounds__(256) void k_xg(const unsigned short* __restrict__ xp,
                                            const int* __restrict__ gcnt,
                                            unsigned short* __restrict__ xgb) {
  int b = blockIdx.x;
  int d = blockIdx.y * 256 + threadIdx.x;
  int nb = gcnt[b];
  float inv = 1.0f / (float)(nb > 1 ? nb : 1);
  const unsigned short* Xb = xp + (size_t)b * M * D;
  float s = 0.f;
  for (int m = 0; m < M; ++m) s += bf2f(Xb[(size_t)m * D + d]);
  xgb[(size_t)b * D + d] = f2bf(s * inv);
}

// gpre = xg @ atom_w (32x768, K=768); B from packed AwPk
__global__ __launch_bounds__(256) void k_atom(const unsigned short* __restrict__ xgb,
                                              const unsigned short* __restrict__ AwPk,
                                              float* __restrict__ gpre) {
  int tid = threadIdx.x;
  int w = tid >> 6, lane = tid & 63;
  int q = lane >> 4, t = lane & 15;
  int nbase = blockIdx.x * 64 + w * 16;
  int pb = nbase >> 4;
  f32x4 acc[2];
  acc[0] = (f32x4){0.f, 0.f, 0.f, 0.f};
  acc[1] = (f32x4){0.f, 0.f, 0.f, 0.f};
  for (int kk = 0; kk < 24; ++kk) {
    bf16x8 a0 = *(const bf16x8*)(xgb + (size_t)t * D + kk * 32 + q * 8);
    bf16x8 a1 = *(const bf16x8*)(xgb + (size_t)(16 + t) * D + kk * 32 + q * 8);
    bf16x8 bv = *(const bf16x8*)(AwPk + (((size_t)(pb * 24 + kk)) << 9) + (lane << 3));
    acc[0] = mfma16(a0, bv, acc[0]);
    acc[1] = mfma16(a1, bv, acc[1]);
  }
#pragma unroll
  for (int mi = 0; mi < 2; ++mi)
#pragma unroll
    for (int r = 0; r < 4; ++r) {
      int row = mi * 16 + q * 4 + r;
      gpre[(size_t)row * D + nbase + t] = acc[mi][r];
    }
}

__global__ __launch_bounds__(256) void k_final(
    const unsigned short* __restrict__ Tpk, const float* __restrict__ gpre,
    const float* __restrict__ pooled, const void* __restrict__ ab,
    const void* __restrict__ dmask, const void* __restrict__ gmask,
    const void* __restrict__ remb, const int* __restrict__ flags,
    void* __restrict__ out) {
  int f = flags[0];
  int b = blockIdx.x, tid = threadIdx.x;
  float dm = ldf(dmask, b, f);
  float gm = ldf(gmask, b, f);
  float dg = dm * gm;
  size_t base = (size_t)b * 2304;
#pragma unroll
  for (int j = 0; j < 3; ++j) {
    int d = tid + j * 256;
    float z = ldf(remb, d, f);
    float tv = pk_read(Tpk, b * 32, 0, d);  // text[b, l=0, d]
    float o0 = tv * dm + (1.f - dm) * z;
    float gv = tanhf(gpre[(size_t)b * D + d] + ldf(ab, d, f));
    float o1 = gv * gm + (1.f - gm) * z;
    float p = pooled[(size_t)b * D + d] * (1.f / 3.f);
    float o2 = p * dg + (1.f - dg) * z;
    if (f) {
      float* of = (float*)out;
      of[base + d] = o0; of[base + 768 + d] = o1; of[base + 1536 + d] = o2;
    } else {
      unsigned short* ob = (unsigned short*)out;
      ob[base + d] = f2bf(o0); ob[base + 768 + d] = f2bf(o1); ob[base + 1536 + d] = f2bf(o2);
    }
  }
}

extern "C" void kernel_launch(void* const* d_in, const int* in_sizes, int n_in,
                              void* d_out, int out_size, void* d_ws, size_t ws_size,
                              hipStream_t stream) {
  const void* x_in  = d_in[0];
  const void* text  = d_in[1];
  const void* dmask = d_in[2];
  const void* gmask = d_in[3];
  const void* gws   = d_in[4];
  const void* gwn   = d_in[5];
  const void* gb    = d_in[6];
  const void* aw    = d_in[7];
  const void* ab    = d_in[8];
  const void* remb  = d_in[9];
  const void* batch = d_in[10];
  const void* pidx  = d_in[11];
  const void* esrc  = d_in[13];
  const void* edst  = d_in[14];

  char* wsp = (char*)d_ws;
  size_t off = 0;
  auto carve = [&](size_t bytes) -> void* {
    void* p = wsp + off;
    off += (bytes + 255) & ~(size_t)255;
    return p;
  };
  int* flags = (int*)carve(2 * 4);
  unsigned short* x0    = (unsigned short*)carve((size_t)NNODES * D * 2);
  unsigned short* xA    = (unsigned short*)carve((size_t)NNODES * D * 2);
  unsigned short* xB    = (unsigned short*)carve((size_t)NNODES * D * 2);
  unsigned short* msg   = (unsigned short*)carve((size_t)NNODES * D * 2);
  unsigned short* PkA   = (unsigned short*)carve((size_t)NNODES * D * 2);
  unsigned short* PkB   = (unsigned short*)carve((size_t)NNODES * D * 2);
  unsigned short* Mpk   = (unsigned short*)carve((size_t)NNODES * D * 2);
  unsigned short* Tpk   = (unsigned short*)carve((size_t)B * L * D * 2);
  unsigned short* WsT   = (unsigned short*)carve((size_t)3 * D * D * 2);
  unsigned short* WnT   = (unsigned short*)carve((size_t)3 * D * D * 2);
  unsigned short* AwT   = (unsigned short*)carve((size_t)D * D * 2);
  unsigned short* WsPk  = (unsigned short*)carve((size_t)3 * D * D * 2);
  unsigned short* WnPk  = (unsigned short*)carve((size_t)3 * D * D * 2);
  unsigned short* AwPk  = (unsigned short*)carve((size_t)D * D * 2);
  unsigned short* xp    = (unsigned short*)carve((size_t)B * M * D * 2);
  unsigned short* XpPk  = (unsigned short*)carve((size_t)B * M * D * 2);
  unsigned short* xgb   = (unsigned short*)carve((size_t)B * D * 2);
  float* gpre    = (float*)carve((size_t)B * D * 4);
  float* S       = (float*)carve((size_t)B * M * L * 4);
  float* rmax    = (float*)carve((size_t)B * M * 4);
  float* rsum    = (float*)carve((size_t)B * M * 4);
  float* wv      = (float*)carve((size_t)B * L * 4);
  float* cmaxv   = (float*)carve((size_t)B * L * 4);
  float* csumv   = (float*)carve((size_t)B * L * 4);
  float* t2gcol  = (float*)carve((size_t)B * M * 4);
  float* pooled  = (float*)carve((size_t)B * D * 4);
  int* cnt      = (int*)carve((size_t)NNODES * 4);
  int* rowstart = (int*)carve((size_t)(NNODES + 1) * 4);
  int* cursor   = (int*)carve((size_t)NNODES * 4);
  int* gcnt     = (int*)carve((size_t)B * 4);
  int* csr      = (int*)carve((size_t)NEDGES * 4);

  k_detect<<<1, 256, 0, stream>>>((const unsigned short*)text, (const unsigned int*)edst, flags);
  k_init<<<96, 256, 0, stream>>>(cnt, cursor, gcnt, pooled);
  k_cvt<<<(NNODES * D + 255) / 256, 256, 0, stream>>>(x_in, x0, NNODES * D, flags);
  k_pack<<<NNODES / 16, 256, 0, stream>>>(x_in, PkA, flags, 1);
  k_pack<<<B * L / 16, 256, 0, stream>>>(text, Tpk, flags, 1);
  k_transpose<<<dim3(24, 24, 7), dim3(32, 8), 0, stream>>>(gws, gwn, aw, flags, WsT, WnT, AwT);
  for (int i = 0; i < 3; ++i) {
    k_pack<<<48, 256, 0, stream>>>(WsT + (size_t)i * D * D, WsPk + (size_t)i * D * D, flags, 0);
    k_pack<<<48, 256, 0, stream>>>(WnT + (size_t)i * D * D, WnPk + (size_t)i * D * D, flags, 0);
  }
  k_pack<<<48, 256, 0, stream>>>(AwT, AwPk, flags, 0);
  k_count<<<96, 256, 0, stream>>>(edst, batch, flags, cnt, gcnt);
  k_scan<<<1, 1024, 0, stream>>>(cnt, rowstart);
  k_scatter<<<96, 256, 0, stream>>>(esrc, edst, flags, rowstart, cursor, csr);

  const unsigned short* xsrc = x0;        // rows for msg gather
  const unsigned short* Apk = PkA;        // packed A for gemm
  unsigned short* Y[3] = {xA, xB, xA};
  unsigned short* Npk[3] = {PkB, PkA, nullptr};
  for (int i = 0; i < 3; ++i) {
    k_msg<<<NNODES, 192, 0, stream>>>(xsrc, cnt, rowstart, csr, msg);
    k_pack<<<NNODES / 16, 256, 0, stream>>>(msg, Mpk, flags, 0);
    k_gemm_gnn<<<dim3(48, 12), 256, 0, stream>>>(Apk, Mpk, WsPk + (size_t)i * D * D,
                                                 WnPk + (size_t)i * D * D, gb, (size_t)i * D,
                                                 flags, Y[i]);
    if (i < 2) k_pack<<<NNODES / 16, 256, 0, stream>>>(Y[i], Npk[i], flags, 0);
    k_xp<<<B * M, 192, 0, stream>>>(Y[i], pidx, flags, gcnt, xp);
    k_pack<<<B * M / 16, 256, 0, stream>>>(xp, XpPk, flags, 0);
    k_scores<<<dim3(2, 8, B), 256, 0, stream>>>(XpPk, Tpk, S);
    k_rowstat<<<B * M, 256, 0, stream>>>(S, rmax, rsum);
    k_colstat<<<dim3(B, 8), 256, 0, stream>>>(S, rmax, rsum, gcnt, wv, cmaxv, csumv);
    k_colsum<<<B * M, 256, 0, stream>>>(S, cmaxv, csumv, gcnt, t2gcol);
    k_pooled<<<dim3(B, 3, 10), 256, 0, stream>>>(wv, t2gcol, Tpk, xp, gcnt, pooled);
    xsrc = Y[i];
    Apk = Npk[i];
  }
  k_xg<<<dim3(B, 3), 256, 0, stream>>>(xp, gcnt, xgb);
  k_atom<<<12, 256, 0, stream>>>(xgb, AwPk, gpre);
  k_final<<<B, 256, 0, stream>>>(Tpk, gpre, pooled, ab, dmask, gmask, remb, flags, d_out);
}

// Round 7
// 537.517 us; speedup vs baseline: 1.1484x; 1.0356x over previous
//
#include <hip/hip_runtime.h>

#define D 768
#define B 32
#define L 512
#define M 128
#define NNODES 3072
#define NEDGES 24576

using bf16x8 = __attribute__((ext_vector_type(8))) short;
using f32x4  = __attribute__((ext_vector_type(4))) float;

__device__ __forceinline__ float bf2f(unsigned short u) {
  union { unsigned int i; float f; } v; v.i = ((unsigned int)u) << 16; return v.f;
}
__device__ __forceinline__ unsigned short f2bf(float f) {
  union { float f; unsigned int i; } v; v.f = f;
  unsigned int x = v.i;
  return (unsigned short)((x + 0x7FFFu + ((x >> 16) & 1u)) >> 16);
}
__device__ __forceinline__ float ldf(const void* p, size_t i, int f32) {
  return f32 ? ((const float*)p)[i] : bf2f(((const unsigned short*)p)[i]);
}
__device__ __forceinline__ int ldi(const void* p, size_t i, int w64) {
  return w64 ? (int)((const long long*)p)[i] : ((const int*)p)[i];
}
__device__ __forceinline__ f32x4 mfma16(bf16x8 a, bf16x8 b, f32x4 c) {
  return __builtin_amdgcn_mfma_f32_16x16x32_bf16(a, b, c, 0, 0, 0);
}

// Packed fragment layout for row-major [R x 768] bf16:
//   (row,k) -> panel p=row/16, kk=k/32, lane=((k%32)/8)*16+row%16, e=k%8
//   ushort off = ((p*24+kk)<<9) + lane*8 + e   (panel = 12288 ushorts)
__device__ __forceinline__ float pk_read(const unsigned short* P, int p, int l, int d) {
  return bf2f(P[(((size_t)(p * 24 + (d >> 5))) << 9) + ((((d & 31) >> 3) << 4) + l) * 8 + (d & 7)]);
}

// ---------- dtype detection ----------
__global__ void k_detect(const unsigned short* __restrict__ t,
                         const unsigned int* __restrict__ e, int* __restrict__ flags) {
  __shared__ int r0[256];
  __shared__ unsigned r1[256];
  int tid = threadIdx.x;
  int bad = 0;
  for (int i = tid; i < 8192; i += 256) {
    unsigned short u = t[2 * i];
    unsigned ex = (u >> 7) & 0xFF;
    if (ex >= 0xC0) bad = 1;
  }
  unsigned o = 0;
  for (int i = tid; i < NEDGES / 2; i += 256) o |= e[2 * i + 1];
  r0[tid] = bad; r1[tid] = o;
  __syncthreads();
  for (int s = 128; s > 0; s >>= 1) {
    if (tid < s) { r0[tid] |= r0[tid + s]; r1[tid] |= r1[tid + s]; }
    __syncthreads();
  }
  if (tid == 0) { flags[0] = r0[0]; flags[1] = (r1[0] == 0) ? 1 : 0; }
}

__global__ void k_cvt(const void* __restrict__ src, unsigned short* __restrict__ dst,
                      int n, const int* __restrict__ flags) {
  int f = flags[0];
  int i = blockIdx.x * 256 + threadIdx.x;
  if (i >= n) return;
  dst[i] = f ? f2bf(((const float*)src)[i]) : ((const unsigned short*)src)[i];
}

// pack row-major [panels*16 x 768] -> fragment-packed (fp32 flag applies to src if raw)
__device__ __forceinline__ void pack_body(const void* src, unsigned short* dst,
                                          int p, int tid, int f) {
  __shared__ unsigned short buf[12288];
#pragma unroll
  for (int j = 0; j < 6; ++j) {
    int idx = j * 256 + tid;
    int r = idx / 96, c = idx % 96;
    size_t sbase = (size_t)(p * 16 + r) * 768 + c * 8;
    unsigned short v[8];
    if (f) {
      const float* sp = (const float*)src + sbase;
#pragma unroll
      for (int e = 0; e < 8; ++e) v[e] = f2bf(sp[e]);
    } else {
      const unsigned short* sp = (const unsigned short*)src + sbase;
#pragma unroll
      for (int e = 0; e < 8; ++e) v[e] = sp[e];
    }
    int lpos = (c >> 2) * 64 + (c & 3) * 16 + r;
#pragma unroll
    for (int e = 0; e < 8; ++e) buf[lpos * 8 + e] = v[e];
  }
  __syncthreads();
  uint4* d4 = (uint4*)(dst + (size_t)p * 12288);
  const uint4* b4 = (const uint4*)buf;
#pragma unroll
  for (int j = 0; j < 6; ++j) d4[j * 256 + tid] = b4[j * 256 + tid];
}

__global__ __launch_bounds__(256) void k_pack(const void* __restrict__ src,
                                              unsigned short* __restrict__ dst,
                                              const int* __restrict__ flags, int raw) {
  pack_body(src, dst, blockIdx.x, threadIdx.x, raw ? flags[0] : 0);
}

// all 7 weight matrices in one dispatch: y<3 Ws, y<6 Wn, y==6 Aw (already bf16 rows)
__global__ __launch_bounds__(256) void k_packw(
    const unsigned short* __restrict__ WsT, const unsigned short* __restrict__ WnT,
    const unsigned short* __restrict__ AwT, unsigned short* __restrict__ WsPk,
    unsigned short* __restrict__ WnPk, unsigned short* __restrict__ AwPk) {
  int z = blockIdx.y;
  const unsigned short* src; unsigned short* dst;
  if (z < 3)      { src = WsT + (size_t)z * D * D;       dst = WsPk + (size_t)z * D * D; }
  else if (z < 6) { src = WnT + (size_t)(z - 3) * D * D; dst = WnPk + (size_t)(z - 3) * D * D; }
  else            { src = AwT;                           dst = AwPk; }
  pack_body(src, dst, blockIdx.x, threadIdx.x, 0);
}

// ---------------- setup kernels ----------------

__global__ void k_init(int* cnt, int* cursor, int* gcnt, float* pooled) {
  int i = blockIdx.x * 256 + threadIdx.x;
  if (i < NNODES) { cnt[i] = 0; cursor[i] = 0; }
  if (i < B) gcnt[i] = 0;
  if (i < B * D) pooled[i] = 0.f;
}

__global__ void k_count(const void* __restrict__ edst, const void* __restrict__ batch,
                        const int* __restrict__ flags, int* __restrict__ cnt,
                        int* __restrict__ gcnt) {
  int w = flags[1];
  int i = blockIdx.x * 256 + threadIdx.x;
  if (i < NEDGES) atomicAdd(&cnt[ldi(edst, i, w)], 1);
  if (i < NNODES) atomicAdd(&gcnt[ldi(batch, i, w)], 1);
}

__global__ void k_scan(const int* __restrict__ cnt, int* __restrict__ rowstart) {
  __shared__ int a[NNODES], b[NNODES];
  int tid = threadIdx.x;
  for (int i = tid; i < NNODES; i += 1024) a[i] = cnt[i];
  __syncthreads();
  int* s = a; int* d = b;
  for (int off = 1; off < NNODES; off <<= 1) {
    for (int i = tid; i < NNODES; i += 1024)
      d[i] = s[i] + (i >= off ? s[i - off] : 0);
    __syncthreads();
    int* t = s; s = d; d = t;
  }
  for (int i = tid; i < NNODES; i += 1024) rowstart[i + 1] = s[i];
  if (tid == 0) rowstart[0] = 0;
}

__global__ void k_scatter(const void* __restrict__ esrc, const void* __restrict__ edst,
                          const int* __restrict__ flags, const int* __restrict__ rowstart,
                          int* __restrict__ cursor, int* __restrict__ csr) {
  int w = flags[1];
  int i = blockIdx.x * 256 + threadIdx.x;
  if (i < NEDGES) {
    int dd = ldi(edst, i, w);
    int pos = atomicAdd(&cursor[dd], 1);
    csr[rowstart[dd] + pos] = ldi(esrc, i, w);
  }
}

__global__ void k_transpose(const void* __restrict__ Ws, const void* __restrict__ Wn,
                            const void* __restrict__ Aw, const int* __restrict__ flags,
                            unsigned short* __restrict__ WsT,
                            unsigned short* __restrict__ WnT,
                            unsigned short* __restrict__ AwT) {
  __shared__ unsigned short tile[32][33];
  int f = flags[0];
  int z = blockIdx.z;
  const void* src; unsigned short* dst; size_t zoff;
  if (z < 3)      { src = Ws; zoff = (size_t)z * D * D;       dst = WsT + zoff; }
  else if (z < 6) { src = Wn; zoff = (size_t)(z - 3) * D * D; dst = WnT + zoff; }
  else            { src = Aw; zoff = 0;                       dst = AwT; }
  int k0 = blockIdx.x * 32, n0 = blockIdx.y * 32;
  int tx = threadIdx.x, ty = threadIdx.y;
#pragma unroll
  for (int j = 0; j < 4; ++j)
    tile[ty + j * 8][tx] = f2bf(ldf(src, zoff + (size_t)(k0 + ty + j * 8) * D + n0 + tx, f));
  __syncthreads();
#pragma unroll
  for (int j = 0; j < 4; ++j)
    dst[(size_t)(n0 + ty + j * 8) * D + k0 + tx] = tile[tx][ty + j * 8];
}

// ---------------- per-layer kernels ----------------

// msg mean written DIRECTLY in packed layout; block = one 16-node panel
__global__ __launch_bounds__(256) void k_msg_pack(
    const unsigned short* __restrict__ x, const int* __restrict__ cnt,
    const int* __restrict__ rowstart, const int* __restrict__ csr,
    unsigned short* __restrict__ Mpk) {
  __shared__ unsigned short buf[12288];
  int p = blockIdx.x, tid = threadIdx.x;
  int w = tid >> 6, lane = tid & 63;
#pragma unroll
  for (int i = 0; i < 4; ++i) {
    int r = w * 4 + i;
    int n = p * 16 + r;
    int deg = cnt[n], base = rowstart[n];
    float inv = 1.0f / (float)(deg > 1 ? deg : 1);
    float a[12];
#pragma unroll
    for (int j = 0; j < 12; ++j) a[j] = 0.f;
    for (int e = 0; e < deg; ++e) {
      const uint2* xr = (const uint2*)(x + (size_t)csr[base + e] * D);
#pragma unroll
      for (int j = 0; j < 3; ++j) {
        uint2 v = xr[lane + j * 64];
        a[j * 4 + 0] += bf2f((unsigned short)(v.x & 0xFFFFu));
        a[j * 4 + 1] += bf2f((unsigned short)(v.x >> 16));
        a[j * 4 + 2] += bf2f((unsigned short)(v.y & 0xFFFFu));
        a[j * 4 + 3] += bf2f((unsigned short)(v.y >> 16));
      }
    }
#pragma unroll
    for (int j = 0; j < 3; ++j) {
      int d0 = (lane + j * 64) * 4;
      int c = d0 >> 3, e0 = d0 & 7;
      int lpos = (c >> 2) * 64 + (c & 3) * 16 + r;
      unsigned short* bp = &buf[lpos * 8 + e0];
      bp[0] = f2bf(a[j * 4 + 0] * inv);
      bp[1] = f2bf(a[j * 4 + 1] * inv);
      bp[2] = f2bf(a[j * 4 + 2] * inv);
      bp[3] = f2bf(a[j * 4 + 3] * inv);
    }
  }
  __syncthreads();
  uint4* d4 = (uint4*)(Mpk + (size_t)p * 12288);
  const uint4* b4 = (const uint4*)buf;
#pragma unroll
  for (int j = 0; j < 6; ++j) d4[j * 256 + tid] = b4[j * 256 + tid];
}

// Y = relu([X|MSG]@[Ws;Wn]^T + b); packed operands; emits Y rows AND (optional) packed Y
__global__ __launch_bounds__(256) void k_gemm_gnn(
    const unsigned short* __restrict__ Xpk, const unsigned short* __restrict__ Mpk,
    const unsigned short* __restrict__ WsPk, const unsigned short* __restrict__ WnPk,
    const void* __restrict__ bias, size_t bias_off, const int* __restrict__ flags,
    unsigned short* __restrict__ Y, unsigned short* __restrict__ Ypk) {
  __shared__ unsigned short cbuf[64 * 72];
  int f = flags[0];
  int tid = threadIdx.x;
  int wave = tid >> 6, lane = tid & 63;
  int q = lane >> 4, t = lane & 15;
  int mL = (wave >> 1) * 32, nL = (wave & 1) * 32;
  int pa = (blockIdx.x * 64 + mL) >> 4, pb = (blockIdx.y * 64 + nL) >> 4;
  f32x4 acc[2][2];
#pragma unroll
  for (int mi = 0; mi < 2; ++mi)
#pragma unroll
    for (int ni = 0; ni < 2; ++ni)
      acc[mi][ni] = (f32x4){0.f, 0.f, 0.f, 0.f};

  auto ldA = [&](int s, int mi) -> bf16x8 {
    const unsigned short* P = (s < 24) ? Xpk : Mpk;
    int kk = (s < 24) ? s : s - 24;
    return *(const bf16x8*)(P + (((size_t)((pa + mi) * 24 + kk)) << 9) + (lane << 3));
  };
  auto ldB = [&](int s, int ni) -> bf16x8 {
    const unsigned short* P = (s < 24) ? WsPk : WnPk;
    int kk = (s < 24) ? s : s - 24;
    return *(const bf16x8*)(P + (((size_t)((pb + ni) * 24 + kk)) << 9) + (lane << 3));
  };

  bf16x8 ca0 = ldA(0, 0), ca1 = ldA(0, 1), cb0 = ldB(0, 0), cb1 = ldB(0, 1);
#pragma unroll
  for (int s = 0; s < 48; ++s) {
    bf16x8 na0, na1, nb0, nb1;
    if (s < 47) {
      int sn = s + 1;
      na0 = ldA(sn, 0); na1 = ldA(sn, 1); nb0 = ldB(sn, 0); nb1 = ldB(sn, 1);
    }
    acc[0][0] = mfma16(ca0, cb0, acc[0][0]);
    acc[0][1] = mfma16(ca0, cb1, acc[0][1]);
    acc[1][0] = mfma16(ca1, cb0, acc[1][0]);
    acc[1][1] = mfma16(ca1, cb1, acc[1][1]);
    ca0 = na0; ca1 = na1; cb0 = nb0; cb1 = nb1;
  }

#pragma unroll
  for (int ni = 0; ni < 2; ++ni) {
    int colL = nL + ni * 16 + t;
    int col = blockIdx.y * 64 + colL;
    float bv = ldf(bias, bias_off + col, f);
#pragma unroll
    for (int mi = 0; mi < 2; ++mi) {
#pragma unroll
      for (int r = 0; r < 4; ++r) {
        int rowL = mL + mi * 16 + q * 4 + r;
        int row = blockIdx.x * 64 + rowL;
        float v = acc[mi][ni][r] + bv;
        unsigned short o = f2bf(v > 0.f ? v : 0.f);
        Y[(size_t)row * D + col] = o;
        cbuf[rowL * 72 + colL] = o;
      }
    }
  }
  if (Ypk) {
    __syncthreads();
    int ch = tid >> 5, pos2 = (tid & 31) * 2;
    int pl = ch >> 1, kl = ch & 1;
    int pG = blockIdx.x * 4 + pl;
    int kkG = blockIdx.y * 2 + kl;
    unsigned short* dbase = Ypk + (((size_t)(pG * 24 + kkG)) << 9);
#pragma unroll
    for (int u = 0; u < 2; ++u) {
      int lpos = pos2 + u;
      int rowL = pl * 16 + (lpos & 15);
      int colL = kl * 32 + (lpos >> 4) * 8;
      uint4 vv = *(const uint4*)&cbuf[rowL * 72 + colL];
      *(uint4*)&dbase[lpos * 8] = vv;
    }
  }
}

// gather xp rows per panel; emits rows AND packed
__global__ __launch_bounds__(256) void k_xp_pack(
    const unsigned short* __restrict__ Xn, const void* __restrict__ pidx,
    const int* __restrict__ flags, const int* __restrict__ gcnt,
    unsigned short* __restrict__ xp, unsigned short* __restrict__ XpPk) {
  __shared__ unsigned short rows[16 * 776];   // +8 pad per row
  int p = blockIdx.x, tid = threadIdx.x;
  int w64 = flags[1];
  int r = tid >> 4, c16 = tid & 15;
  int bm = p * 16 + r;
  int b = bm >> 7, m = bm & 127;
  int nb = gcnt[b];
  uint4* dl = (uint4*)&rows[r * 776];
  if (m < nb) {
    const uint4* srcr = (const uint4*)(Xn + (size_t)ldi(pidx, bm, w64) * D);
#pragma unroll
    for (int j = 0; j < 6; ++j) dl[c16 + j * 16] = srcr[c16 + j * 16];
  } else {
    uint4 z = {0u, 0u, 0u, 0u};
#pragma unroll
    for (int j = 0; j < 6; ++j) dl[c16 + j * 16] = z;
  }
  __syncthreads();
  // row-major out (coalesced within rows)
#pragma unroll
  for (int j = 0; j < 6; ++j) {
    int idx = j * 256 + tid;
    int rr = idx / 96, cc = idx % 96;
    uint4 vv = *(const uint4*)&rows[rr * 776 + cc * 8];
    *(uint4*)&xp[(size_t)(p * 16 + rr) * D + cc * 8] = vv;
  }
  // packed out (contiguous stores)
  unsigned short* pb = XpPk + (size_t)p * 12288;
#pragma unroll
  for (int j = 0; j < 6; ++j) {
    int odx = j * 256 + tid;          // output 16B-chunk index 0..1535
    int kk = odx >> 6, lanep = odx & 63;
    int rr = lanep & 15, cg = lanep >> 4;
    int cc = kk * 4 + cg;
    uint4 vv = *(const uint4*)&rows[rr * 776 + cc * 8];
    *(uint4*)&pb[odx * 8] = vv;
  }
}

// S[b] = xp[b] @ text[b]^T; packed operands; fp32 S out
__global__ __launch_bounds__(256) void k_scores(
    const unsigned short* __restrict__ XpPk, const unsigned short* __restrict__ Tpk,
    float* __restrict__ S) {
  int b = blockIdx.z;
  int tid = threadIdx.x;
  int wave = tid >> 6, lane = tid & 63;
  int q = lane >> 4, t = lane & 15;
  int m0 = blockIdx.x * 64 + (wave >> 1) * 32;
  int l0 = blockIdx.y * 64 + (wave & 1) * 32;
  int pa = (b * M + m0) >> 4, pb = (b * L + l0) >> 4;
  f32x4 acc[2][2];
#pragma unroll
  for (int mi = 0; mi < 2; ++mi)
#pragma unroll
    for (int ni = 0; ni < 2; ++ni)
      acc[mi][ni] = (f32x4){0.f, 0.f, 0.f, 0.f};

  auto ldA = [&](int s, int mi) -> bf16x8 {
    return *(const bf16x8*)(XpPk + (((size_t)((pa + mi) * 24 + s)) << 9) + (lane << 3));
  };
  auto ldB = [&](int s, int ni) -> bf16x8 {
    return *(const bf16x8*)(Tpk + (((size_t)((pb + ni) * 24 + s)) << 9) + (lane << 3));
  };

  bf16x8 ca0 = ldA(0, 0), ca1 = ldA(0, 1), cb0 = ldB(0, 0), cb1 = ldB(0, 1);
#pragma unroll
  for (int s = 0; s < 24; ++s) {
    bf16x8 na0, na1, nb0, nb1;
    if (s < 23) {
      int sn = s + 1;
      na0 = ldA(sn, 0); na1 = ldA(sn, 1); nb0 = ldB(sn, 0); nb1 = ldB(sn, 1);
    }
    acc[0][0] = mfma16(ca0, cb0, acc[0][0]);
    acc[0][1] = mfma16(ca0, cb1, acc[0][1]);
    acc[1][0] = mfma16(ca1, cb0, acc[1][0]);
    acc[1][1] = mfma16(ca1, cb1, acc[1][1]);
    ca0 = na0; ca1 = na1; cb0 = nb0; cb1 = nb1;
  }

  float* Sb = S + (size_t)b * M * L;
#pragma unroll
  for (int ni = 0; ni < 2; ++ni) {
    int col = l0 + ni * 16 + t;
#pragma unroll
    for (int mi = 0; mi < 2; ++mi) {
#pragma unroll
      for (int r = 0; r < 4; ++r) {
        int row = m0 + mi * 16 + q * 4 + r;
        Sb[(size_t)row * L + col] = acc[mi][ni][r];
      }
    }
  }
}

__global__ __launch_bounds__(256) void k_rowstat(const float* __restrict__ S,
                                                 float* __restrict__ rmax, float* __restrict__ rsum) {
  __shared__ float red[4];
  int row = blockIdx.x, tid = threadIdx.x;
  int lane = tid & 63, wv = tid >> 6;
  const float* r = S + (size_t)row * L;
  float s0 = r[tid], s1 = r[tid + 256];
  float m = fmaxf(s0, s1);
#pragma unroll
  for (int o = 32; o > 0; o >>= 1) m = fmaxf(m, __shfl_down(m, o));
  if (lane == 0) red[wv] = m;
  __syncthreads();
  float bm = fmaxf(fmaxf(red[0], red[1]), fmaxf(red[2], red[3]));
  __syncthreads();
  float e = __expf(s0 - bm) + __expf(s1 - bm);
#pragma unroll
  for (int o = 32; o > 0; o >>= 1) e += __shfl_down(e, o);
  if (lane == 0) red[wv] = e;
  __syncthreads();
  if (tid == 0) { rmax[row] = bm; rsum[row] = red[0] + red[1] + red[2] + red[3]; }
}

__global__ __launch_bounds__(256) void k_colstat(
    const float* __restrict__ S, const float* __restrict__ rmax, const float* __restrict__ rsum,
    const int* __restrict__ gcnt, float* __restrict__ wv, float* __restrict__ cmaxv,
    float* __restrict__ csumv) {
  __shared__ float rm[M], ri[M];
  __shared__ float pw[4][64], pm[4][64], ps[4][64];
  int b = blockIdx.x, tid = threadIdx.x;
  int w = tid >> 6, lane = tid & 63;
  if (tid < M) { rm[tid] = rmax[b * M + tid]; ri[tid] = 1.f / rsum[b * M + tid]; }
  __syncthreads();
  int l = blockIdx.y * 64 + lane;
  int nb = gcnt[b];
  const float* Sb = S + (size_t)b * M * L;
  int m0 = w * 32;
  int m1 = min(m0 + 32, nb);
  float wp = 0.f, cm = -1e30f, cs = 0.f;
  for (int m = m0; m < m1; ++m) {
    float s = Sb[(size_t)m * L + l];
    wp += __expf(s - rm[m]) * ri[m];
    if (s > cm) { cs = cs * __expf(cm - s) + 1.f; cm = s; }
    else cs += __expf(s - cm);
  }
  pw[w][lane] = wp; pm[w][lane] = cm; ps[w][lane] = cs;
  __syncthreads();
  if (w == 0) {
    float W = 0.f, CM = -1e30f;
#pragma unroll
    for (int j = 0; j < 4; ++j) { W += pw[j][lane]; CM = fmaxf(CM, pm[j][lane]); }
    float CS = 0.f;
#pragma unroll
    for (int j = 0; j < 4; ++j) CS += ps[j][lane] * __expf(pm[j][lane] - CM);
    wv[b * L + l] = W; cmaxv[b * L + l] = CM; csumv[b * L + l] = CS;
  }
}

__global__ __launch_bounds__(256) void k_colsum(
    const float* __restrict__ S, const float* __restrict__ cmaxv, const float* __restrict__ csumv,
    const int* __restrict__ gcnt, float* __restrict__ t2gcol) {
  __shared__ float red[4];
  int bm = blockIdx.x, tid = threadIdx.x;
  int b = bm >> 7, m = bm & 127;
  int lane = tid & 63, wv_ = tid >> 6;
  int nb = gcnt[b];
  float acc = 0.f;
  if (m < nb) {
    const float* r = S + (size_t)bm * L;
    const float* cm = cmaxv + b * L;
    const float* cs = csumv + b * L;
    acc = __expf(r[tid] - cm[tid]) / cs[tid]
        + __expf(r[tid + 256] - cm[tid + 256]) / cs[tid + 256];
  }
#pragma unroll
  for (int o = 32; o > 0; o >>= 1) acc += __shfl_down(acc, o);
  if (lane == 0) red[wv_] = acc;
  __syncthreads();
  if (tid == 0) t2gcol[bm] = red[0] + red[1] + red[2] + red[3];
}

__global__ __launch_bounds__(256) void k_pooled(
    const float* __restrict__ wv, const float* __restrict__ t2gcol,
    const unsigned short* __restrict__ Tpk, const unsigned short* __restrict__ xp,
    const int* __restrict__ gcnt, float* __restrict__ pooled) {
  int b = blockIdx.x;
  int d = blockIdx.y * 256 + threadIdx.x;
  int c = blockIdx.z;
  float acc = 0.f;
  if (c < 8) {
    int l0 = c * 64;
    for (int l = l0; l < l0 + 64; ++l) {
      int p = b * 32 + (l >> 4);
      acc += wv[b * L + l] * pk_read(Tpk, p, l & 15, d);
    }
  } else {
    const unsigned short* Xb = xp + (size_t)b * M * D;
    int mm0 = (c - 8) * 64;
    for (int m = mm0; m < mm0 + 64; ++m) acc += t2gcol[b * M + m] * bf2f(Xb[(size_t)m * D + d]);
  }
  atomicAdd(&pooled[(size_t)b * D + d], acc / ((float)gcnt[b] + 512.f));
}

// ---------------- final-stage kernels ----------------

__global__ __launch_bounds__(256) void k_xg(const unsigned short* __restrict__ xp,
                                            const int* __restrict__ gcnt,
                                            unsigned short* __restrict__ xgb) {
  int b = blockIdx.x;
  int d = blockIdx.y * 256 + threadIdx.x;
  int nb = gcnt[b];
  float inv = 1.0f / (float)(nb > 1 ? nb : 1);
  const unsigned short* Xb = xp + (size_t)b * M * D;
  float s = 0.f;
  for (int m = 0; m < M; ++m) s += bf2f(Xb[(size_t)m * D + d]);
  xgb[(size_t)b * D + d] = f2bf(s * inv);
}

__global__ __launch_bounds__(256) void k_atom(const unsigned short* __restrict__ xgb,
                                              const unsigned short* __restrict__ AwPk,
                                              float* __restrict__ gpre) {
  int tid = threadIdx.x;
  int w = tid >> 6, lane = tid & 63;
  int q = lane >> 4, t = lane & 15;
  int nbase = blockIdx.x * 64 + w * 16;
  int pb = nbase >> 4;
  f32x4 acc[2];
  acc[0] = (f32x4){0.f, 0.f, 0.f, 0.f};
  acc[1] = (f32x4){0.f, 0.f, 0.f, 0.f};
  for (int kk = 0; kk < 24; ++kk) {
    bf16x8 a0 = *(const bf16x8*)(xgb + (size_t)t * D + kk * 32 + q * 8);
    bf16x8 a1 = *(const bf16x8*)(xgb + (size_t)(16 + t) * D + kk * 32 + q * 8);
    bf16x8 bv = *(const bf16x8*)(AwPk + (((size_t)(pb * 24 + kk)) << 9) + (lane << 3));
    acc[0] = mfma16(a0, bv, acc[0]);
    acc[1] = mfma16(a1, bv, acc[1]);
  }
#pragma unroll
  for (int mi = 0; mi < 2; ++mi)
#pragma unroll
    for (int r = 0; r < 4; ++r) {
      int row = mi * 16 + q * 4 + r;
      gpre[(size_t)row * D + nbase + t] = acc[mi][r];
    }
}

__global__ __launch_bounds__(256) void k_final(
    const unsigned short* __restrict__ Tpk, const float* __restrict__ gpre,
    const float* __restrict__ pooled, const void* __restrict__ ab,
    const void* __restrict__ dmask, const void* __restrict__ gmask,
    const void* __restrict__ remb, const int* __restrict__ flags,
    void* __restrict__ out) {
  int f = flags[0];
  int b = blockIdx.x, tid = threadIdx.x;
  float dm = ldf(dmask, b, f);
  float gm = ldf(gmask, b, f);
  float dg = dm * gm;
  size_t base = (size_t)b * 2304;
#pragma unroll
  for (int j = 0; j < 3; ++j) {
    int d = tid + j * 256;
    float z = ldf(remb, d, f);
    float tv = pk_read(Tpk, b * 32, 0, d);
    float o0 = tv * dm + (1.f - dm) * z;
    float gv = tanhf(gpre[(size_t)b * D + d] + ldf(ab, d, f));
    float o1 = gv * gm + (1.f - gm) * z;
    float p = pooled[(size_t)b * D + d] * (1.f / 3.f);
    float o2 = p * dg + (1.f - dg) * z;
    if (f) {
      float* of = (float*)out;
      of[base + d] = o0; of[base + 768 + d] = o1; of[base + 1536 + d] = o2;
    } else {
      unsigned short* ob = (unsigned short*)out;
      ob[base + d] = f2bf(o0); ob[base + 768 + d] = f2bf(o1); ob[base + 1536 + d] = f2bf(o2);
    }
  }
}

extern "C" void kernel_launch(void* const* d_in, const int* in_sizes, int n_in,
                              void* d_out, int out_size, void* d_ws, size_t ws_size,
                              hipStream_t stream) {
  const void* x_in  = d_in[0];
  const void* text  = d_in[1];
  const void* dmask = d_in[2];
  const void* gmask = d_in[3];
  const void* gws   = d_in[4];
  const void* gwn   = d_in[5];
  const void* gb    = d_in[6];
  const void* aw    = d_in[7];
  const void* ab    = d_in[8];
  const void* remb  = d_in[9];
  const void* batch = d_in[10];
  const void* pidx  = d_in[11];
  const void* esrc  = d_in[13];
  const void* edst  = d_in[14];

  char* wsp = (char*)d_ws;
  size_t off = 0;
  auto carve = [&](size_t bytes) -> void* {
    void* p = wsp + off;
    off += (bytes + 255) & ~(size_t)255;
    return p;
  };
  int* flags = (int*)carve(2 * 4);
  unsigned short* x0    = (unsigned short*)carve((size_t)NNODES * D * 2);
  unsigned short* xA    = (unsigned short*)carve((size_t)NNODES * D * 2);
  unsigned short* xB    = (unsigned short*)carve((size_t)NNODES * D * 2);
  unsigned short* PkA   = (unsigned short*)carve((size_t)NNODES * D * 2);
  unsigned short* PkB   = (unsigned short*)carve((size_t)NNODES * D * 2);
  unsigned short* Mpk   = (unsigned short*)carve((size_t)NNODES * D * 2);
  unsigned short* Tpk   = (unsigned short*)carve((size_t)B * L * D * 2);
  unsigned short* WsT   = (unsigned short*)carve((size_t)3 * D * D * 2);
  unsigned short* WnT   = (unsigned short*)carve((size_t)3 * D * D * 2);
  unsigned short* AwT   = (unsigned short*)carve((size_t)D * D * 2);
  unsigned short* WsPk  = (unsigned short*)carve((size_t)3 * D * D * 2);
  unsigned short* WnPk  = (unsigned short*)carve((size_t)3 * D * D * 2);
  unsigned short* AwPk  = (unsigned short*)carve((size_t)D * D * 2);
  unsigned short* xp    = (unsigned short*)carve((size_t)B * M * D * 2);
  unsigned short* XpPk  = (unsigned short*)carve((size_t)B * M * D * 2);
  unsigned short* xgb   = (unsigned short*)carve((size_t)B * D * 2);
  float* gpre    = (float*)carve((size_t)B * D * 4);
  float* S       = (float*)carve((size_t)B * M * L * 4);
  float* rmax    = (float*)carve((size_t)B * M * 4);
  float* rsum    = (float*)carve((size_t)B * M * 4);
  float* wv      = (float*)carve((size_t)B * L * 4);
  float* cmaxv   = (float*)carve((size_t)B * L * 4);
  float* csumv   = (float*)carve((size_t)B * L * 4);
  float* t2gcol  = (float*)carve((size_t)B * M * 4);
  float* pooled  = (float*)carve((size_t)B * D * 4);
  int* cnt      = (int*)carve((size_t)NNODES * 4);
  int* rowstart = (int*)carve((size_t)(NNODES + 1) * 4);
  int* cursor   = (int*)carve((size_t)NNODES * 4);
  int* gcnt     = (int*)carve((size_t)B * 4);
  int* csr      = (int*)carve((size_t)NEDGES * 4);

  k_detect<<<1, 256, 0, stream>>>((const unsigned short*)text, (const unsigned int*)edst, flags);
  k_init<<<96, 256, 0, stream>>>(cnt, cursor, gcnt, pooled);
  k_cvt<<<(NNODES * D + 255) / 256, 256, 0, stream>>>(x_in, x0, NNODES * D, flags);
  k_pack<<<NNODES / 16, 256, 0, stream>>>(x_in, PkA, flags, 1);
  k_pack<<<B * L / 16, 256, 0, stream>>>(text, Tpk, flags, 1);
  k_transpose<<<dim3(24, 24, 7), dim3(32, 8), 0, stream>>>(gws, gwn, aw, flags, WsT, WnT, AwT);
  k_packw<<<dim3(48, 7), 256, 0, stream>>>(WsT, WnT, AwT, WsPk, WnPk, AwPk);
  k_count<<<96, 256, 0, stream>>>(edst, batch, flags, cnt, gcnt);
  k_scan<<<1, 1024, 0, stream>>>(cnt, rowstart);
  k_scatter<<<96, 256, 0, stream>>>(esrc, edst, flags, rowstart, cursor, csr);

  const unsigned short* xsrc = x0;        // rows for msg gather
  const unsigned short* Apk = PkA;        // packed A for gemm
  unsigned short* Y[3]   = {xA, xB, xA};
  unsigned short* Npk[3] = {PkB, PkA, nullptr};
  for (int i = 0; i < 3; ++i) {
    k_msg_pack<<<NNODES / 16, 256, 0, stream>>>(xsrc, cnt, rowstart, csr, Mpk);
    k_gemm_gnn<<<dim3(48, 12), 256, 0, stream>>>(Apk, Mpk, WsPk + (size_t)i * D * D,
                                                 WnPk + (size_t)i * D * D, gb, (size_t)i * D,
                                                 flags, Y[i], Npk[i]);
    k_xp_pack<<<B * M / 16, 256, 0, stream>>>(Y[i], pidx, flags, gcnt, xp, XpPk);
    k_scores<<<dim3(2, 8, B), 256, 0, stream>>>(XpPk, Tpk, S);
    k_rowstat<<<B * M, 256, 0, stream>>>(S, rmax, rsum);
    k_colstat<<<dim3(B, 8), 256, 0, stream>>>(S, rmax, rsum, gcnt, wv, cmaxv, csumv);
    k_colsum<<<B * M, 256, 0, stream>>>(S, cmaxv, csumv, gcnt, t2gcol);
    k_pooled<<<dim3(B, 3, 10), 256, 0, stream>>>(wv, t2gcol, Tpk, xp, gcnt, pooled);
    xsrc = Y[i];
    Apk = Npk[i];
  }
  k_xg<<<dim3(B, 3), 256, 0, stream>>>(xp, gcnt, xgb);
  k_atom<<<12, 256, 0, stream>>>(xgb, AwPk, gpre);
  k_final<<<B, 256, 0, stream>>>(Tpk, gpre, pooled, ab, dmask, gmask, remb, flags, d_out);
}

// Round 8
// 518.177 us; speedup vs baseline: 1.1912x; 1.0373x over previous
//
#include <hip/hip_runtime.h>

#define D 768
#define B 32
#define L 512
#define M 128
#define NNODES 3072
#define NEDGES 24576

using bf16x8 = __attribute__((ext_vector_type(8))) short;
using f32x4  = __attribute__((ext_vector_type(4))) float;

__device__ __forceinline__ float bf2f(unsigned short u) {
  union { unsigned int i; float f; } v; v.i = ((unsigned int)u) << 16; return v.f;
}
__device__ __forceinline__ unsigned short f2bf(float f) {
  union { float f; unsigned int i; } v; v.f = f;
  unsigned int x = v.i;
  return (unsigned short)((x + 0x7FFFu + ((x >> 16) & 1u)) >> 16);
}
__device__ __forceinline__ float ldf(const void* p, size_t i, int f32) {
  return f32 ? ((const float*)p)[i] : bf2f(((const unsigned short*)p)[i]);
}
__device__ __forceinline__ int ldi(const void* p, size_t i, int w64) {
  return w64 ? (int)((const long long*)p)[i] : ((const int*)p)[i];
}
__device__ __forceinline__ f32x4 mfma16(bf16x8 a, bf16x8 b, f32x4 c) {
  return __builtin_amdgcn_mfma_f32_16x16x32_bf16(a, b, c, 0, 0, 0);
}
__device__ __forceinline__ void gl_lds(const unsigned short* gsrc, unsigned short* lbase,
                                       int lane) {
  __builtin_amdgcn_global_load_lds(
      (const __attribute__((address_space(1))) unsigned int*)(gsrc + lane * 8),
      (__attribute__((address_space(3))) unsigned int*)lbase, 16, 0, 0);
}

// Packed fragment layout for row-major [R x 768] bf16:
//   (row,k) -> panel p=row/16, kk=k/32, lane=((k%32)/8)*16+row%16, e=k%8
//   ushort off = ((p*24+kk)<<9) + lane*8 + e   (chunk = 512 ushorts = 1 KB/wave)
__device__ __forceinline__ float pk_read(const unsigned short* P, int p, int l, int d) {
  return bf2f(P[(((size_t)(p * 24 + (d >> 5))) << 9) + ((((d & 31) >> 3) << 4) + l) * 8 + (d & 7)]);
}

// ---------- dtype detection ----------
__global__ void k_detect(const unsigned short* __restrict__ t,
                         const unsigned int* __restrict__ e, int* __restrict__ flags) {
  __shared__ int r0[256];
  __shared__ unsigned r1[256];
  int tid = threadIdx.x;
  int bad = 0;
  for (int i = tid; i < 8192; i += 256) {
    unsigned short u = t[2 * i];
    unsigned ex = (u >> 7) & 0xFF;
    if (ex >= 0xC0) bad = 1;
  }
  unsigned o = 0;
  for (int i = tid; i < NEDGES / 2; i += 256) o |= e[2 * i + 1];
  r0[tid] = bad; r1[tid] = o;
  __syncthreads();
  for (int s = 128; s > 0; s >>= 1) {
    if (tid < s) { r0[tid] |= r0[tid + s]; r1[tid] |= r1[tid + s]; }
    __syncthreads();
  }
  if (tid == 0) { flags[0] = r0[0]; flags[1] = (r1[0] == 0) ? 1 : 0; }
}

// pack row-major [panels*16 x 768] -> fragment-packed
__device__ __forceinline__ void pack_body(const void* src, unsigned short* dst,
                                          int p, int tid, int f) {
  __shared__ unsigned short buf[12288];
#pragma unroll
  for (int j = 0; j < 6; ++j) {
    int idx = j * 256 + tid;
    int r = idx / 96, c = idx % 96;
    size_t sbase = (size_t)(p * 16 + r) * 768 + c * 8;
    unsigned short v[8];
    if (f) {
      const float* sp = (const float*)src + sbase;
#pragma unroll
      for (int e = 0; e < 8; ++e) v[e] = f2bf(sp[e]);
    } else {
      const unsigned short* sp = (const unsigned short*)src + sbase;
#pragma unroll
      for (int e = 0; e < 8; ++e) v[e] = sp[e];
    }
    int lpos = (c >> 2) * 64 + (c & 3) * 16 + r;
#pragma unroll
    for (int e = 0; e < 8; ++e) buf[lpos * 8 + e] = v[e];
  }
  __syncthreads();
  uint4* d4 = (uint4*)(dst + (size_t)p * 12288);
  const uint4* b4 = (const uint4*)buf;
#pragma unroll
  for (int j = 0; j < 6; ++j) d4[j * 256 + tid] = b4[j * 256 + tid];
}

__global__ __launch_bounds__(256) void k_pack(const void* __restrict__ src,
                                              unsigned short* __restrict__ dst,
                                              const int* __restrict__ flags, int raw) {
  pack_body(src, dst, blockIdx.x, threadIdx.x, raw ? flags[0] : 0);
}

// x_in -> bf16 rows (x0) AND packed (PkA) in one pass
__global__ __launch_bounds__(256) void k_cvt_pack(const void* __restrict__ src,
                                                  unsigned short* __restrict__ rows,
                                                  unsigned short* __restrict__ dst,
                                                  const int* __restrict__ flags) {
  __shared__ unsigned short buf[12288];
  int p = blockIdx.x, tid = threadIdx.x;
  int f = flags[0];
#pragma unroll
  for (int j = 0; j < 6; ++j) {
    int idx = j * 256 + tid;
    int r = idx / 96, c = idx % 96;
    size_t sbase = (size_t)(p * 16 + r) * 768 + c * 8;
    union { unsigned short v[8]; uint4 q; } u;
    if (f) {
      const float* sp = (const float*)src + sbase;
#pragma unroll
      for (int e = 0; e < 8; ++e) u.v[e] = f2bf(sp[e]);
    } else {
      const unsigned short* sp = (const unsigned short*)src + sbase;
#pragma unroll
      for (int e = 0; e < 8; ++e) u.v[e] = sp[e];
    }
    *(uint4*)&rows[sbase] = u.q;
    int lpos = (c >> 2) * 64 + (c & 3) * 16 + r;
#pragma unroll
    for (int e = 0; e < 8; ++e) buf[lpos * 8 + e] = u.v[e];
  }
  __syncthreads();
  uint4* d4 = (uint4*)(dst + (size_t)p * 12288);
  const uint4* b4 = (const uint4*)buf;
#pragma unroll
  for (int j = 0; j < 6; ++j) d4[j * 256 + tid] = b4[j * 256 + tid];
}

// all 7 weight matrices packed in one dispatch
__global__ __launch_bounds__(256) void k_packw(
    const unsigned short* __restrict__ WsT, const unsigned short* __restrict__ WnT,
    const unsigned short* __restrict__ AwT, unsigned short* __restrict__ WsPk,
    unsigned short* __restrict__ WnPk, unsigned short* __restrict__ AwPk) {
  int z = blockIdx.y;
  const unsigned short* src; unsigned short* dst;
  if (z < 3)      { src = WsT + (size_t)z * D * D;       dst = WsPk + (size_t)z * D * D; }
  else if (z < 6) { src = WnT + (size_t)(z - 3) * D * D; dst = WnPk + (size_t)(z - 3) * D * D; }
  else            { src = AwT;                           dst = AwPk; }
  pack_body(src, dst, blockIdx.x, threadIdx.x, 0);
}

// ---------------- setup kernels ----------------

__global__ void k_init(int* cnt, int* cursor, int* gcnt, float* pooled) {
  int i = blockIdx.x * 256 + threadIdx.x;
  if (i < NNODES) { cnt[i] = 0; cursor[i] = 0; }
  if (i < B) gcnt[i] = 0;
  if (i < B * D) pooled[i] = 0.f;
}

__global__ void k_count(const void* __restrict__ edst, const void* __restrict__ batch,
                        const int* __restrict__ flags, int* __restrict__ cnt,
                        int* __restrict__ gcnt) {
  int w = flags[1];
  int i = blockIdx.x * 256 + threadIdx.x;
  if (i < NEDGES) atomicAdd(&cnt[ldi(edst, i, w)], 1);
  if (i < NNODES) atomicAdd(&gcnt[ldi(batch, i, w)], 1);
}

__global__ void k_scan(const int* __restrict__ cnt, int* __restrict__ rowstart) {
  __shared__ int a[NNODES], b[NNODES];
  int tid = threadIdx.x;
  for (int i = tid; i < NNODES; i += 1024) a[i] = cnt[i];
  __syncthreads();
  int* s = a; int* d = b;
  for (int off = 1; off < NNODES; off <<= 1) {
    for (int i = tid; i < NNODES; i += 1024)
      d[i] = s[i] + (i >= off ? s[i - off] : 0);
    __syncthreads();
    int* t = s; s = d; d = t;
  }
  for (int i = tid; i < NNODES; i += 1024) rowstart[i + 1] = s[i];
  if (tid == 0) rowstart[0] = 0;
}

__global__ void k_scatter(const void* __restrict__ esrc, const void* __restrict__ edst,
                          const int* __restrict__ flags, const int* __restrict__ rowstart,
                          int* __restrict__ cursor, int* __restrict__ csr) {
  int w = flags[1];
  int i = blockIdx.x * 256 + threadIdx.x;
  if (i < NEDGES) {
    int dd = ldi(edst, i, w);
    int pos = atomicAdd(&cursor[dd], 1);
    csr[rowstart[dd] + pos] = ldi(esrc, i, w);
  }
}

__global__ void k_transpose(const void* __restrict__ Ws, const void* __restrict__ Wn,
                            const void* __restrict__ Aw, const int* __restrict__ flags,
                            unsigned short* __restrict__ WsT,
                            unsigned short* __restrict__ WnT,
                            unsigned short* __restrict__ AwT) {
  __shared__ unsigned short tile[32][33];
  int f = flags[0];
  int z = blockIdx.z;
  const void* src; unsigned short* dst; size_t zoff;
  if (z < 3)      { src = Ws; zoff = (size_t)z * D * D;       dst = WsT + zoff; }
  else if (z < 6) { src = Wn; zoff = (size_t)(z - 3) * D * D; dst = WnT + zoff; }
  else            { src = Aw; zoff = 0;                       dst = AwT; }
  int k0 = blockIdx.x * 32, n0 = blockIdx.y * 32;
  int tx = threadIdx.x, ty = threadIdx.y;
#pragma unroll
  for (int j = 0; j < 4; ++j)
    tile[ty + j * 8][tx] = f2bf(ldf(src, zoff + (size_t)(k0 + ty + j * 8) * D + n0 + tx, f));
  __syncthreads();
#pragma unroll
  for (int j = 0; j < 4; ++j)
    dst[(size_t)(n0 + ty + j * 8) * D + k0 + tx] = tile[tx][ty + j * 8];
}

// ---------------- per-layer kernels ----------------

// msg mean written directly in packed layout; block = one 16-node panel
__global__ __launch_bounds__(256) void k_msg_pack(
    const unsigned short* __restrict__ x, const int* __restrict__ cnt,
    const int* __restrict__ rowstart, const int* __restrict__ csr,
    unsigned short* __restrict__ Mpk) {
  __shared__ unsigned short buf[12288];
  int p = blockIdx.x, tid = threadIdx.x;
  int w = tid >> 6, lane = tid & 63;
#pragma unroll
  for (int i = 0; i < 4; ++i) {
    int r = w * 4 + i;
    int n = p * 16 + r;
    int deg = cnt[n], base = rowstart[n];
    float inv = 1.0f / (float)(deg > 1 ? deg : 1);
    float a[12];
#pragma unroll
    for (int j = 0; j < 12; ++j) a[j] = 0.f;
    for (int e = 0; e < deg; ++e) {
      const uint2* xr = (const uint2*)(x + (size_t)csr[base + e] * D);
#pragma unroll
      for (int j = 0; j < 3; ++j) {
        uint2 v = xr[lane + j * 64];
        a[j * 4 + 0] += bf2f((unsigned short)(v.x & 0xFFFFu));
        a[j * 4 + 1] += bf2f((unsigned short)(v.x >> 16));
        a[j * 4 + 2] += bf2f((unsigned short)(v.y & 0xFFFFu));
        a[j * 4 + 3] += bf2f((unsigned short)(v.y >> 16));
      }
    }
#pragma unroll
    for (int j = 0; j < 3; ++j) {
      int d0 = (lane + j * 64) * 4;
      int c = d0 >> 3, e0 = d0 & 7;
      int lpos = (c >> 2) * 64 + (c & 3) * 16 + r;
      unsigned short* bp = &buf[lpos * 8 + e0];
      bp[0] = f2bf(a[j * 4 + 0] * inv);
      bp[1] = f2bf(a[j * 4 + 1] * inv);
      bp[2] = f2bf(a[j * 4 + 2] * inv);
      bp[3] = f2bf(a[j * 4 + 3] * inv);
    }
  }
  __syncthreads();
  uint4* d4 = (uint4*)(Mpk + (size_t)p * 12288);
  const uint4* b4 = (const uint4*)buf;
#pragma unroll
  for (int j = 0; j < 6; ++j) d4[j * 256 + tid] = b4[j * 256 + tid];
}

// Y = relu([X|MSG]@[Ws;Wn]^T + b); LDS-staged 64x64 block via global_load_lds.
// 4 waves share each staged line: halves L2 line-requests vs direct fragment loads.
__global__ __launch_bounds__(256) void k_gemm_gnn(
    const unsigned short* __restrict__ Xpk, const unsigned short* __restrict__ Mpk,
    const unsigned short* __restrict__ WsPk, const unsigned short* __restrict__ WnPk,
    const void* __restrict__ bias, size_t bias_off, const int* __restrict__ flags,
    unsigned short* __restrict__ Y) {
  __shared__ __align__(16) unsigned short lds[4096];   // 8 chunks x 1KB
  int f = flags[0];
  int tid = threadIdx.x;
  int wave = tid >> 6, lane = tid & 63;
  int q = lane >> 4, t = lane & 15;
  int wm = wave >> 1, wn = wave & 1;
  int pa = blockIdx.x * 4, pb = blockIdx.y * 4;
  f32x4 acc[2][2];
#pragma unroll
  for (int mi = 0; mi < 2; ++mi)
#pragma unroll
    for (int ni = 0; ni < 2; ++ni)
      acc[mi][ni] = (f32x4){0.f, 0.f, 0.f, 0.f};

  int c0 = wave * 2;
  for (int s = 0; s < 48; ++s) {
    const unsigned short* Pa = (s < 24) ? Xpk : Mpk;
    const unsigned short* Pb = (s < 24) ? WsPk : WnPk;
    int kk = (s < 24) ? s : s - 24;
    // wave 0: A panels 0,1; wave 1: A 2,3; wave 2: B 0,1; wave 3: B 2,3
    const unsigned short* P = (wave < 2) ? Pa : Pb;
    int pan0 = (wave < 2) ? (pa + c0) : (pb + c0 - 4);
    gl_lds(P + (((size_t)(pan0 * 24 + kk)) << 9), &lds[c0 * 512], lane);
    gl_lds(P + (((size_t)((pan0 + 1) * 24 + kk)) << 9), &lds[(c0 + 1) * 512], lane);
    __syncthreads();
    bf16x8 a0 = *(const bf16x8*)&lds[(wm * 2 + 0) * 512 + lane * 8];
    bf16x8 a1 = *(const bf16x8*)&lds[(wm * 2 + 1) * 512 + lane * 8];
    bf16x8 b0 = *(const bf16x8*)&lds[(4 + wn * 2 + 0) * 512 + lane * 8];
    bf16x8 b1 = *(const bf16x8*)&lds[(4 + wn * 2 + 1) * 512 + lane * 8];
    acc[0][0] = mfma16(a0, b0, acc[0][0]);
    acc[0][1] = mfma16(a0, b1, acc[0][1]);
    acc[1][0] = mfma16(a1, b0, acc[1][0]);
    acc[1][1] = mfma16(a1, b1, acc[1][1]);
    __syncthreads();
  }

#pragma unroll
  for (int ni = 0; ni < 2; ++ni) {
    int col = blockIdx.y * 64 + wn * 32 + ni * 16 + t;
    float bv = ldf(bias, bias_off + col, f);
#pragma unroll
    for (int mi = 0; mi < 2; ++mi) {
#pragma unroll
      for (int r = 0; r < 4; ++r) {
        int row = blockIdx.x * 64 + wm * 32 + mi * 16 + q * 4 + r;
        float v = acc[mi][ni][r] + bv;
        Y[(size_t)row * D + col] = f2bf(v > 0.f ? v : 0.f);
      }
    }
  }
}

// gather xp rows per panel; emits rows AND packed
__global__ __launch_bounds__(256) void k_xp_pack(
    const unsigned short* __restrict__ Xn, const void* __restrict__ pidx,
    const int* __restrict__ flags, const int* __restrict__ gcnt,
    unsigned short* __restrict__ xp, unsigned short* __restrict__ XpPk) {
  __shared__ unsigned short rows[16 * 776];
  int p = blockIdx.x, tid = threadIdx.x;
  int w64 = flags[1];
  int r = tid >> 4, c16 = tid & 15;
  int bm = p * 16 + r;
  int b = bm >> 7, m = bm & 127;
  int nb = gcnt[b];
  uint4* dl = (uint4*)&rows[r * 776];
  if (m < nb) {
    const uint4* srcr = (const uint4*)(Xn + (size_t)ldi(pidx, bm, w64) * D);
#pragma unroll
    for (int j = 0; j < 6; ++j) dl[c16 + j * 16] = srcr[c16 + j * 16];
  } else {
    uint4 z = {0u, 0u, 0u, 0u};
#pragma unroll
    for (int j = 0; j < 6; ++j) dl[c16 + j * 16] = z;
  }
  __syncthreads();
#pragma unroll
  for (int j = 0; j < 6; ++j) {
    int idx = j * 256 + tid;
    int rr = idx / 96, cc = idx % 96;
    uint4 vv = *(const uint4*)&rows[rr * 776 + cc * 8];
    *(uint4*)&xp[(size_t)(p * 16 + rr) * D + cc * 8] = vv;
  }
  unsigned short* pb = XpPk + (size_t)p * 12288;
#pragma unroll
  for (int j = 0; j < 6; ++j) {
    int odx = j * 256 + tid;
    int kk = odx >> 6, lanep = odx & 63;
    int rr = lanep & 15, cg = lanep >> 4;
    int cc = kk * 4 + cg;
    uint4 vv = *(const uint4*)&rows[rr * 776 + cc * 8];
    *(uint4*)&pb[odx * 8] = vv;
  }
}

// S[b] = xp[b] @ text[b]^T; LDS-staged like gemm; fp32 S out. grid (2,8,B)
__global__ __launch_bounds__(256) void k_scores(
    const unsigned short* __restrict__ XpPk, const unsigned short* __restrict__ Tpk,
    float* __restrict__ S) {
  __shared__ __align__(16) unsigned short lds[4096];
  int b = blockIdx.z;
  int tid = threadIdx.x;
  int wave = tid >> 6, lane = tid & 63;
  int q = lane >> 4, t = lane & 15;
  int wm = wave >> 1, wn = wave & 1;
  int pa = b * 8 + blockIdx.x * 4;
  int pb = b * 32 + blockIdx.y * 4;
  f32x4 acc[2][2];
#pragma unroll
  for (int mi = 0; mi < 2; ++mi)
#pragma unroll
    for (int ni = 0; ni < 2; ++ni)
      acc[mi][ni] = (f32x4){0.f, 0.f, 0.f, 0.f};

  int c0 = wave * 2;
  const unsigned short* P = (wave < 2) ? XpPk : Tpk;
  int pan0 = (wave < 2) ? (pa + c0) : (pb + c0 - 4);
  for (int s = 0; s < 24; ++s) {
    gl_lds(P + (((size_t)(pan0 * 24 + s)) << 9), &lds[c0 * 512], lane);
    gl_lds(P + (((size_t)((pan0 + 1) * 24 + s)) << 9), &lds[(c0 + 1) * 512], lane);
    __syncthreads();
    bf16x8 a0 = *(const bf16x8*)&lds[(wm * 2 + 0) * 512 + lane * 8];
    bf16x8 a1 = *(const bf16x8*)&lds[(wm * 2 + 1) * 512 + lane * 8];
    bf16x8 b0 = *(const bf16x8*)&lds[(4 + wn * 2 + 0) * 512 + lane * 8];
    bf16x8 b1 = *(const bf16x8*)&lds[(4 + wn * 2 + 1) * 512 + lane * 8];
    acc[0][0] = mfma16(a0, b0, acc[0][0]);
    acc[0][1] = mfma16(a0, b1, acc[0][1]);
    acc[1][0] = mfma16(a1, b0, acc[1][0]);
    acc[1][1] = mfma16(a1, b1, acc[1][1]);
    __syncthreads();
  }

  float* Sb = S + (size_t)b * M * L;
#pragma unroll
  for (int ni = 0; ni < 2; ++ni) {
    int col = blockIdx.y * 64 + wn * 32 + ni * 16 + t;
#pragma unroll
    for (int mi = 0; mi < 2; ++mi) {
#pragma unroll
      for (int r = 0; r < 4; ++r) {
        int row = blockIdx.x * 64 + wm * 32 + mi * 16 + q * 4 + r;
        Sb[(size_t)row * L + col] = acc[mi][ni][r];
      }
    }
  }
}

__global__ __launch_bounds__(256) void k_rowstat(const float* __restrict__ S,
                                                 float* __restrict__ rmax, float* __restrict__ rsum) {
  __shared__ float red[4];
  int row = blockIdx.x, tid = threadIdx.x;
  int lane = tid & 63, wv = tid >> 6;
  const float* r = S + (size_t)row * L;
  float s0 = r[tid], s1 = r[tid + 256];
  float m = fmaxf(s0, s1);
#pragma unroll
  for (int o = 32; o > 0; o >>= 1) m = fmaxf(m, __shfl_down(m, o));
  if (lane == 0) red[wv] = m;
  __syncthreads();
  float bm = fmaxf(fmaxf(red[0], red[1]), fmaxf(red[2], red[3]));
  __syncthreads();
  float e = __expf(s0 - bm) + __expf(s1 - bm);
#pragma unroll
  for (int o = 32; o > 0; o >>= 1) e += __shfl_down(e, o);
  if (lane == 0) red[wv] = e;
  __syncthreads();
  if (tid == 0) { rmax[row] = bm; rsum[row] = red[0] + red[1] + red[2] + red[3]; }
}

__global__ __launch_bounds__(256) void k_colstat(
    const float* __restrict__ S, const float* __restrict__ rmax, const float* __restrict__ rsum,
    const int* __restrict__ gcnt, float* __restrict__ wv, float* __restrict__ cmaxv,
    float* __restrict__ csumv) {
  __shared__ float rm[M], ri[M];
  __shared__ float pw[4][64], pm[4][64], ps[4][64];
  int b = blockIdx.x, tid = threadIdx.x;
  int w = tid >> 6, lane = tid & 63;
  if (tid < M) { rm[tid] = rmax[b * M + tid]; ri[tid] = 1.f / rsum[b * M + tid]; }
  __syncthreads();
  int l = blockIdx.y * 64 + lane;
  int nb = gcnt[b];
  const float* Sb = S + (size_t)b * M * L;
  int m0 = w * 32;
  int m1 = min(m0 + 32, nb);
  float wp = 0.f, cm = -1e30f, cs = 0.f;
  for (int m = m0; m < m1; ++m) {
    float s = Sb[(size_t)m * L + l];
    wp += __expf(s - rm[m]) * ri[m];
    if (s > cm) { cs = cs * __expf(cm - s) + 1.f; cm = s; }
    else cs += __expf(s - cm);
  }
  pw[w][lane] = wp; pm[w][lane] = cm; ps[w][lane] = cs;
  __syncthreads();
  if (w == 0) {
    float W = 0.f, CM = -1e30f;
#pragma unroll
    for (int j = 0; j < 4; ++j) { W += pw[j][lane]; CM = fmaxf(CM, pm[j][lane]); }
    float CS = 0.f;
#pragma unroll
    for (int j = 0; j < 4; ++j) CS += ps[j][lane] * __expf(pm[j][lane] - CM);
    wv[b * L + l] = W; cmaxv[b * L + l] = CM; csumv[b * L + l] = CS;
  }
}

__global__ __launch_bounds__(256) void k_colsum(
    const float* __restrict__ S, const float* __restrict__ cmaxv, const float* __restrict__ csumv,
    const int* __restrict__ gcnt, float* __restrict__ t2gcol) {
  __shared__ float red[4];
  int bm = blockIdx.x, tid = threadIdx.x;
  int b = bm >> 7, m = bm & 127;
  int lane = tid & 63, wv_ = tid >> 6;
  int nb = gcnt[b];
  float acc = 0.f;
  if (m < nb) {
    const float* r = S + (size_t)bm * L;
    const float* cm = cmaxv + b * L;
    const float* cs = csumv + b * L;
    acc = __expf(r[tid] - cm[tid]) / cs[tid]
        + __expf(r[tid + 256] - cm[tid + 256]) / cs[tid + 256];
  }
#pragma unroll
  for (int o = 32; o > 0; o >>= 1) acc += __shfl_down(acc, o);
  if (lane == 0) red[wv_] = acc;
  __syncthreads();
  if (tid == 0) t2gcol[bm] = red[0] + red[1] + red[2] + red[3];
}

__global__ __launch_bounds__(256) void k_pooled(
    const float* __restrict__ wv, const float* __restrict__ t2gcol,
    const unsigned short* __restrict__ Tpk, const unsigned short* __restrict__ xp,
    const int* __restrict__ gcnt, float* __restrict__ pooled) {
  int b = blockIdx.x;
  int d = blockIdx.y * 256 + threadIdx.x;
  int c = blockIdx.z;
  float acc = 0.f;
  if (c < 8) {
    int l0 = c * 64;
    for (int l = l0; l < l0 + 64; ++l) {
      int p = b * 32 + (l >> 4);
      acc += wv[b * L + l] * pk_read(Tpk, p, l & 15, d);
    }
  } else {
    const unsigned short* Xb = xp + (size_t)b * M * D;
    int mm0 = (c - 8) * 64;
    for (int m = mm0; m < mm0 + 64; ++m) acc += t2gcol[b * M + m] * bf2f(Xb[(size_t)m * D + d]);
  }
  atomicAdd(&pooled[(size_t)b * D + d], acc / ((float)gcnt[b] + 512.f));
}

// ---------------- final-stage kernels ----------------

__global__ __launch_bounds__(256) void k_xg(const unsigned short* __restrict__ xp,
                                            const int* __restrict__ gcnt,
                                            unsigned short* __restrict__ xgb) {
  int b = blockIdx.x;
  int d = blockIdx.y * 256 + threadIdx.x;
  int nb = gcnt[b];
  float inv = 1.0f / (float)(nb > 1 ? nb : 1);
  const unsigned short* Xb = xp + (size_t)b * M * D;
  float s = 0.f;
  for (int m = 0; m < M; ++m) s += bf2f(Xb[(size_t)m * D + d]);
  xgb[(size_t)b * D + d] = f2bf(s * inv);
}

__global__ __launch_bounds__(256) void k_atom(const unsigned short* __restrict__ xgb,
                                              const unsigned short* __restrict__ AwPk,
                                              float* __restrict__ gpre) {
  int tid = threadIdx.x;
  int w = tid >> 6, lane = tid & 63;
  int q = lane >> 4, t = lane & 15;
  int nbase = blockIdx.x * 64 + w * 16;
  int pb = nbase >> 4;
  f32x4 acc[2];
  acc[0] = (f32x4){0.f, 0.f, 0.f, 0.f};
  acc[1] = (f32x4){0.f, 0.f, 0.f, 0.f};
  for (int kk = 0; kk < 24; ++kk) {
    bf16x8 a0 = *(const bf16x8*)(xgb + (size_t)t * D + kk * 32 + q * 8);
    bf16x8 a1 = *(const bf16x8*)(xgb + (size_t)(16 + t) * D + kk * 32 + q * 8);
    bf16x8 bv = *(const bf16x8*)(AwPk + (((size_t)(pb * 24 + kk)) << 9) + (lane << 3));
    acc[0] = mfma16(a0, bv, acc[0]);
    acc[1] = mfma16(a1, bv, acc[1]);
  }
#pragma unroll
  for (int mi = 0; mi < 2; ++mi)
#pragma unroll
    for (int r = 0; r < 4; ++r) {
      int row = mi * 16 + q * 4 + r;
      gpre[(size_t)row * D + nbase + t] = acc[mi][r];
    }
}

__global__ __launch_bounds__(256) void k_final(
    const unsigned short* __restrict__ Tpk, const float* __restrict__ gpre,
    const float* __restrict__ pooled, const void* __restrict__ ab,
    const void* __restrict__ dmask, const void* __restrict__ gmask,
    const void* __restrict__ remb, const int* __restrict__ flags,
    void* __restrict__ out) {
  int f = flags[0];
  int b = blockIdx.x, tid = threadIdx.x;
  float dm = ldf(dmask, b, f);
  float gm = ldf(gmask, b, f);
  float dg = dm * gm;
  size_t base = (size_t)b * 2304;
#pragma unroll
  for (int j = 0; j < 3; ++j) {
    int d = tid + j * 256;
    float z = ldf(remb, d, f);
    float tv = pk_read(Tpk, b * 32, 0, d);
    float o0 = tv * dm + (1.f - dm) * z;
    float gv = tanhf(gpre[(size_t)b * D + d] + ldf(ab, d, f));
    float o1 = gv * gm + (1.f - gm) * z;
    float p = pooled[(size_t)b * D + d] * (1.f / 3.f);
    float o2 = p * dg + (1.f - dg) * z;
    if (f) {
      float* of = (float*)out;
      of[base + d] = o0; of[base + 768 + d] = o1; of[base + 1536 + d] = o2;
    } else {
      unsigned short* ob = (unsigned short*)out;
      ob[base + d] = f2bf(o0); ob[base + 768 + d] = f2bf(o1); ob[base + 1536 + d] = f2bf(o2);
    }
  }
}

extern "C" void kernel_launch(void* const* d_in, const int* in_sizes, int n_in,
                              void* d_out, int out_size, void* d_ws, size_t ws_size,
                              hipStream_t stream) {
  const void* x_in  = d_in[0];
  const void* text  = d_in[1];
  const void* dmask = d_in[2];
  const void* gmask = d_in[3];
  const void* gws   = d_in[4];
  const void* gwn   = d_in[5];
  const void* gb    = d_in[6];
  const void* aw    = d_in[7];
  const void* ab    = d_in[8];
  const void* remb  = d_in[9];
  const void* batch = d_in[10];
  const void* pidx  = d_in[11];
  const void* esrc  = d_in[13];
  const void* edst  = d_in[14];

  char* wsp = (char*)d_ws;
  size_t off = 0;
  auto carve = [&](size_t bytes) -> void* {
    void* p = wsp + off;
    off += (bytes + 255) & ~(size_t)255;
    return p;
  };
  int* flags = (int*)carve(2 * 4);
  unsigned short* x0    = (unsigned short*)carve((size_t)NNODES * D * 2);
  unsigned short* xA    = (unsigned short*)carve((size_t)NNODES * D * 2);
  unsigned short* xB    = (unsigned short*)carve((size_t)NNODES * D * 2);
  unsigned short* PkA   = (unsigned short*)carve((size_t)NNODES * D * 2);
  unsigned short* PkB   = (unsigned short*)carve((size_t)NNODES * D * 2);
  unsigned short* Mpk   = (unsigned short*)carve((size_t)NNODES * D * 2);
  unsigned short* Tpk   = (unsigned short*)carve((size_t)B * L * D * 2);
  unsigned short* WsT   = (unsigned short*)carve((size_t)3 * D * D * 2);
  unsigned short* WnT   = (unsigned short*)carve((size_t)3 * D * D * 2);
  unsigned short* AwT   = (unsigned short*)carve((size_t)D * D * 2);
  unsigned short* WsPk  = (unsigned short*)carve((size_t)3 * D * D * 2);
  unsigned short* WnPk  = (unsigned short*)carve((size_t)3 * D * D * 2);
  unsigned short* AwPk  = (unsigned short*)carve((size_t)D * D * 2);
  unsigned short* xp    = (unsigned short*)carve((size_t)B * M * D * 2);
  unsigned short* XpPk  = (unsigned short*)carve((size_t)B * M * D * 2);
  unsigned short* xgb   = (unsigned short*)carve((size_t)B * D * 2);
  float* gpre    = (float*)carve((size_t)B * D * 4);
  float* S       = (float*)carve((size_t)B * M * L * 4);
  float* rmax    = (float*)carve((size_t)B * M * 4);
  float* rsum    = (float*)carve((size_t)B * M * 4);
  float* wv      = (float*)carve((size_t)B * L * 4);
  float* cmaxv   = (float*)carve((size_t)B * L * 4);
  float* csumv   = (float*)carve((size_t)B * L * 4);
  float* t2gcol  = (float*)carve((size_t)B * M * 4);
  float* pooled  = (float*)carve((size_t)B * D * 4);
  int* cnt      = (int*)carve((size_t)NNODES * 4);
  int* rowstart = (int*)carve((size_t)(NNODES + 1) * 4);
  int* cursor   = (int*)carve((size_t)NNODES * 4);
  int* gcnt     = (int*)carve((size_t)B * 4);
  int* csr      = (int*)carve((size_t)NEDGES * 4);

  k_detect<<<1, 256, 0, stream>>>((const unsigned short*)text, (const unsigned int*)edst, flags);
  k_init<<<96, 256, 0, stream>>>(cnt, cursor, gcnt, pooled);
  k_cvt_pack<<<NNODES / 16, 256, 0, stream>>>(x_in, x0, PkA, flags);
  k_pack<<<B * L / 16, 256, 0, stream>>>(text, Tpk, flags, 1);
  k_transpose<<<dim3(24, 24, 7), dim3(32, 8), 0, stream>>>(gws, gwn, aw, flags, WsT, WnT, AwT);
  k_packw<<<dim3(48, 7), 256, 0, stream>>>(WsT, WnT, AwT, WsPk, WnPk, AwPk);
  k_count<<<96, 256, 0, stream>>>(edst, batch, flags, cnt, gcnt);
  k_scan<<<1, 1024, 0, stream>>>(cnt, rowstart);
  k_scatter<<<96, 256, 0, stream>>>(esrc, edst, flags, rowstart, cursor, csr);

  const unsigned short* xsrc = x0;        // rows for msg gather
  const unsigned short* Apk = PkA;        // packed A for gemm
  unsigned short* Y[3]   = {xA, xB, xA};
  unsigned short* Npk[3] = {PkB, PkA, nullptr};
  for (int i = 0; i < 3; ++i) {
    k_msg_pack<<<NNODES / 16, 256, 0, stream>>>(xsrc, cnt, rowstart, csr, Mpk);
    k_gemm_gnn<<<dim3(48, 12), 256, 0, stream>>>(Apk, Mpk, WsPk + (size_t)i * D * D,
                                                 WnPk + (size_t)i * D * D, gb, (size_t)i * D,
                                                 flags, Y[i]);
    if (i < 2) k_pack<<<NNODES / 16, 256, 0, stream>>>(Y[i], Npk[i], flags, 0);
    k_xp_pack<<<B * M / 16, 256, 0, stream>>>(Y[i], pidx, flags, gcnt, xp, XpPk);
    k_scores<<<dim3(2, 8, B), 256, 0, stream>>>(XpPk, Tpk, S);
    k_rowstat<<<B * M, 256, 0, stream>>>(S, rmax, rsum);
    k_colstat<<<dim3(B, 8), 256, 0, stream>>>(S, rmax, rsum, gcnt, wv, cmaxv, csumv);
    k_colsum<<<B * M, 256, 0, stream>>>(S, cmaxv, csumv, gcnt, t2gcol);
    k_pooled<<<dim3(B, 3, 10), 256, 0, stream>>>(wv, t2gcol, Tpk, xp, gcnt, pooled);
    xsrc = Y[i];
    Apk = Npk[i];
  }
  k_xg<<<dim3(B, 3), 256, 0, stream>>>(xp, gcnt, xgb);
  k_atom<<<12, 256, 0, stream>>>(xgb, AwPk, gpre);
  k_final<<<B, 256, 0, stream>>>(Tpk, gpre, pooled, ab, dmask, gmask, remb, flags, d_out);
}

// Round 9
// 487.497 us; speedup vs baseline: 1.2662x; 1.0629x over previous
//
#include <hip/hip_runtime.h>

#define D 768
#define B 32
#define L 512
#define M 128
#define NNODES 3072
#define NEDGES 24576

using bf16x8 = __attribute__((ext_vector_type(8))) short;
using f32x4  = __attribute__((ext_vector_type(4))) float;

__device__ __forceinline__ float bf2f(unsigned short u) {
  union { unsigned int i; float f; } v; v.i = ((unsigned int)u) << 16; return v.f;
}
__device__ __forceinline__ unsigned short f2bf(float f) {
  union { float f; unsigned int i; } v; v.f = f;
  unsigned int x = v.i;
  return (unsigned short)((x + 0x7FFFu + ((x >> 16) & 1u)) >> 16);
}
__device__ __forceinline__ float ldf(const void* p, size_t i, int f32) {
  return f32 ? ((const float*)p)[i] : bf2f(((const unsigned short*)p)[i]);
}
__device__ __forceinline__ int ldi(const void* p, size_t i, int w64) {
  return w64 ? (int)((const long long*)p)[i] : ((const int*)p)[i];
}
__device__ __forceinline__ f32x4 mfma16(bf16x8 a, bf16x8 b, f32x4 c) {
  return __builtin_amdgcn_mfma_f32_16x16x32_bf16(a, b, c, 0, 0, 0);
}
__device__ __forceinline__ void gl_lds(const unsigned short* gsrc, unsigned short* lbase,
                                       int lane) {
  __builtin_amdgcn_global_load_lds(
      (const __attribute__((address_space(1))) unsigned int*)(gsrc + lane * 8),
      (__attribute__((address_space(3))) unsigned int*)lbase, 16, 0, 0);
}

// Packed fragment layout for row-major [R x 768] bf16:
//   (row,k) -> panel p=row/16, kk=k/32, lane=((k%32)/8)*16+row%16, e=k%8
__device__ __forceinline__ float pk_read(const unsigned short* P, int p, int l, int d) {
  return bf2f(P[(((size_t)(p * 24 + (d >> 5))) << 9) + ((((d & 31) >> 3) << 4) + l) * 8 + (d & 7)]);
}

// ---------------- setup kernels ----------------

// init + (block 0) dtype detection
__global__ void k_init(int* cnt, int* cursor, int* gcnt, float* pooled,
                       const unsigned short* __restrict__ t,
                       const unsigned int* __restrict__ e, int* __restrict__ flags) {
  int i = blockIdx.x * 256 + threadIdx.x;
  if (i < NNODES) { cnt[i] = 0; cursor[i] = 0; }
  if (i < B) gcnt[i] = 0;
  if (i < B * D) pooled[i] = 0.f;
  if (blockIdx.x == 0) {
    __shared__ int r0[256];
    __shared__ unsigned r1[256];
    int tid = threadIdx.x;
    int bad = 0;
    for (int j = tid; j < 8192; j += 256) {
      unsigned short u = t[2 * j];
      unsigned ex = (u >> 7) & 0xFF;
      if (ex >= 0xC0) bad = 1;
    }
    unsigned o = 0;
    for (int j = tid; j < NEDGES / 2; j += 256) o |= e[2 * j + 1];
    r0[tid] = bad; r1[tid] = o;
    __syncthreads();
    for (int s = 128; s > 0; s >>= 1) {
      if (tid < s) { r0[tid] |= r0[tid + s]; r1[tid] |= r1[tid + s]; }
      __syncthreads();
    }
    if (tid == 0) { flags[0] = r0[0]; flags[1] = (r1[0] == 0) ? 1 : 0; }
  }
}

// x_in -> rows(x0)+packed(PkA), and text -> packed(Tpk), one dispatch
__global__ __launch_bounds__(256) void k_pack_in(
    const void* __restrict__ x_in, unsigned short* __restrict__ x0,
    unsigned short* __restrict__ PkA, const void* __restrict__ text,
    unsigned short* __restrict__ Tpk, const int* __restrict__ flags) {
  __shared__ unsigned short buf[12288];
  int f = flags[0];
  int bid = blockIdx.x, tid = threadIdx.x;
  const void* src; unsigned short* dst; unsigned short* rows; int p;
  if (bid < NNODES / 16) { src = x_in; dst = PkA; rows = x0; p = bid; }
  else                   { src = text; dst = Tpk; rows = nullptr; p = bid - NNODES / 16; }
#pragma unroll
  for (int j = 0; j < 6; ++j) {
    int idx = j * 256 + tid;
    int r = idx / 96, c = idx % 96;
    size_t sbase = (size_t)(p * 16 + r) * 768 + c * 8;
    union { unsigned short v[8]; uint4 q; } u;
    if (f) {
      const float* sp = (const float*)src + sbase;
#pragma unroll
      for (int e = 0; e < 8; ++e) u.v[e] = f2bf(sp[e]);
    } else {
      const unsigned short* sp = (const unsigned short*)src + sbase;
#pragma unroll
      for (int e = 0; e < 8; ++e) u.v[e] = sp[e];
    }
    if (rows) *(uint4*)&rows[sbase] = u.q;
    int lpos = (c >> 2) * 64 + (c & 3) * 16 + r;
#pragma unroll
    for (int e = 0; e < 8; ++e) buf[lpos * 8 + e] = u.v[e];
  }
  __syncthreads();
  uint4* d4 = (uint4*)(dst + (size_t)p * 12288);
  const uint4* b4 = (const uint4*)buf;
#pragma unroll
  for (int j = 0; j < 6; ++j) d4[j * 256 + tid] = b4[j * 256 + tid];
}

// pack row-major bf16 panels (for Y between layers)
__global__ __launch_bounds__(256) void k_pack(const unsigned short* __restrict__ src,
                                              unsigned short* __restrict__ dst) {
  __shared__ unsigned short buf[12288];
  int p = blockIdx.x, tid = threadIdx.x;
#pragma unroll
  for (int j = 0; j < 6; ++j) {
    int idx = j * 256 + tid;
    int r = idx / 96, c = idx % 96;
    size_t sbase = (size_t)(p * 16 + r) * 768 + c * 8;
    uint4 q = *(const uint4*)(src + sbase);
    int lpos = (c >> 2) * 64 + (c & 3) * 16 + r;
    *(uint4*)&buf[lpos * 8] = q;
  }
  __syncthreads();
  uint4* d4 = (uint4*)(dst + (size_t)p * 12288);
  const uint4* b4 = (const uint4*)buf;
#pragma unroll
  for (int j = 0; j < 6; ++j) d4[j * 256 + tid] = b4[j * 256 + tid];
}

__global__ void k_count(const void* __restrict__ edst, const void* __restrict__ batch,
                        const int* __restrict__ flags, int* __restrict__ cnt,
                        int* __restrict__ gcnt) {
  int w = flags[1];
  int i = blockIdx.x * 256 + threadIdx.x;
  if (i < NEDGES) atomicAdd(&cnt[ldi(edst, i, w)], 1);
  if (i < NNODES) atomicAdd(&gcnt[ldi(batch, i, w)], 1);
}

__global__ void k_scan(const int* __restrict__ cnt, int* __restrict__ rowstart) {
  __shared__ int a[NNODES], b[NNODES];
  int tid = threadIdx.x;
  for (int i = tid; i < NNODES; i += 1024) a[i] = cnt[i];
  __syncthreads();
  int* s = a; int* d = b;
  for (int off = 1; off < NNODES; off <<= 1) {
    for (int i = tid; i < NNODES; i += 1024)
      d[i] = s[i] + (i >= off ? s[i - off] : 0);
    __syncthreads();
    int* t = s; s = d; d = t;
  }
  for (int i = tid; i < NNODES; i += 1024) rowstart[i + 1] = s[i];
  if (tid == 0) rowstart[0] = 0;
}

__global__ void k_scatter(const void* __restrict__ esrc, const void* __restrict__ edst,
                          const int* __restrict__ flags, const int* __restrict__ rowstart,
                          int* __restrict__ cursor, int* __restrict__ csr) {
  int w = flags[1];
  int i = blockIdx.x * 256 + threadIdx.x;
  if (i < NEDGES) {
    int dd = ldi(edst, i, w);
    int pos = atomicAdd(&cursor[dd], 1);
    csr[rowstart[dd] + pos] = ldi(esrc, i, w);
  }
}

__global__ void k_transpose(const void* __restrict__ Ws, const void* __restrict__ Wn,
                            const void* __restrict__ Aw, const int* __restrict__ flags,
                            unsigned short* __restrict__ WsT,
                            unsigned short* __restrict__ WnT,
                            unsigned short* __restrict__ AwT) {
  __shared__ unsigned short tile[32][33];
  int f = flags[0];
  int z = blockIdx.z;
  const void* src; unsigned short* dst; size_t zoff;
  if (z < 3)      { src = Ws; zoff = (size_t)z * D * D;       dst = WsT + zoff; }
  else if (z < 6) { src = Wn; zoff = (size_t)(z - 3) * D * D; dst = WnT + zoff; }
  else            { src = Aw; zoff = 0;                       dst = AwT; }
  int k0 = blockIdx.x * 32, n0 = blockIdx.y * 32;
  int tx = threadIdx.x, ty = threadIdx.y;
#pragma unroll
  for (int j = 0; j < 4; ++j)
    tile[ty + j * 8][tx] = f2bf(ldf(src, zoff + (size_t)(k0 + ty + j * 8) * D + n0 + tx, f));
  __syncthreads();
#pragma unroll
  for (int j = 0; j < 4; ++j)
    dst[(size_t)(n0 + ty + j * 8) * D + k0 + tx] = tile[tx][ty + j * 8];
}

__global__ __launch_bounds__(256) void k_packw(
    const unsigned short* __restrict__ WsT, const unsigned short* __restrict__ WnT,
    const unsigned short* __restrict__ AwT, unsigned short* __restrict__ WsPk,
    unsigned short* __restrict__ WnPk, unsigned short* __restrict__ AwPk) {
  __shared__ unsigned short buf[12288];
  int z = blockIdx.y;
  const unsigned short* src; unsigned short* dst;
  if (z < 3)      { src = WsT + (size_t)z * D * D;       dst = WsPk + (size_t)z * D * D; }
  else if (z < 6) { src = WnT + (size_t)(z - 3) * D * D; dst = WnPk + (size_t)(z - 3) * D * D; }
  else            { src = AwT;                           dst = AwPk; }
  int p = blockIdx.x, tid = threadIdx.x;
#pragma unroll
  for (int j = 0; j < 6; ++j) {
    int idx = j * 256 + tid;
    int r = idx / 96, c = idx % 96;
    size_t sbase = (size_t)(p * 16 + r) * 768 + c * 8;
    uint4 q = *(const uint4*)(src + sbase);
    int lpos = (c >> 2) * 64 + (c & 3) * 16 + r;
    *(uint4*)&buf[lpos * 8] = q;
  }
  __syncthreads();
  uint4* d4 = (uint4*)(dst + (size_t)p * 12288);
  const uint4* b4 = (const uint4*)buf;
#pragma unroll
  for (int j = 0; j < 6; ++j) d4[j * 256 + tid] = b4[j * 256 + tid];
}

// ---------------- per-layer kernels ----------------

__global__ __launch_bounds__(256) void k_msg_pack(
    const unsigned short* __restrict__ x, const int* __restrict__ cnt,
    const int* __restrict__ rowstart, const int* __restrict__ csr,
    unsigned short* __restrict__ Mpk) {
  __shared__ unsigned short buf[12288];
  int p = blockIdx.x, tid = threadIdx.x;
  int w = tid >> 6, lane = tid & 63;
#pragma unroll
  for (int i = 0; i < 4; ++i) {
    int r = w * 4 + i;
    int n = p * 16 + r;
    int deg = cnt[n], base = rowstart[n];
    float inv = 1.0f / (float)(deg > 1 ? deg : 1);
    float a[12];
#pragma unroll
    for (int j = 0; j < 12; ++j) a[j] = 0.f;
    for (int e = 0; e < deg; ++e) {
      const uint2* xr = (const uint2*)(x + (size_t)csr[base + e] * D);
#pragma unroll
      for (int j = 0; j < 3; ++j) {
        uint2 v = xr[lane + j * 64];
        a[j * 4 + 0] += bf2f((unsigned short)(v.x & 0xFFFFu));
        a[j * 4 + 1] += bf2f((unsigned short)(v.x >> 16));
        a[j * 4 + 2] += bf2f((unsigned short)(v.y & 0xFFFFu));
        a[j * 4 + 3] += bf2f((unsigned short)(v.y >> 16));
      }
    }
#pragma unroll
    for (int j = 0; j < 3; ++j) {
      int d0 = (lane + j * 64) * 4;
      int c = d0 >> 3, e0 = d0 & 7;
      int lpos = (c >> 2) * 64 + (c & 3) * 16 + r;
      unsigned short* bp = &buf[lpos * 8 + e0];
      bp[0] = f2bf(a[j * 4 + 0] * inv);
      bp[1] = f2bf(a[j * 4 + 1] * inv);
      bp[2] = f2bf(a[j * 4 + 2] * inv);
      bp[3] = f2bf(a[j * 4 + 3] * inv);
    }
  }
  __syncthreads();
  uint4* d4 = (uint4*)(Mpk + (size_t)p * 12288);
  const uint4* b4 = (const uint4*)buf;
#pragma unroll
  for (int j = 0; j < 6; ++j) d4[j * 256 + tid] = b4[j * 256 + tid];
}

// Y = relu([X|MSG]@[Ws;Wn]^T + b); LDS-staged, 2 K-steps per barrier round
__global__ __launch_bounds__(256) void k_gemm_gnn(
    const unsigned short* __restrict__ Xpk, const unsigned short* __restrict__ Mpk,
    const unsigned short* __restrict__ WsPk, const unsigned short* __restrict__ WnPk,
    const void* __restrict__ bias, size_t bias_off, const int* __restrict__ flags,
    unsigned short* __restrict__ Y) {
  __shared__ __align__(16) unsigned short lds[2][4096];   // 2 x 8 chunks x 1KB
  int f = flags[0];
  int tid = threadIdx.x;
  int wave = tid >> 6, lane = tid & 63;
  int q = lane >> 4, t = lane & 15;
  int wm = wave >> 1, wn = wave & 1;
  int pa = blockIdx.x * 4, pb = blockIdx.y * 4;
  f32x4 acc[2][2];
#pragma unroll
  for (int mi = 0; mi < 2; ++mi)
#pragma unroll
    for (int ni = 0; ni < 2; ++ni)
      acc[mi][ni] = (f32x4){0.f, 0.f, 0.f, 0.f};

  int c0 = wave * 2;
  for (int r = 0; r < 24; ++r) {
    int s0 = r * 2;                 // steps s0, s0+1; never straddle 24
    int h = (s0 < 24) ? 0 : 1;
    int kk0 = s0 - h * 24;
    const unsigned short* P = (wave < 2) ? (h ? Mpk : Xpk) : (h ? WnPk : WsPk);
    int pan0 = (wave < 2) ? (pa + c0) : (pb + c0 - 4);
    gl_lds(P + (((size_t)(pan0 * 24 + kk0)) << 9), &lds[0][c0 * 512], lane);
    gl_lds(P + (((size_t)((pan0 + 1) * 24 + kk0)) << 9), &lds[0][(c0 + 1) * 512], lane);
    gl_lds(P + (((size_t)(pan0 * 24 + kk0 + 1)) << 9), &lds[1][c0 * 512], lane);
    gl_lds(P + (((size_t)((pan0 + 1) * 24 + kk0 + 1)) << 9), &lds[1][(c0 + 1) * 512], lane);
    __syncthreads();
#pragma unroll
    for (int st = 0; st < 2; ++st) {
      bf16x8 a0 = *(const bf16x8*)&lds[st][(wm * 2 + 0) * 512 + lane * 8];
      bf16x8 a1 = *(const bf16x8*)&lds[st][(wm * 2 + 1) * 512 + lane * 8];
      bf16x8 b0 = *(const bf16x8*)&lds[st][(4 + wn * 2 + 0) * 512 + lane * 8];
      bf16x8 b1 = *(const bf16x8*)&lds[st][(4 + wn * 2 + 1) * 512 + lane * 8];
      acc[0][0] = mfma16(a0, b0, acc[0][0]);
      acc[0][1] = mfma16(a0, b1, acc[0][1]);
      acc[1][0] = mfma16(a1, b0, acc[1][0]);
      acc[1][1] = mfma16(a1, b1, acc[1][1]);
    }
    __syncthreads();
  }

#pragma unroll
  for (int ni = 0; ni < 2; ++ni) {
    int col = blockIdx.y * 64 + wn * 32 + ni * 16 + t;
    float bv = ldf(bias, bias_off + col, f);
#pragma unroll
    for (int mi = 0; mi < 2; ++mi) {
#pragma unroll
      for (int r = 0; r < 4; ++r) {
        int row = blockIdx.x * 64 + wm * 32 + mi * 16 + q * 4 + r;
        float v = acc[mi][ni][r] + bv;
        Y[(size_t)row * D + col] = f2bf(v > 0.f ? v : 0.f);
      }
    }
  }
}

// gather xp rows per panel; emits rows AND packed
__global__ __launch_bounds__(256) void k_xp_pack(
    const unsigned short* __restrict__ Xn, const void* __restrict__ pidx,
    const int* __restrict__ flags, const int* __restrict__ gcnt,
    unsigned short* __restrict__ xp, unsigned short* __restrict__ XpPk) {
  __shared__ unsigned short rows[16 * 776];
  int p = blockIdx.x, tid = threadIdx.x;
  int w64 = flags[1];
  int r = tid >> 4, c16 = tid & 15;
  int bm = p * 16 + r;
  int b = bm >> 7, m = bm & 127;
  int nb = gcnt[b];
  uint4* dl = (uint4*)&rows[r * 776];
  if (m < nb) {
    const uint4* srcr = (const uint4*)(Xn + (size_t)ldi(pidx, bm, w64) * D);
#pragma unroll
    for (int j = 0; j < 6; ++j) dl[c16 + j * 16] = srcr[c16 + j * 16];
  } else {
    uint4 z = {0u, 0u, 0u, 0u};
#pragma unroll
    for (int j = 0; j < 6; ++j) dl[c16 + j * 16] = z;
  }
  __syncthreads();
#pragma unroll
  for (int j = 0; j < 6; ++j) {
    int idx = j * 256 + tid;
    int rr = idx / 96, cc = idx % 96;
    uint4 vv = *(const uint4*)&rows[rr * 776 + cc * 8];
    *(uint4*)&xp[(size_t)(p * 16 + rr) * D + cc * 8] = vv;
  }
  unsigned short* pb = XpPk + (size_t)p * 12288;
#pragma unroll
  for (int j = 0; j < 6; ++j) {
    int odx = j * 256 + tid;
    int kk = odx >> 6, lanep = odx & 63;
    int rr = lanep & 15, cg = lanep >> 4;
    int cc = kk * 4 + cg;
    uint4 vv = *(const uint4*)&rows[rr * 776 + cc * 8];
    *(uint4*)&pb[odx * 8] = vv;
  }
}

// S[b] = xp[b] @ text[b]^T; LDS-staged, 2 K-steps per round; grid (2,8,B)
__global__ __launch_bounds__(256) void k_scores(
    const unsigned short* __restrict__ XpPk, const unsigned short* __restrict__ Tpk,
    float* __restrict__ S) {
  __shared__ __align__(16) unsigned short lds[2][4096];
  int b = blockIdx.z;
  int tid = threadIdx.x;
  int wave = tid >> 6, lane = tid & 63;
  int q = lane >> 4, t = lane & 15;
  int wm = wave >> 1, wn = wave & 1;
  int pa = b * 8 + blockIdx.x * 4;
  int pb = b * 32 + blockIdx.y * 4;
  f32x4 acc[2][2];
#pragma unroll
  for (int mi = 0; mi < 2; ++mi)
#pragma unroll
    for (int ni = 0; ni < 2; ++ni)
      acc[mi][ni] = (f32x4){0.f, 0.f, 0.f, 0.f};

  int c0 = wave * 2;
  const unsigned short* P = (wave < 2) ? XpPk : Tpk;
  int pan0 = (wave < 2) ? (pa + c0) : (pb + c0 - 4);
  for (int r = 0; r < 12; ++r) {
    int s0 = r * 2;
    gl_lds(P + (((size_t)(pan0 * 24 + s0)) << 9), &lds[0][c0 * 512], lane);
    gl_lds(P + (((size_t)((pan0 + 1) * 24 + s0)) << 9), &lds[0][(c0 + 1) * 512], lane);
    gl_lds(P + (((size_t)(pan0 * 24 + s0 + 1)) << 9), &lds[1][c0 * 512], lane);
    gl_lds(P + (((size_t)((pan0 + 1) * 24 + s0 + 1)) << 9), &lds[1][(c0 + 1) * 512], lane);
    __syncthreads();
#pragma unroll
    for (int st = 0; st < 2; ++st) {
      bf16x8 a0 = *(const bf16x8*)&lds[st][(wm * 2 + 0) * 512 + lane * 8];
      bf16x8 a1 = *(const bf16x8*)&lds[st][(wm * 2 + 1) * 512 + lane * 8];
      bf16x8 b0 = *(const bf16x8*)&lds[st][(4 + wn * 2 + 0) * 512 + lane * 8];
      bf16x8 b1 = *(const bf16x8*)&lds[st][(4 + wn * 2 + 1) * 512 + lane * 8];
      acc[0][0] = mfma16(a0, b0, acc[0][0]);
      acc[0][1] = mfma16(a0, b1, acc[0][1]);
      acc[1][0] = mfma16(a1, b0, acc[1][0]);
      acc[1][1] = mfma16(a1, b1, acc[1][1]);
    }
    __syncthreads();
  }

  float* Sb = S + (size_t)b * M * L;
#pragma unroll
  for (int ni = 0; ni < 2; ++ni) {
    int col = blockIdx.y * 64 + wn * 32 + ni * 16 + t;
#pragma unroll
    for (int mi = 0; mi < 2; ++mi) {
#pragma unroll
      for (int r = 0; r < 4; ++r) {
        int row = blockIdx.x * 64 + wm * 32 + mi * 16 + q * 4 + r;
        Sb[(size_t)row * L + col] = acc[mi][ni][r];
      }
    }
  }
}

// rowstat (blocks 0..4095) + col max/sum (blocks 4096..4351), one dispatch
__global__ __launch_bounds__(256) void k_stats(
    const float* __restrict__ S, const int* __restrict__ gcnt,
    float* __restrict__ rmax, float* __restrict__ rsum,
    float* __restrict__ cmaxv, float* __restrict__ csumv) {
  int bid = blockIdx.x, tid = threadIdx.x;
  if (bid < B * M) {
    __shared__ float red[4];
    int lane = tid & 63, wv = tid >> 6;
    const float* r = S + (size_t)bid * L;
    float s0 = r[tid], s1 = r[tid + 256];
    float m = fmaxf(s0, s1);
#pragma unroll
    for (int o = 32; o > 0; o >>= 1) m = fmaxf(m, __shfl_down(m, o));
    if (lane == 0) red[wv] = m;
    __syncthreads();
    float bm = fmaxf(fmaxf(red[0], red[1]), fmaxf(red[2], red[3]));
    __syncthreads();
    float e = __expf(s0 - bm) + __expf(s1 - bm);
#pragma unroll
    for (int o = 32; o > 0; o >>= 1) e += __shfl_down(e, o);
    if (lane == 0) red[wv] = e;
    __syncthreads();
    if (tid == 0) { rmax[bid] = bm; rsum[bid] = red[0] + red[1] + red[2] + red[3]; }
  } else {
    __shared__ float pm[4][64], ps[4][64];
    int cid = bid - B * M;
    int b = cid >> 3, ly = cid & 7;
    int w = tid >> 6, lane = tid & 63;
    int l = ly * 64 + lane;
    int nb = gcnt[b];
    const float* Sb = S + (size_t)b * M * L;
    int m0 = w * 32, m1 = min(m0 + 32, nb);
    float cm = -1e30f, cs = 0.f;
    for (int m = m0; m < m1; ++m) {
      float s = Sb[(size_t)m * L + l];
      if (s > cm) { cs = cs * __expf(cm - s) + 1.f; cm = s; }
      else cs += __expf(s - cm);
    }
    pm[w][lane] = cm; ps[w][lane] = cs;
    __syncthreads();
    if (w == 0) {
      float CM = -1e30f;
#pragma unroll
      for (int j = 0; j < 4; ++j) CM = fmaxf(CM, pm[j][lane]);
      float CS = 0.f;
#pragma unroll
      for (int j = 0; j < 4; ++j) CS += ps[j][lane] * __expf(pm[j][lane] - CM);
      cmaxv[b * L + l] = CM; csumv[b * L + l] = CS;
    }
  }
}

// wv (blocks 0..255, needs rmax/rsum) + t2gcol (blocks 256.., needs cmax/csum)
__global__ __launch_bounds__(256) void k_cross(
    const float* __restrict__ S, const float* __restrict__ rmax,
    const float* __restrict__ rsum, const float* __restrict__ cmaxv,
    const float* __restrict__ csumv, const int* __restrict__ gcnt,
    float* __restrict__ wv, float* __restrict__ t2gcol) {
  int bid = blockIdx.x, tid = threadIdx.x;
  if (bid < 256) {
    __shared__ float rm[M], ri[M];
    __shared__ float pw[4][64];
    int b = bid >> 3, ly = bid & 7;
    int w = tid >> 6, lane = tid & 63;
    if (tid < M) { rm[tid] = rmax[b * M + tid]; ri[tid] = 1.f / rsum[b * M + tid]; }
    __syncthreads();
    int l = ly * 64 + lane;
    int nb = gcnt[b];
    const float* Sb = S + (size_t)b * M * L;
    int m0 = w * 32, m1 = min(m0 + 32, nb);
    float wp = 0.f;
    for (int m = m0; m < m1; ++m)
      wp += __expf(Sb[(size_t)m * L + l] - rm[m]) * ri[m];
    pw[w][lane] = wp;
    __syncthreads();
    if (w == 0)
      wv[b * L + l] = pw[0][lane] + pw[1][lane] + pw[2][lane] + pw[3][lane];
  } else {
    __shared__ float red[4];
    int bm = bid - 256;
    int b = bm >> 7, m = bm & 127;
    int lane = tid & 63, w = tid >> 6;
    int nb = gcnt[b];
    float acc = 0.f;
    if (m < nb) {
      const float* r = S + (size_t)bm * L;
      const float* cm = cmaxv + b * L;
      const float* cs = csumv + b * L;
      acc = __expf(r[tid] - cm[tid]) / cs[tid]
          + __expf(r[tid + 256] - cm[tid + 256]) / cs[tid + 256];
    }
#pragma unroll
    for (int o = 32; o > 0; o >>= 1) acc += __shfl_down(acc, o);
    if (lane == 0) red[w] = acc;
    __syncthreads();
    if (tid == 0) t2gcol[bm] = red[0] + red[1] + red[2] + red[3];
  }
}

__global__ __launch_bounds__(256) void k_pooled(
    const float* __restrict__ wv, const float* __restrict__ t2gcol,
    const unsigned short* __restrict__ Tpk, const unsigned short* __restrict__ xp,
    const int* __restrict__ gcnt, float* __restrict__ pooled) {
  int b = blockIdx.x;
  int d = blockIdx.y * 256 + threadIdx.x;
  int c = blockIdx.z;
  float acc = 0.f;
  if (c < 8) {
    int l0 = c * 64;
    for (int l = l0; l < l0 + 64; ++l) {
      int p = b * 32 + (l >> 4);
      acc += wv[b * L + l] * pk_read(Tpk, p, l & 15, d);
    }
  } else {
    const unsigned short* Xb = xp + (size_t)b * M * D;
    int mm0 = (c - 8) * 64;
    for (int m = mm0; m < mm0 + 64; ++m) acc += t2gcol[b * M + m] * bf2f(Xb[(size_t)m * D + d]);
  }
  atomicAdd(&pooled[(size_t)b * D + d], acc / ((float)gcnt[b] + 512.f));
}

// ---------------- final-stage kernels ----------------

__global__ __launch_bounds__(256) void k_xg(const unsigned short* __restrict__ xp,
                                            const int* __restrict__ gcnt,
                                            unsigned short* __restrict__ xgb) {
  int b = blockIdx.x;
  int d = blockIdx.y * 256 + threadIdx.x;
  int nb = gcnt[b];
  float inv = 1.0f / (float)(nb > 1 ? nb : 1);
  const unsigned short* Xb = xp + (size_t)b * M * D;
  float s = 0.f;
  for (int m = 0; m < M; ++m) s += bf2f(Xb[(size_t)m * D + d]);
  xgb[(size_t)b * D + d] = f2bf(s * inv);
}

__global__ __launch_bounds__(256) void k_atom(const unsigned short* __restrict__ xgb,
                                              const unsigned short* __restrict__ AwPk,
                                              float* __restrict__ gpre) {
  int tid = threadIdx.x;
  int w = tid >> 6, lane = tid & 63;
  int q = lane >> 4, t = lane & 15;
  int nbase = blockIdx.x * 64 + w * 16;
  int pb = nbase >> 4;
  f32x4 acc[2];
  acc[0] = (f32x4){0.f, 0.f, 0.f, 0.f};
  acc[1] = (f32x4){0.f, 0.f, 0.f, 0.f};
  for (int kk = 0; kk < 24; ++kk) {
    bf16x8 a0 = *(const bf16x8*)(xgb + (size_t)t * D + kk * 32 + q * 8);
    bf16x8 a1 = *(const bf16x8*)(xgb + (size_t)(16 + t) * D + kk * 32 + q * 8);
    bf16x8 bv = *(const bf16x8*)(AwPk + (((size_t)(pb * 24 + kk)) << 9) + (lane << 3));
    acc[0] = mfma16(a0, bv, acc[0]);
    acc[1] = mfma16(a1, bv, acc[1]);
  }
#pragma unroll
  for (int mi = 0; mi < 2; ++mi)
#pragma unroll
    for (int r = 0; r < 4; ++r) {
      int row = mi * 16 + q * 4 + r;
      gpre[(size_t)row * D + nbase + t] = acc[mi][r];
    }
}

__global__ __launch_bounds__(256) void k_final(
    const unsigned short* __restrict__ Tpk, const float* __restrict__ gpre,
    const float* __restrict__ pooled, const void* __restrict__ ab,
    const void* __restrict__ dmask, const void* __restrict__ gmask,
    const void* __restrict__ remb, const int* __restrict__ flags,
    void* __restrict__ out) {
  int f = flags[0];
  int b = blockIdx.x, tid = threadIdx.x;
  float dm = ldf(dmask, b, f);
  float gm = ldf(gmask, b, f);
  float dg = dm * gm;
  size_t base = (size_t)b * 2304;
#pragma unroll
  for (int j = 0; j < 3; ++j) {
    int d = tid + j * 256;
    float z = ldf(remb, d, f);
    float tv = pk_read(Tpk, b * 32, 0, d);
    float o0 = tv * dm + (1.f - dm) * z;
    float gv = tanhf(gpre[(size_t)b * D + d] + ldf(ab, d, f));
    float o1 = gv * gm + (1.f - gm) * z;
    float p = pooled[(size_t)b * D + d] * (1.f / 3.f);
    float o2 = p * dg + (1.f - dg) * z;
    if (f) {
      float* of = (float*)out;
      of[base + d] = o0; of[base + 768 + d] = o1; of[base + 1536 + d] = o2;
    } else {
      unsigned short* ob = (unsigned short*)out;
      ob[base + d] = f2bf(o0); ob[base + 768 + d] = f2bf(o1); ob[base + 1536 + d] = f2bf(o2);
    }
  }
}

extern "C" void kernel_launch(void* const* d_in, const int* in_sizes, int n_in,
                              void* d_out, int out_size, void* d_ws, size_t ws_size,
                              hipStream_t stream) {
  const void* x_in  = d_in[0];
  const void* text  = d_in[1];
  const void* dmask = d_in[2];
  const void* gmask = d_in[3];
  const void* gws   = d_in[4];
  const void* gwn   = d_in[5];
  const void* gb    = d_in[6];
  const void* aw    = d_in[7];
  const void* ab    = d_in[8];
  const void* remb  = d_in[9];
  const void* batch = d_in[10];
  const void* pidx  = d_in[11];
  const void* esrc  = d_in[13];
  const void* edst  = d_in[14];

  char* wsp = (char*)d_ws;
  size_t off = 0;
  auto carve = [&](size_t bytes) -> void* {
    void* p = wsp + off;
    off += (bytes + 255) & ~(size_t)255;
    return p;
  };
  int* flags = (int*)carve(2 * 4);
  unsigned short* x0    = (unsigned short*)carve((size_t)NNODES * D * 2);
  unsigned short* xA    = (unsigned short*)carve((size_t)NNODES * D * 2);
  unsigned short* xB    = (unsigned short*)carve((size_t)NNODES * D * 2);
  unsigned short* PkA   = (unsigned short*)carve((size_t)NNODES * D * 2);
  unsigned short* PkB   = (unsigned short*)carve((size_t)NNODES * D * 2);
  unsigned short* Mpk   = (unsigned short*)carve((size_t)NNODES * D * 2);
  unsigned short* Tpk   = (unsigned short*)carve((size_t)B * L * D * 2);
  unsigned short* WsT   = (unsigned short*)carve((size_t)3 * D * D * 2);
  unsigned short* WnT   = (unsigned short*)carve((size_t)3 * D * D * 2);
  unsigned short* AwT   = (unsigned short*)carve((size_t)D * D * 2);
  unsigned short* WsPk  = (unsigned short*)carve((size_t)3 * D * D * 2);
  unsigned short* WnPk  = (unsigned short*)carve((size_t)3 * D * D * 2);
  unsigned short* AwPk  = (unsigned short*)carve((size_t)D * D * 2);
  unsigned short* xp    = (unsigned short*)carve((size_t)B * M * D * 2);
  unsigned short* XpPk  = (unsigned short*)carve((size_t)B * M * D * 2);
  unsigned short* xgb   = (unsigned short*)carve((size_t)B * D * 2);
  float* gpre    = (float*)carve((size_t)B * D * 4);
  float* S       = (float*)carve((size_t)B * M * L * 4);
  float* rmax    = (float*)carve((size_t)B * M * 4);
  float* rsum    = (float*)carve((size_t)B * M * 4);
  float* wv      = (float*)carve((size_t)B * L * 4);
  float* cmaxv   = (float*)carve((size_t)B * L * 4);
  float* csumv   = (float*)carve((size_t)B * L * 4);
  float* t2gcol  = (float*)carve((size_t)B * M * 4);
  float* pooled  = (float*)carve((size_t)B * D * 4);
  int* cnt      = (int*)carve((size_t)NNODES * 4);
  int* rowstart = (int*)carve((size_t)(NNODES + 1) * 4);
  int* cursor   = (int*)carve((size_t)NNODES * 4);
  int* gcnt     = (int*)carve((size_t)B * 4);
  int* csr      = (int*)carve((size_t)NEDGES * 4);

  k_init<<<96, 256, 0, stream>>>(cnt, cursor, gcnt, pooled,
                                 (const unsigned short*)text, (const unsigned int*)edst, flags);
  k_pack_in<<<NNODES / 16 + B * L / 16, 256, 0, stream>>>(x_in, x0, PkA, text, Tpk, flags);
  k_transpose<<<dim3(24, 24, 7), dim3(32, 8), 0, stream>>>(gws, gwn, aw, flags, WsT, WnT, AwT);
  k_packw<<<dim3(48, 7), 256, 0, stream>>>(WsT, WnT, AwT, WsPk, WnPk, AwPk);
  k_count<<<96, 256, 0, stream>>>(edst, batch, flags, cnt, gcnt);
  k_scan<<<1, 1024, 0, stream>>>(cnt, rowstart);
  k_scatter<<<96, 256, 0, stream>>>(esrc, edst, flags, rowstart, cursor, csr);

  const unsigned short* xsrc = x0;
  const unsigned short* Apk = PkA;
  unsigned short* Y[3]   = {xA, xB, xA};
  unsigned short* Npk[3] = {PkB, PkA, nullptr};
  for (int i = 0; i < 3; ++i) {
    k_msg_pack<<<NNODES / 16, 256, 0, stream>>>(xsrc, cnt, rowstart, csr, Mpk);
    k_gemm_gnn<<<dim3(48, 12), 256, 0, stream>>>(Apk, Mpk, WsPk + (size_t)i * D * D,
                                                 WnPk + (size_t)i * D * D, gb, (size_t)i * D,
                                                 flags, Y[i]);
    if (i < 2) k_pack<<<NNODES / 16, 256, 0, stream>>>(Y[i], Npk[i]);
    k_xp_pack<<<B * M / 16, 256, 0, stream>>>(Y[i], pidx, flags, gcnt, xp, XpPk);
    k_scores<<<dim3(2, 8, B), 256, 0, stream>>>(XpPk, Tpk, S);
    k_stats<<<B * M + 256, 256, 0, stream>>>(S, gcnt, rmax, rsum, cmaxv, csumv);
    k_cross<<<256 + B * M, 256, 0, stream>>>(S, rmax, rsum, cmaxv, csumv, gcnt, wv, t2gcol);
    k_pooled<<<dim3(B, 3, 10), 256, 0, stream>>>(wv, t2gcol, Tpk, xp, gcnt, pooled);
    xsrc = Y[i];
    Apk = Npk[i];
  }
  k_xg<<<dim3(B, 3), 256, 0, stream>>>(xp, gcnt, xgb);
  k_atom<<<12, 256, 0, stream>>>(xgb, AwPk, gpre);
  k_final<<<B, 256, 0, stream>>>(Tpk, gpre, pooled, ab, dmask, gmask, remb, flags, d_out);
}

// Round 10
// 471.248 us; speedup vs baseline: 1.3099x; 1.0345x over previous
//
#include <hip/hip_runtime.h>

#define D 768
#define B 32
#define L 512
#define M 128
#define NNODES 3072
#define NEDGES 24576

using bf16x8 = __attribute__((ext_vector_type(8))) short;
using f32x4  = __attribute__((ext_vector_type(4))) float;

__device__ __forceinline__ float bf2f(unsigned short u) {
  union { unsigned int i; float f; } v; v.i = ((unsigned int)u) << 16; return v.f;
}
__device__ __forceinline__ unsigned short f2bf(float f) {
  union { float f; unsigned int i; } v; v.f = f;
  unsigned int x = v.i;
  return (unsigned short)((x + 0x7FFFu + ((x >> 16) & 1u)) >> 16);
}
__device__ __forceinline__ float ldf(const void* p, size_t i, int f32) {
  return f32 ? ((const float*)p)[i] : bf2f(((const unsigned short*)p)[i]);
}
__device__ __forceinline__ int ldi(const void* p, size_t i, int w64) {
  return w64 ? (int)((const long long*)p)[i] : ((const int*)p)[i];
}
__device__ __forceinline__ f32x4 mfma16(bf16x8 a, bf16x8 b, f32x4 c) {
  return __builtin_amdgcn_mfma_f32_16x16x32_bf16(a, b, c, 0, 0, 0);
}
__device__ __forceinline__ void gl_lds(const unsigned short* gsrc, unsigned short* lbase,
                                       int lane) {
  __builtin_amdgcn_global_load_lds(
      (const __attribute__((address_space(1))) unsigned int*)(gsrc + lane * 8),
      (__attribute__((address_space(3))) unsigned int*)lbase, 16, 0, 0);
}

// Packed fragment layout for row-major [R x 768] bf16:
//   (row,k) -> panel p=row/16, kk=k/32, lane=((k%32)/8)*16+row%16, e=k%8
__device__ __forceinline__ float pk_read(const unsigned short* P, int p, int l, int d) {
  return bf2f(P[(((size_t)(p * 24 + (d >> 5))) << 9) + ((((d & 31) >> 3) << 4) + l) * 8 + (d & 7)]);
}

// ---------------- setup kernels ----------------

// init + (block 0) dtype detection
__global__ void k_init(int* cnt, int* cursor, int* gcnt, float* pooled, float* xgacc,
                       const unsigned short* __restrict__ t,
                       const unsigned int* __restrict__ e, int* __restrict__ flags) {
  int i = blockIdx.x * 256 + threadIdx.x;
  if (i < NNODES) { cnt[i] = 0; cursor[i] = 0; }
  if (i < B) gcnt[i] = 0;
  if (i < B * D) { pooled[i] = 0.f; xgacc[i] = 0.f; }
  if (blockIdx.x == 0) {
    __shared__ int r0[256];
    __shared__ unsigned r1[256];
    int tid = threadIdx.x;
    int bad = 0;
    for (int j = tid; j < 8192; j += 256) {
      unsigned short u = t[2 * j];
      unsigned ex = (u >> 7) & 0xFF;
      if (ex >= 0xC0) bad = 1;
    }
    unsigned o = 0;
    for (int j = tid; j < NEDGES / 2; j += 256) o |= e[2 * j + 1];
    r0[tid] = bad; r1[tid] = o;
    __syncthreads();
    for (int s = 128; s > 0; s >>= 1) {
      if (tid < s) { r0[tid] |= r0[tid + s]; r1[tid] |= r1[tid + s]; }
      __syncthreads();
    }
    if (tid == 0) { flags[0] = r0[0]; flags[1] = (r1[0] == 0) ? 1 : 0; }
  }
}

// x_in -> rows(x0)+packed(PkA), and text -> packed(Tpk), one dispatch
__global__ __launch_bounds__(256) void k_pack_in(
    const void* __restrict__ x_in, unsigned short* __restrict__ x0,
    unsigned short* __restrict__ PkA, const void* __restrict__ text,
    unsigned short* __restrict__ Tpk, const int* __restrict__ flags) {
  __shared__ unsigned short buf[12288];
  int f = flags[0];
  int bid = blockIdx.x, tid = threadIdx.x;
  const void* src; unsigned short* dst; unsigned short* rows; int p;
  if (bid < NNODES / 16) { src = x_in; dst = PkA; rows = x0; p = bid; }
  else                   { src = text; dst = Tpk; rows = nullptr; p = bid - NNODES / 16; }
#pragma unroll
  for (int j = 0; j < 6; ++j) {
    int idx = j * 256 + tid;
    int r = idx / 96, c = idx % 96;
    size_t sbase = (size_t)(p * 16 + r) * 768 + c * 8;
    union { unsigned short v[8]; uint4 q; } u;
    if (f) {
      const float* sp = (const float*)src + sbase;
#pragma unroll
      for (int e = 0; e < 8; ++e) u.v[e] = f2bf(sp[e]);
    } else {
      const unsigned short* sp = (const unsigned short*)src + sbase;
#pragma unroll
      for (int e = 0; e < 8; ++e) u.v[e] = sp[e];
    }
    if (rows) *(uint4*)&rows[sbase] = u.q;
    int lpos = (c >> 2) * 64 + (c & 3) * 16 + r;
#pragma unroll
    for (int e = 0; e < 8; ++e) buf[lpos * 8 + e] = u.v[e];
  }
  __syncthreads();
  uint4* d4 = (uint4*)(dst + (size_t)p * 12288);
  const uint4* b4 = (const uint4*)buf;
#pragma unroll
  for (int j = 0; j < 6; ++j) d4[j * 256 + tid] = b4[j * 256 + tid];
}

// pack row-major bf16 panels (for Y between layers)
__global__ __launch_bounds__(256) void k_pack(const unsigned short* __restrict__ src,
                                              unsigned short* __restrict__ dst) {
  __shared__ unsigned short buf[12288];
  int p = blockIdx.x, tid = threadIdx.x;
#pragma unroll
  for (int j = 0; j < 6; ++j) {
    int idx = j * 256 + tid;
    int r = idx / 96, c = idx % 96;
    size_t sbase = (size_t)(p * 16 + r) * 768 + c * 8;
    uint4 q = *(const uint4*)(src + sbase);
    int lpos = (c >> 2) * 64 + (c & 3) * 16 + r;
    *(uint4*)&buf[lpos * 8] = q;
  }
  __syncthreads();
  uint4* d4 = (uint4*)(dst + (size_t)p * 12288);
  const uint4* b4 = (const uint4*)buf;
#pragma unroll
  for (int j = 0; j < 6; ++j) d4[j * 256 + tid] = b4[j * 256 + tid];
}

// fused transpose+pack of weights, direct from raw inputs.
// grid (12 nblk, 24 ktile, 7 z): tile = W[k0..k0+32][n0..n0+64] -> 4 packed chunks
__global__ __launch_bounds__(256) void k_wpack(
    const void* __restrict__ Ws, const void* __restrict__ Wn, const void* __restrict__ Aw,
    const int* __restrict__ flags, unsigned short* __restrict__ WsPk,
    unsigned short* __restrict__ WnPk, unsigned short* __restrict__ AwPk) {
  __shared__ unsigned short buf[2048];   // 4 chunks x 1KB
  int f = flags[0];
  int z = blockIdx.z;
  const void* src; unsigned short* dst; size_t zoff;
  if (z < 3)      { src = Ws; zoff = (size_t)z * D * D;       dst = WsPk + zoff; }
  else if (z < 6) { src = Wn; zoff = (size_t)(z - 3) * D * D; dst = WnPk + zoff; }
  else            { src = Aw; zoff = 0;                       dst = AwPk; }
  int n0 = blockIdx.x * 64, kk = blockIdx.y;
  int tid = threadIdx.x;
  int kl = tid >> 3, c8 = tid & 7;        // k local 0..31, 8-col chunk 0..7
  size_t sbase = zoff + (size_t)(kk * 32 + kl) * D + n0 + c8 * 8;
  unsigned short v[8];
  if (f) {
    const float* sp = (const float*)src + sbase;
#pragma unroll
    for (int e = 0; e < 8; ++e) v[e] = f2bf(sp[e]);
  } else {
    const unsigned short* sp = (const unsigned short*)src + sbase;
#pragma unroll
    for (int e = 0; e < 8; ++e) v[e] = sp[e];
  }
  // element (k=kk*32+kl, n=n0+c8*8+i): panel pl=(c8*8+i)/16, lane=(kl/8)*16+(n%16), e=kl%8
  int ebit = kl & 7, quad = kl >> 3;
#pragma unroll
  for (int i = 0; i < 8; ++i) {
    int nl = c8 * 8 + i;
    int pl = nl >> 4;
    int lane = quad * 16 + (nl & 15);
    buf[pl * 512 + lane * 8 + ebit] = v[i];
  }
  __syncthreads();
  int pl = tid >> 6, pos = tid & 63;
  int pG = blockIdx.x * 4 + pl;
  uint4 q = *(const uint4*)&buf[pl * 512 + pos * 8];
  *(uint4*)&dst[(((size_t)(pG * 24 + kk)) << 9) + pos * 8] = q;
}

__global__ void k_count(const void* __restrict__ edst, const void* __restrict__ batch,
                        const int* __restrict__ flags, int* __restrict__ cnt,
                        int* __restrict__ gcnt) {
  int w = flags[1];
  int i = blockIdx.x * 256 + threadIdx.x;
  if (i < NEDGES) atomicAdd(&cnt[ldi(edst, i, w)], 1);
  if (i < NNODES) atomicAdd(&gcnt[ldi(batch, i, w)], 1);
}

__global__ void k_scan(const int* __restrict__ cnt, int* __restrict__ rowstart) {
  __shared__ int a[NNODES], b[NNODES];
  int tid = threadIdx.x;
  for (int i = tid; i < NNODES; i += 1024) a[i] = cnt[i];
  __syncthreads();
  int* s = a; int* d = b;
  for (int off = 1; off < NNODES; off <<= 1) {
    for (int i = tid; i < NNODES; i += 1024)
      d[i] = s[i] + (i >= off ? s[i - off] : 0);
    __syncthreads();
    int* t = s; s = d; d = t;
  }
  for (int i = tid; i < NNODES; i += 1024) rowstart[i + 1] = s[i];
  if (tid == 0) rowstart[0] = 0;
}

__global__ void k_scatter(const void* __restrict__ esrc, const void* __restrict__ edst,
                          const int* __restrict__ flags, const int* __restrict__ rowstart,
                          int* __restrict__ cursor, int* __restrict__ csr) {
  int w = flags[1];
  int i = blockIdx.x * 256 + threadIdx.x;
  if (i < NEDGES) {
    int dd = ldi(edst, i, w);
    int pos = atomicAdd(&cursor[dd], 1);
    csr[rowstart[dd] + pos] = ldi(esrc, i, w);
  }
}

// ---------------- per-layer kernels ----------------

__global__ __launch_bounds__(256) void k_msg_pack(
    const unsigned short* __restrict__ x, const int* __restrict__ cnt,
    const int* __restrict__ rowstart, const int* __restrict__ csr,
    unsigned short* __restrict__ Mpk) {
  __shared__ unsigned short buf[12288];
  int p = blockIdx.x, tid = threadIdx.x;
  int w = tid >> 6, lane = tid & 63;
#pragma unroll
  for (int i = 0; i < 4; ++i) {
    int r = w * 4 + i;
    int n = p * 16 + r;
    int deg = cnt[n], base = rowstart[n];
    float inv = 1.0f / (float)(deg > 1 ? deg : 1);
    float a[12];
#pragma unroll
    for (int j = 0; j < 12; ++j) a[j] = 0.f;
    for (int e = 0; e < deg; ++e) {
      const uint2* xr = (const uint2*)(x + (size_t)csr[base + e] * D);
#pragma unroll
      for (int j = 0; j < 3; ++j) {
        uint2 v = xr[lane + j * 64];
        a[j * 4 + 0] += bf2f((unsigned short)(v.x & 0xFFFFu));
        a[j * 4 + 1] += bf2f((unsigned short)(v.x >> 16));
        a[j * 4 + 2] += bf2f((unsigned short)(v.y & 0xFFFFu));
        a[j * 4 + 3] += bf2f((unsigned short)(v.y >> 16));
      }
    }
#pragma unroll
    for (int j = 0; j < 3; ++j) {
      int d0 = (lane + j * 64) * 4;
      int c = d0 >> 3, e0 = d0 & 7;
      int lpos = (c >> 2) * 64 + (c & 3) * 16 + r;
      unsigned short* bp = &buf[lpos * 8 + e0];
      bp[0] = f2bf(a[j * 4 + 0] * inv);
      bp[1] = f2bf(a[j * 4 + 1] * inv);
      bp[2] = f2bf(a[j * 4 + 2] * inv);
      bp[3] = f2bf(a[j * 4 + 3] * inv);
    }
  }
  __syncthreads();
  uint4* d4 = (uint4*)(Mpk + (size_t)p * 12288);
  const uint4* b4 = (const uint4*)buf;
#pragma unroll
  for (int j = 0; j < 6; ++j) d4[j * 256 + tid] = b4[j * 256 + tid];
}

// Y = relu([X|MSG]@[Ws;Wn]^T + b); LDS-staged, 6 K-steps per barrier round (8 rounds)
__global__ __launch_bounds__(256) void k_gemm_gnn(
    const unsigned short* __restrict__ Xpk, const unsigned short* __restrict__ Mpk,
    const unsigned short* __restrict__ WsPk, const unsigned short* __restrict__ WnPk,
    const void* __restrict__ bias, size_t bias_off, const int* __restrict__ flags,
    unsigned short* __restrict__ Y) {
  __shared__ __align__(16) unsigned short lds[6 * 4096];   // 48 KB: 6 steps x 8 chunks
  int f = flags[0];
  int tid = threadIdx.x;
  int wave = tid >> 6, lane = tid & 63;
  int q = lane >> 4, t = lane & 15;
  int wm = wave >> 1, wn = wave & 1;
  int pa = blockIdx.x * 4, pb = blockIdx.y * 4;
  f32x4 acc[2][2];
#pragma unroll
  for (int mi = 0; mi < 2; ++mi)
#pragma unroll
    for (int ni = 0; ni < 2; ++ni)
      acc[mi][ni] = (f32x4){0.f, 0.f, 0.f, 0.f};

  int c0 = wave * 2;
  int pan0A = (wave < 2) ? (pa + c0) : (pb + c0 - 4);
  for (int r = 0; r < 8; ++r) {
    int h = r >> 2;                       // rounds 0-3: X/Ws, 4-7: MSG/Wn
    int kk0 = r * 6 - h * 24;
    const unsigned short* P = (wave < 2) ? (h ? Mpk : Xpk) : (h ? WnPk : WsPk);
#pragma unroll
    for (int st = 0; st < 6; ++st) {
      gl_lds(P + (((size_t)(pan0A * 24 + kk0 + st)) << 9), &lds[st * 4096 + c0 * 512], lane);
      gl_lds(P + (((size_t)((pan0A + 1) * 24 + kk0 + st)) << 9), &lds[st * 4096 + (c0 + 1) * 512], lane);
    }
    __syncthreads();
#pragma unroll
    for (int st = 0; st < 6; ++st) {
      bf16x8 a0 = *(const bf16x8*)&lds[st * 4096 + (wm * 2 + 0) * 512 + lane * 8];
      bf16x8 a1 = *(const bf16x8*)&lds[st * 4096 + (wm * 2 + 1) * 512 + lane * 8];
      bf16x8 b0 = *(const bf16x8*)&lds[st * 4096 + (4 + wn * 2 + 0) * 512 + lane * 8];
      bf16x8 b1 = *(const bf16x8*)&lds[st * 4096 + (4 + wn * 2 + 1) * 512 + lane * 8];
      acc[0][0] = mfma16(a0, b0, acc[0][0]);
      acc[0][1] = mfma16(a0, b1, acc[0][1]);
      acc[1][0] = mfma16(a1, b0, acc[1][0]);
      acc[1][1] = mfma16(a1, b1, acc[1][1]);
    }
    __syncthreads();
  }

#pragma unroll
  for (int ni = 0; ni < 2; ++ni) {
    int col = blockIdx.y * 64 + wn * 32 + ni * 16 + t;
    float bv = ldf(bias, bias_off + col, f);
#pragma unroll
    for (int mi = 0; mi < 2; ++mi) {
#pragma unroll
      for (int r = 0; r < 4; ++r) {
        int row = blockIdx.x * 64 + wm * 32 + mi * 16 + q * 4 + r;
        float v = acc[mi][ni][r] + bv;
        Y[(size_t)row * D + col] = f2bf(v > 0.f ? v : 0.f);
      }
    }
  }
}

// gather xp rows per panel; emits rows AND packed; optional xg accumulation (last layer)
__global__ __launch_bounds__(256) void k_xp_pack(
    const unsigned short* __restrict__ Xn, const void* __restrict__ pidx,
    const int* __restrict__ flags, const int* __restrict__ gcnt,
    unsigned short* __restrict__ xp, unsigned short* __restrict__ XpPk,
    float* __restrict__ xgacc) {
  __shared__ unsigned short rows[16 * 776];
  int p = blockIdx.x, tid = threadIdx.x;
  int w64 = flags[1];
  int r = tid >> 4, c16 = tid & 15;
  int bm = p * 16 + r;
  int b = bm >> 7, m = bm & 127;
  int nb = gcnt[b];
  uint4* dl = (uint4*)&rows[r * 776];
  if (m < nb) {
    const uint4* srcr = (const uint4*)(Xn + (size_t)ldi(pidx, bm, w64) * D);
#pragma unroll
    for (int j = 0; j < 6; ++j) dl[c16 + j * 16] = srcr[c16 + j * 16];
  } else {
    uint4 z = {0u, 0u, 0u, 0u};
#pragma unroll
    for (int j = 0; j < 6; ++j) dl[c16 + j * 16] = z;
  }
  __syncthreads();
#pragma unroll
  for (int j = 0; j < 6; ++j) {
    int idx = j * 256 + tid;
    int rr = idx / 96, cc = idx % 96;
    uint4 vv = *(const uint4*)&rows[rr * 776 + cc * 8];
    *(uint4*)&xp[(size_t)(p * 16 + rr) * D + cc * 8] = vv;
  }
  unsigned short* pb = XpPk + (size_t)p * 12288;
#pragma unroll
  for (int j = 0; j < 6; ++j) {
    int odx = j * 256 + tid;
    int kk = odx >> 6, lanep = odx & 63;
    int rr = lanep & 15, cg = lanep >> 4;
    int cc = kk * 4 + cg;
    uint4 vv = *(const uint4*)&rows[rr * 776 + cc * 8];
    *(uint4*)&pb[odx * 8] = vv;
  }
  if (xgacc) {
    int bb = p >> 3;   // 8 panels per batch
#pragma unroll
    for (int j = 0; j < 3; ++j) {
      int d = j * 256 + tid;
      float s = 0.f;
#pragma unroll
      for (int rr = 0; rr < 16; ++rr) s += bf2f(rows[rr * 776 + d]);
      atomicAdd(&xgacc[(size_t)bb * D + d], s);
    }
  }
}

// S[b] = xp[b] @ text[b]^T; LDS-staged, 6 K-steps per round (4 rounds); grid (2,8,B)
__global__ __launch_bounds__(256) void k_scores(
    const unsigned short* __restrict__ XpPk, const unsigned short* __restrict__ Tpk,
    float* __restrict__ S) {
  __shared__ __align__(16) unsigned short lds[6 * 4096];
  int b = blockIdx.z;
  int tid = threadIdx.x;
  int wave = tid >> 6, lane = tid & 63;
  int q = lane >> 4, t = lane & 15;
  int wm = wave >> 1, wn = wave & 1;
  int pa = b * 8 + blockIdx.x * 4;
  int pb = b * 32 + blockIdx.y * 4;
  f32x4 acc[2][2];
#pragma unroll
  for (int mi = 0; mi < 2; ++mi)
#pragma unroll
    for (int ni = 0; ni < 2; ++ni)
      acc[mi][ni] = (f32x4){0.f, 0.f, 0.f, 0.f};

  int c0 = wave * 2;
  const unsigned short* P = (wave < 2) ? XpPk : Tpk;
  int pan0 = (wave < 2) ? (pa + c0) : (pb + c0 - 4);
  for (int r = 0; r < 4; ++r) {
    int kk0 = r * 6;
#pragma unroll
    for (int st = 0; st < 6; ++st) {
      gl_lds(P + (((size_t)(pan0 * 24 + kk0 + st)) << 9), &lds[st * 4096 + c0 * 512], lane);
      gl_lds(P + (((size_t)((pan0 + 1) * 24 + kk0 + st)) << 9), &lds[st * 4096 + (c0 + 1) * 512], lane);
    }
    __syncthreads();
#pragma unroll
    for (int st = 0; st < 6; ++st) {
      bf16x8 a0 = *(const bf16x8*)&lds[st * 4096 + (wm * 2 + 0) * 512 + lane * 8];
      bf16x8 a1 = *(const bf16x8*)&lds[st * 4096 + (wm * 2 + 1) * 512 + lane * 8];
      bf16x8 b0 = *(const bf16x8*)&lds[st * 4096 + (4 + wn * 2 + 0) * 512 + lane * 8];
      bf16x8 b1 = *(const bf16x8*)&lds[st * 4096 + (4 + wn * 2 + 1) * 512 + lane * 8];
      acc[0][0] = mfma16(a0, b0, acc[0][0]);
      acc[0][1] = mfma16(a0, b1, acc[0][1]);
      acc[1][0] = mfma16(a1, b0, acc[1][0]);
      acc[1][1] = mfma16(a1, b1, acc[1][1]);
    }
    __syncthreads();
  }

  float* Sb = S + (size_t)b * M * L;
#pragma unroll
  for (int ni = 0; ni < 2; ++ni) {
    int col = blockIdx.y * 64 + wn * 32 + ni * 16 + t;
#pragma unroll
    for (int mi = 0; mi < 2; ++mi) {
#pragma unroll
      for (int r = 0; r < 4; ++r) {
        int row = blockIdx.x * 64 + wm * 32 + mi * 16 + q * 4 + r;
        Sb[(size_t)row * L + col] = acc[mi][ni][r];
      }
    }
  }
}

// rowstat (blocks 0..4095) + col max/sum (blocks 4096..4351)
__global__ __launch_bounds__(256) void k_stats(
    const float* __restrict__ S, const int* __restrict__ gcnt,
    float* __restrict__ rmax, float* __restrict__ rsum,
    float* __restrict__ cmaxv, float* __restrict__ csumv) {
  int bid = blockIdx.x, tid = threadIdx.x;
  if (bid < B * M) {
    __shared__ float red[4];
    int lane = tid & 63, wv = tid >> 6;
    const float* r = S + (size_t)bid * L;
    float s0 = r[tid], s1 = r[tid + 256];
    float m = fmaxf(s0, s1);
#pragma unroll
    for (int o = 32; o > 0; o >>= 1) m = fmaxf(m, __shfl_down(m, o));
    if (lane == 0) red[wv] = m;
    __syncthreads();
    float bm = fmaxf(fmaxf(red[0], red[1]), fmaxf(red[2], red[3]));
    __syncthreads();
    float e = __expf(s0 - bm) + __expf(s1 - bm);
#pragma unroll
    for (int o = 32; o > 0; o >>= 1) e += __shfl_down(e, o);
    if (lane == 0) red[wv] = e;
    __syncthreads();
    if (tid == 0) { rmax[bid] = bm; rsum[bid] = red[0] + red[1] + red[2] + red[3]; }
  } else {
    __shared__ float pm[4][64], ps[4][64];
    int cid = bid - B * M;
    int b = cid >> 3, ly = cid & 7;
    int w = tid >> 6, lane = tid & 63;
    int l = ly * 64 + lane;
    int nb = gcnt[b];
    const float* Sb = S + (size_t)b * M * L;
    int m0 = w * 32, m1 = min(m0 + 32, nb);
    float cm = -1e30f, cs = 0.f;
    for (int m = m0; m < m1; ++m) {
      float s = Sb[(size_t)m * L + l];
      if (s > cm) { cs = cs * __expf(cm - s) + 1.f; cm = s; }
      else cs += __expf(s - cm);
    }
    pm[w][lane] = cm; ps[w][lane] = cs;
    __syncthreads();
    if (w == 0) {
      float CM = -1e30f;
#pragma unroll
      for (int j = 0; j < 4; ++j) CM = fmaxf(CM, pm[j][lane]);
      float CS = 0.f;
#pragma unroll
      for (int j = 0; j < 4; ++j) CS += ps[j][lane] * __expf(pm[j][lane] - CM);
      cmaxv[b * L + l] = CM; csumv[b * L + l] = CS;
    }
  }
}

// wv (blocks 0..255) + t2gcol (blocks 256..)
__global__ __launch_bounds__(256) void k_cross(
    const float* __restrict__ S, const float* __restrict__ rmax,
    const float* __restrict__ rsum, const float* __restrict__ cmaxv,
    const float* __restrict__ csumv, const int* __restrict__ gcnt,
    float* __restrict__ wv, float* __restrict__ t2gcol) {
  int bid = blockIdx.x, tid = threadIdx.x;
  if (bid < 256) {
    __shared__ float rm[M], ri[M];
    __shared__ float pw[4][64];
    int b = bid >> 3, ly = bid & 7;
    int w = tid >> 6, lane = tid & 63;
    if (tid < M) { rm[tid] = rmax[b * M + tid]; ri[tid] = 1.f / rsum[b * M + tid]; }
    __syncthreads();
    int l = ly * 64 + lane;
    int nb = gcnt[b];
    const float* Sb = S + (size_t)b * M * L;
    int m0 = w * 32, m1 = min(m0 + 32, nb);
    float wp = 0.f;
    for (int m = m0; m < m1; ++m)
      wp += __expf(Sb[(size_t)m * L + l] - rm[m]) * ri[m];
    pw[w][lane] = wp;
    __syncthreads();
    if (w == 0)
      wv[b * L + l] = pw[0][lane] + pw[1][lane] + pw[2][lane] + pw[3][lane];
  } else {
    __shared__ float red[4];
    int bm = bid - 256;
    int b = bm >> 7, m = bm & 127;
    int lane = tid & 63, w = tid >> 6;
    int nb = gcnt[b];
    float acc = 0.f;
    if (m < nb) {
      const float* r = S + (size_t)bm * L;
      const float* cm = cmaxv + b * L;
      const float* cs = csumv + b * L;
      acc = __expf(r[tid] - cm[tid]) / cs[tid]
          + __expf(r[tid + 256] - cm[tid + 256]) / cs[tid + 256];
    }
#pragma unroll
    for (int o = 32; o > 0; o >>= 1) acc += __shfl_down(acc, o);
    if (lane == 0) red[w] = acc;
    __syncthreads();
    if (tid == 0) t2gcol[bm] = red[0] + red[1] + red[2] + red[3];
  }
}

__global__ __launch_bounds__(256) void k_pooled(
    const float* __restrict__ wv, const float* __restrict__ t2gcol,
    const unsigned short* __restrict__ Tpk, const unsigned short* __restrict__ xp,
    const int* __restrict__ gcnt, float* __restrict__ pooled) {
  int b = blockIdx.x;
  int d = blockIdx.y * 256 + threadIdx.x;
  int c = blockIdx.z;
  float acc = 0.f;
  if (c < 8) {
    int l0 = c * 64;
    for (int l = l0; l < l0 + 64; ++l) {
      int p = b * 32 + (l >> 4);
      acc += wv[b * L + l] * pk_read(Tpk, p, l & 15, d);
    }
  } else {
    const unsigned short* Xb = xp + (size_t)b * M * D;
    int mm0 = (c - 8) * 64;
    for (int m = mm0; m < mm0 + 64; ++m) acc += t2gcol[b * M + m] * bf2f(Xb[(size_t)m * D + d]);
  }
  atomicAdd(&pooled[(size_t)b * D + d], acc / ((float)gcnt[b] + 512.f));
}

// ---------------- final-stage kernels ----------------

// gpre = xg @ atom_w; A from fp32 xgacc (divide by node count, convert inline)
__global__ __launch_bounds__(256) void k_atom(const float* __restrict__ xgacc,
                                              const int* __restrict__ gcnt,
                                              const unsigned short* __restrict__ AwPk,
                                              float* __restrict__ gpre) {
  int tid = threadIdx.x;
  int w = tid >> 6, lane = tid & 63;
  int q = lane >> 4, t = lane & 15;
  int nbase = blockIdx.x * 64 + w * 16;
  int pb = nbase >> 4;
  int n0 = gcnt[t], n1 = gcnt[16 + t];
  float inv0 = 1.f / (float)(n0 > 1 ? n0 : 1);
  float inv1 = 1.f / (float)(n1 > 1 ? n1 : 1);
  f32x4 acc[2];
  acc[0] = (f32x4){0.f, 0.f, 0.f, 0.f};
  acc[1] = (f32x4){0.f, 0.f, 0.f, 0.f};
  for (int kk = 0; kk < 24; ++kk) {
    const float* s0 = xgacc + (size_t)t * D + kk * 32 + q * 8;
    const float* s1 = xgacc + (size_t)(16 + t) * D + kk * 32 + q * 8;
    union { unsigned short v[8]; bf16x8 f; } a0, a1;
#pragma unroll
    for (int j = 0; j < 8; ++j) { a0.v[j] = f2bf(s0[j] * inv0); a1.v[j] = f2bf(s1[j] * inv1); }
    bf16x8 bv = *(const bf16x8*)(AwPk + (((size_t)(pb * 24 + kk)) << 9) + (lane << 3));
    acc[0] = mfma16(a0.f, bv, acc[0]);
    acc[1] = mfma16(a1.f, bv, acc[1]);
  }
#pragma unroll
  for (int mi = 0; mi < 2; ++mi)
#pragma unroll
    for (int r = 0; r < 4; ++r) {
      int row = mi * 16 + q * 4 + r;
      gpre[(size_t)row * D + nbase + t] = acc[mi][r];
    }
}

__global__ __launch_bounds__(256) void k_final(
    const unsigned short* __restrict__ Tpk, const float* __restrict__ gpre,
    const float* __restrict__ pooled, const void* __restrict__ ab,
    const void* __restrict__ dmask, const void* __restrict__ gmask,
    const void* __restrict__ remb, const int* __restrict__ flags,
    void* __restrict__ out) {
  int f = flags[0];
  int b = blockIdx.x, tid = threadIdx.x;
  float dm = ldf(dmask, b, f);
  float gm = ldf(gmask, b, f);
  float dg = dm * gm;
  size_t base = (size_t)b * 2304;
#pragma unroll
  for (int j = 0; j < 3; ++j) {
    int d = tid + j * 256;
    float z = ldf(remb, d, f);
    float tv = pk_read(Tpk, b * 32, 0, d);
    float o0 = tv * dm + (1.f - dm) * z;
    float gv = tanhf(gpre[(size_t)b * D + d] + ldf(ab, d, f));
    float o1 = gv * gm + (1.f - gm) * z;
    float p = pooled[(size_t)b * D + d] * (1.f / 3.f);
    float o2 = p * dg + (1.f - dg) * z;
    if (f) {
      float* of = (float*)out;
      of[base + d] = o0; of[base + 768 + d] = o1; of[base + 1536 + d] = o2;
    } else {
      unsigned short* ob = (unsigned short*)out;
      ob[base + d] = f2bf(o0); ob[base + 768 + d] = f2bf(o1); ob[base + 1536 + d] = f2bf(o2);
    }
  }
}

extern "C" void kernel_launch(void* const* d_in, const int* in_sizes, int n_in,
                              void* d_out, int out_size, void* d_ws, size_t ws_size,
                              hipStream_t stream) {
  const void* x_in  = d_in[0];
  const void* text  = d_in[1];
  const void* dmask = d_in[2];
  const void* gmask = d_in[3];
  const void* gws   = d_in[4];
  const void* gwn   = d_in[5];
  const void* gb    = d_in[6];
  const void* aw    = d_in[7];
  const void* ab    = d_in[8];
  const void* remb  = d_in[9];
  const void* batch = d_in[10];
  const void* pidx  = d_in[11];
  const void* esrc  = d_in[13];
  const void* edst  = d_in[14];

  char* wsp = (char*)d_ws;
  size_t off = 0;
  auto carve = [&](size_t bytes) -> void* {
    void* p = wsp + off;
    off += (bytes + 255) & ~(size_t)255;
    return p;
  };
  int* flags = (int*)carve(2 * 4);
  unsigned short* x0    = (unsigned short*)carve((size_t)NNODES * D * 2);
  unsigned short* xA    = (unsigned short*)carve((size_t)NNODES * D * 2);
  unsigned short* xB    = (unsigned short*)carve((size_t)NNODES * D * 2);
  unsigned short* PkA   = (unsigned short*)carve((size_t)NNODES * D * 2);
  unsigned short* PkB   = (unsigned short*)carve((size_t)NNODES * D * 2);
  unsigned short* Mpk   = (unsigned short*)carve((size_t)NNODES * D * 2);
  unsigned short* Tpk   = (unsigned short*)carve((size_t)B * L * D * 2);
  unsigned short* WsPk  = (unsigned short*)carve((size_t)3 * D * D * 2);
  unsigned short* WnPk  = (unsigned short*)carve((size_t)3 * D * D * 2);
  unsigned short* AwPk  = (unsigned short*)carve((size_t)D * D * 2);
  unsigned short* xp    = (unsigned short*)carve((size_t)B * M * D * 2);
  unsigned short* XpPk  = (unsigned short*)carve((size_t)B * M * D * 2);
  float* xgacc   = (float*)carve((size_t)B * D * 4);
  float* gpre    = (float*)carve((size_t)B * D * 4);
  float* S       = (float*)carve((size_t)B * M * L * 4);
  float* rmax    = (float*)carve((size_t)B * M * 4);
  float* rsum    = (float*)carve((size_t)B * M * 4);
  float* wv      = (float*)carve((size_t)B * L * 4);
  float* cmaxv   = (float*)carve((size_t)B * L * 4);
  float* csumv   = (float*)carve((size_t)B * L * 4);
  float* t2gcol  = (float*)carve((size_t)B * M * 4);
  float* pooled  = (float*)carve((size_t)B * D * 4);
  int* cnt      = (int*)carve((size_t)NNODES * 4);
  int* rowstart = (int*)carve((size_t)(NNODES + 1) * 4);
  int* cursor   = (int*)carve((size_t)NNODES * 4);
  int* gcnt     = (int*)carve((size_t)B * 4);
  int* csr      = (int*)carve((size_t)NEDGES * 4);

  k_init<<<96, 256, 0, stream>>>(cnt, cursor, gcnt, pooled, xgacc,
                                 (const unsigned short*)text, (const unsigned int*)edst, flags);
  k_pack_in<<<NNODES / 16 + B * L / 16, 256, 0, stream>>>(x_in, x0, PkA, text, Tpk, flags);
  k_wpack<<<dim3(12, 24, 7), 256, 0, stream>>>(gws, gwn, aw, flags, WsPk, WnPk, AwPk);
  k_count<<<96, 256, 0, stream>>>(edst, batch, flags, cnt, gcnt);
  k_scan<<<1, 1024, 0, stream>>>(cnt, rowstart);
  k_scatter<<<96, 256, 0, stream>>>(esrc, edst, flags, rowstart, cursor, csr);

  const unsigned short* xsrc = x0;
  const unsigned short* Apk = PkA;
  unsigned short* Y[3]   = {xA, xB, xA};
  unsigned short* Npk[3] = {PkB, PkA, nullptr};
  for (int i = 0; i < 3; ++i) {
    k_msg_pack<<<NNODES / 16, 256, 0, stream>>>(xsrc, cnt, rowstart, csr, Mpk);
    k_gemm_gnn<<<dim3(48, 12), 256, 0, stream>>>(Apk, Mpk, WsPk + (size_t)i * D * D,
                                                 WnPk + (size_t)i * D * D, gb, (size_t)i * D,
                                                 flags, Y[i]);
    if (i < 2) k_pack<<<NNODES / 16, 256, 0, stream>>>(Y[i], Npk[i]);
    k_xp_pack<<<B * M / 16, 256, 0, stream>>>(Y[i], pidx, flags, gcnt, xp, XpPk,
                                              (i == 2) ? xgacc : nullptr);
    k_scores<<<dim3(2, 8, B), 256, 0, stream>>>(XpPk, Tpk, S);
    k_stats<<<B * M + 256, 256, 0, stream>>>(S, gcnt, rmax, rsum, cmaxv, csumv);
    k_cross<<<256 + B * M, 256, 0, stream>>>(S, rmax, rsum, cmaxv, csumv, gcnt, wv, t2gcol);
    k_pooled<<<dim3(B, 3, 10), 256, 0, stream>>>(wv, t2gcol, Tpk, xp, gcnt, pooled);
    xsrc = Y[i];
    Apk = Npk[i];
  }
  k_atom<<<12, 256, 0, stream>>>(xgacc, gcnt, AwPk, gpre);
  k_final<<<B, 256, 0, stream>>>(Tpk, gpre, pooled, ab, dmask, gmask, remb, flags, d_out);
}

// Round 11
// 454.640 us; speedup vs baseline: 1.3577x; 1.0365x over previous
//
#include <hip/hip_runtime.h>

#define D 768
#define B 32
#define L 512
#define M 128
#define NNODES 3072
#define NEDGES 24576

using bf16x8 = __attribute__((ext_vector_type(8))) short;
using f32x4  = __attribute__((ext_vector_type(4))) float;

__device__ __forceinline__ float bf2f(unsigned short u) {
  union { unsigned int i; float f; } v; v.i = ((unsigned int)u) << 16; return v.f;
}
__device__ __forceinline__ unsigned short f2bf(float f) {
  union { float f; unsigned int i; } v; v.f = f;
  unsigned int x = v.i;
  return (unsigned short)((x + 0x7FFFu + ((x >> 16) & 1u)) >> 16);
}
__device__ __forceinline__ float ldf(const void* p, size_t i, int f32) {
  return f32 ? ((const float*)p)[i] : bf2f(((const unsigned short*)p)[i]);
}
__device__ __forceinline__ int ldi(const void* p, size_t i, int w64) {
  return w64 ? (int)((const long long*)p)[i] : ((const int*)p)[i];
}
__device__ __forceinline__ f32x4 mfma16(bf16x8 a, bf16x8 b, f32x4 c) {
  return __builtin_amdgcn_mfma_f32_16x16x32_bf16(a, b, c, 0, 0, 0);
}
__device__ __forceinline__ void gl_lds(const unsigned short* gsrc, unsigned short* lbase,
                                       int lane) {
  __builtin_amdgcn_global_load_lds(
      (const __attribute__((address_space(1))) unsigned int*)(gsrc + lane * 8),
      (__attribute__((address_space(3))) unsigned int*)lbase, 16, 0, 0);
}

// Packed fragment layout for row-major [R x 768] bf16:
//   (row,k) -> panel p=row/16, kk=k/32, lane=((k%32)/8)*16+row%16, e=k%8
__device__ __forceinline__ float pk_read(const unsigned short* P, int p, int l, int d) {
  return bf2f(P[(((size_t)(p * 24 + (d >> 5))) << 9) + ((((d & 31) >> 3) << 4) + l) * 8 + (d & 7)]);
}

// ================= device role bodies =================

__device__ void d_pack_in(const void* src, unsigned short* rows, unsigned short* dst,
                          int p, int tid, int f, char* smem) {
  unsigned short* buf = (unsigned short*)smem;   // 12288 ushorts
#pragma unroll
  for (int j = 0; j < 6; ++j) {
    int idx = j * 256 + tid;
    int r = idx / 96, c = idx % 96;
    size_t sbase = (size_t)(p * 16 + r) * 768 + c * 8;
    union { unsigned short v[8]; uint4 q; } u;
    if (f) {
      const float* sp = (const float*)src + sbase;
#pragma unroll
      for (int e = 0; e < 8; ++e) u.v[e] = f2bf(sp[e]);
    } else {
      const unsigned short* sp = (const unsigned short*)src + sbase;
#pragma unroll
      for (int e = 0; e < 8; ++e) u.v[e] = sp[e];
    }
    if (rows) *(uint4*)&rows[sbase] = u.q;
    int lpos = (c >> 2) * 64 + (c & 3) * 16 + r;
#pragma unroll
    for (int e = 0; e < 8; ++e) buf[lpos * 8 + e] = u.v[e];
  }
  __syncthreads();
  uint4* d4 = (uint4*)(dst + (size_t)p * 12288);
  const uint4* b4 = (const uint4*)buf;
#pragma unroll
  for (int j = 0; j < 6; ++j) d4[j * 256 + tid] = b4[j * 256 + tid];
}

__device__ void d_pack(const unsigned short* src, unsigned short* dst,
                       int p, int tid, char* smem) {
  unsigned short* buf = (unsigned short*)smem;
#pragma unroll
  for (int j = 0; j < 6; ++j) {
    int idx = j * 256 + tid;
    int r = idx / 96, c = idx % 96;
    size_t sbase = (size_t)(p * 16 + r) * 768 + c * 8;
    uint4 q = *(const uint4*)(src + sbase);
    int lpos = (c >> 2) * 64 + (c & 3) * 16 + r;
    *(uint4*)&buf[lpos * 8] = q;
  }
  __syncthreads();
  uint4* d4 = (uint4*)(dst + (size_t)p * 12288);
  const uint4* b4 = (const uint4*)buf;
#pragma unroll
  for (int j = 0; j < 6; ++j) d4[j * 256 + tid] = b4[j * 256 + tid];
}

__device__ void d_wpack(const void* Ws, const void* Wn, const void* Aw, int f,
                        unsigned short* WsPk, unsigned short* WnPk, unsigned short* AwPk,
                        int r0, int tid, char* smem) {
  unsigned short* buf = (unsigned short*)smem;   // 2048 ushorts
  int z = r0 / 288, rem = r0 % 288;
  int nblk = rem % 12, kk = rem / 12;
  const void* src; unsigned short* dst; size_t zoff;
  if (z < 3)      { src = Ws; zoff = (size_t)z * D * D;       dst = WsPk + zoff; }
  else if (z < 6) { src = Wn; zoff = (size_t)(z - 3) * D * D; dst = WnPk + zoff; }
  else            { src = Aw; zoff = 0;                       dst = AwPk; }
  int n0 = nblk * 64;
  int kl = tid >> 3, c8 = tid & 7;
  size_t sbase = zoff + (size_t)(kk * 32 + kl) * D + n0 + c8 * 8;
  unsigned short v[8];
  if (f) {
    const float* sp = (const float*)src + sbase;
#pragma unroll
    for (int e = 0; e < 8; ++e) v[e] = f2bf(sp[e]);
  } else {
    const unsigned short* sp = (const unsigned short*)src + sbase;
#pragma unroll
    for (int e = 0; e < 8; ++e) v[e] = sp[e];
  }
  int ebit = kl & 7, quad = kl >> 3;
#pragma unroll
  for (int i = 0; i < 8; ++i) {
    int nl = c8 * 8 + i;
    int pl = nl >> 4;
    int lane = quad * 16 + (nl & 15);
    buf[pl * 512 + lane * 8 + ebit] = v[i];
  }
  __syncthreads();
  int pl = tid >> 6, pos = tid & 63;
  int pG = nblk * 4 + pl;
  uint4 q = *(const uint4*)&buf[pl * 512 + pos * 8];
  *(uint4*)&dst[(((size_t)(pG * 24 + kk)) << 9) + pos * 8] = q;
}

__device__ void d_count(const void* edst, const void* batch, int w,
                        int* cnt, int* gcnt, int i) {
  if (i < NEDGES) atomicAdd(&cnt[ldi(edst, i, w)], 1);
  if (i < NNODES) atomicAdd(&gcnt[ldi(batch, i, w)], 1);
}

__device__ void d_msg(const unsigned short* x, const int* cnt, const int* rowstart,
                      const int* csr, unsigned short* Mpk, int p, int tid, char* smem) {
  unsigned short* buf = (unsigned short*)smem;   // 12288
  int w = tid >> 6, lane = tid & 63;
#pragma unroll
  for (int i = 0; i < 4; ++i) {
    int r = w * 4 + i;
    int n = p * 16 + r;
    int deg = cnt[n], base = rowstart[n];
    float inv = 1.0f / (float)(deg > 1 ? deg : 1);
    float a[12];
#pragma unroll
    for (int j = 0; j < 12; ++j) a[j] = 0.f;
    for (int e = 0; e < deg; ++e) {
      const uint2* xr = (const uint2*)(x + (size_t)csr[base + e] * D);
#pragma unroll
      for (int j = 0; j < 3; ++j) {
        uint2 v = xr[lane + j * 64];
        a[j * 4 + 0] += bf2f((unsigned short)(v.x & 0xFFFFu));
        a[j * 4 + 1] += bf2f((unsigned short)(v.x >> 16));
        a[j * 4 + 2] += bf2f((unsigned short)(v.y & 0xFFFFu));
        a[j * 4 + 3] += bf2f((unsigned short)(v.y >> 16));
      }
    }
#pragma unroll
    for (int j = 0; j < 3; ++j) {
      int d0 = (lane + j * 64) * 4;
      int c = d0 >> 3, e0 = d0 & 7;
      int lpos = (c >> 2) * 64 + (c & 3) * 16 + r;
      unsigned short* bp = &buf[lpos * 8 + e0];
      bp[0] = f2bf(a[j * 4 + 0] * inv);
      bp[1] = f2bf(a[j * 4 + 1] * inv);
      bp[2] = f2bf(a[j * 4 + 2] * inv);
      bp[3] = f2bf(a[j * 4 + 3] * inv);
    }
  }
  __syncthreads();
  uint4* d4 = (uint4*)(Mpk + (size_t)p * 12288);
  const uint4* b4 = (const uint4*)buf;
#pragma unroll
  for (int j = 0; j < 6; ++j) d4[j * 256 + tid] = b4[j * 256 + tid];
}

__device__ void d_gemm(const unsigned short* Xpk, const unsigned short* Mpk,
                       const unsigned short* WsPk, const unsigned short* WnPk,
                       const void* bias, size_t bias_off, int f,
                       unsigned short* Y, int bx, int by, int tid, char* smem) {
  unsigned short* lds = (unsigned short*)smem;   // 6*4096 ushorts = 48KB
  int wave = tid >> 6, lane = tid & 63;
  int q = lane >> 4, t = lane & 15;
  int wm = wave >> 1, wn = wave & 1;
  int pa = bx * 4, pb = by * 4;
  f32x4 acc[2][2];
#pragma unroll
  for (int mi = 0; mi < 2; ++mi)
#pragma unroll
    for (int ni = 0; ni < 2; ++ni)
      acc[mi][ni] = (f32x4){0.f, 0.f, 0.f, 0.f};
  int c0 = wave * 2;
  int pan0 = (wave < 2) ? (pa + c0) : (pb + c0 - 4);
  for (int r = 0; r < 8; ++r) {
    int h = r >> 2;
    int kk0 = r * 6 - h * 24;
    const unsigned short* P = (wave < 2) ? (h ? Mpk : Xpk) : (h ? WnPk : WsPk);
#pragma unroll
    for (int st = 0; st < 6; ++st) {
      gl_lds(P + (((size_t)(pan0 * 24 + kk0 + st)) << 9), &lds[st * 4096 + c0 * 512], lane);
      gl_lds(P + (((size_t)((pan0 + 1) * 24 + kk0 + st)) << 9), &lds[st * 4096 + (c0 + 1) * 512], lane);
    }
    __syncthreads();
#pragma unroll
    for (int st = 0; st < 6; ++st) {
      bf16x8 a0 = *(const bf16x8*)&lds[st * 4096 + (wm * 2 + 0) * 512 + lane * 8];
      bf16x8 a1 = *(const bf16x8*)&lds[st * 4096 + (wm * 2 + 1) * 512 + lane * 8];
      bf16x8 b0 = *(const bf16x8*)&lds[st * 4096 + (4 + wn * 2 + 0) * 512 + lane * 8];
      bf16x8 b1 = *(const bf16x8*)&lds[st * 4096 + (4 + wn * 2 + 1) * 512 + lane * 8];
      acc[0][0] = mfma16(a0, b0, acc[0][0]);
      acc[0][1] = mfma16(a0, b1, acc[0][1]);
      acc[1][0] = mfma16(a1, b0, acc[1][0]);
      acc[1][1] = mfma16(a1, b1, acc[1][1]);
    }
    __syncthreads();
  }
#pragma unroll
  for (int ni = 0; ni < 2; ++ni) {
    int col = by * 64 + wn * 32 + ni * 16 + t;
    float bv = ldf(bias, bias_off + col, f);
#pragma unroll
    for (int mi = 0; mi < 2; ++mi) {
#pragma unroll
      for (int r = 0; r < 4; ++r) {
        int row = bx * 64 + wm * 32 + mi * 16 + q * 4 + r;
        float v = acc[mi][ni][r] + bv;
        Y[(size_t)row * D + col] = f2bf(v > 0.f ? v : 0.f);
      }
    }
  }
}

__device__ void d_xp(const unsigned short* Xn, const void* pidx, int w64,
                     const int* gcnt, unsigned short* xp, unsigned short* XpPk,
                     float* xgacc, int p, int tid, char* smem) {
  unsigned short* rows = (unsigned short*)smem;   // 16*776
  int r = tid >> 4, c16 = tid & 15;
  int bm = p * 16 + r;
  int b = bm >> 7, m = bm & 127;
  int nb = gcnt[b];
  uint4* dl = (uint4*)&rows[r * 776];
  if (m < nb) {
    const uint4* srcr = (const uint4*)(Xn + (size_t)ldi(pidx, bm, w64) * D);
#pragma unroll
    for (int j = 0; j < 6; ++j) dl[c16 + j * 16] = srcr[c16 + j * 16];
  } else {
    uint4 z = {0u, 0u, 0u, 0u};
#pragma unroll
    for (int j = 0; j < 6; ++j) dl[c16 + j * 16] = z;
  }
  __syncthreads();
#pragma unroll
  for (int j = 0; j < 6; ++j) {
    int idx = j * 256 + tid;
    int rr = idx / 96, cc = idx % 96;
    uint4 vv = *(const uint4*)&rows[rr * 776 + cc * 8];
    *(uint4*)&xp[(size_t)(p * 16 + rr) * D + cc * 8] = vv;
  }
  unsigned short* pb = XpPk + (size_t)p * 12288;
#pragma unroll
  for (int j = 0; j < 6; ++j) {
    int odx = j * 256 + tid;
    int kk = odx >> 6, lanep = odx & 63;
    int rr = lanep & 15, cg = lanep >> 4;
    int cc = kk * 4 + cg;
    uint4 vv = *(const uint4*)&rows[rr * 776 + cc * 8];
    *(uint4*)&pb[odx * 8] = vv;
  }
  if (xgacc) {
    int bb = p >> 3;
#pragma unroll
    for (int j = 0; j < 3; ++j) {
      int d = j * 256 + tid;
      float s = 0.f;
#pragma unroll
      for (int rr = 0; rr < 16; ++rr) s += bf2f(rows[rr * 776 + d]);
      atomicAdd(&xgacc[(size_t)bb * D + d], s);
    }
  }
}

__device__ void d_scores(const unsigned short* XpPk, const unsigned short* Tpk,
                         float* S, int bx, int by, int bz, int tid, char* smem) {
  unsigned short* lds = (unsigned short*)smem;
  int wave = tid >> 6, lane = tid & 63;
  int q = lane >> 4, t = lane & 15;
  int wm = wave >> 1, wn = wave & 1;
  int pa = bz * 8 + bx * 4;
  int pb = bz * 32 + by * 4;
  f32x4 acc[2][2];
#pragma unroll
  for (int mi = 0; mi < 2; ++mi)
#pragma unroll
    for (int ni = 0; ni < 2; ++ni)
      acc[mi][ni] = (f32x4){0.f, 0.f, 0.f, 0.f};
  int c0 = wave * 2;
  const unsigned short* P = (wave < 2) ? XpPk : Tpk;
  int pan0 = (wave < 2) ? (pa + c0) : (pb + c0 - 4);
  for (int r = 0; r < 4; ++r) {
    int kk0 = r * 6;
#pragma unroll
    for (int st = 0; st < 6; ++st) {
      gl_lds(P + (((size_t)(pan0 * 24 + kk0 + st)) << 9), &lds[st * 4096 + c0 * 512], lane);
      gl_lds(P + (((size_t)((pan0 + 1) * 24 + kk0 + st)) << 9), &lds[st * 4096 + (c0 + 1) * 512], lane);
    }
    __syncthreads();
#pragma unroll
    for (int st = 0; st < 6; ++st) {
      bf16x8 a0 = *(const bf16x8*)&lds[st * 4096 + (wm * 2 + 0) * 512 + lane * 8];
      bf16x8 a1 = *(const bf16x8*)&lds[st * 4096 + (wm * 2 + 1) * 512 + lane * 8];
      bf16x8 b0 = *(const bf16x8*)&lds[st * 4096 + (4 + wn * 2 + 0) * 512 + lane * 8];
      bf16x8 b1 = *(const bf16x8*)&lds[st * 4096 + (4 + wn * 2 + 1) * 512 + lane * 8];
      acc[0][0] = mfma16(a0, b0, acc[0][0]);
      acc[0][1] = mfma16(a0, b1, acc[0][1]);
      acc[1][0] = mfma16(a1, b0, acc[1][0]);
      acc[1][1] = mfma16(a1, b1, acc[1][1]);
    }
    __syncthreads();
  }
  float* Sb = S + (size_t)bz * M * L;
#pragma unroll
  for (int ni = 0; ni < 2; ++ni) {
    int col = by * 64 + wn * 32 + ni * 16 + t;
#pragma unroll
    for (int mi = 0; mi < 2; ++mi) {
#pragma unroll
      for (int r = 0; r < 4; ++r) {
        int row = bx * 64 + wm * 32 + mi * 16 + q * 4 + r;
        Sb[(size_t)row * L + col] = acc[mi][ni][r];
      }
    }
  }
}

__device__ void d_stats(const float* S, const int* gcnt, float* rmax, float* rsum,
                        float* cmaxv, float* csumv, int bid, int tid, char* smem) {
  if (bid < B * M) {
    float* red = (float*)smem;
    int lane = tid & 63, wv = tid >> 6;
    const float* r = S + (size_t)bid * L;
    float s0 = r[tid], s1 = r[tid + 256];
    float m = fmaxf(s0, s1);
#pragma unroll
    for (int o = 32; o > 0; o >>= 1) m = fmaxf(m, __shfl_down(m, o));
    if (lane == 0) red[wv] = m;
    __syncthreads();
    float bm = fmaxf(fmaxf(red[0], red[1]), fmaxf(red[2], red[3]));
    __syncthreads();
    float e = __expf(s0 - bm) + __expf(s1 - bm);
#pragma unroll
    for (int o = 32; o > 0; o >>= 1) e += __shfl_down(e, o);
    if (lane == 0) red[wv] = e;
    __syncthreads();
    if (tid == 0) { rmax[bid] = bm; rsum[bid] = red[0] + red[1] + red[2] + red[3]; }
  } else {
    float (*pm)[64] = (float(*)[64])smem;
    float (*ps)[64] = (float(*)[64])(smem + 1024);
    int cid = bid - B * M;
    int b = cid >> 3, ly = cid & 7;
    int w = tid >> 6, lane = tid & 63;
    int l = ly * 64 + lane;
    int nb = gcnt[b];
    const float* Sb = S + (size_t)b * M * L;
    int m0 = w * 32, m1 = min(m0 + 32, nb);
    float cm = -1e30f, cs = 0.f;
    for (int m = m0; m < m1; ++m) {
      float s = Sb[(size_t)m * L + l];
      if (s > cm) { cs = cs * __expf(cm - s) + 1.f; cm = s; }
      else cs += __expf(s - cm);
    }
    pm[w][lane] = cm; ps[w][lane] = cs;
    __syncthreads();
    if (w == 0) {
      float CM = -1e30f;
#pragma unroll
      for (int j = 0; j < 4; ++j) CM = fmaxf(CM, pm[j][lane]);
      float CS = 0.f;
#pragma unroll
      for (int j = 0; j < 4; ++j) CS += ps[j][lane] * __expf(pm[j][lane] - CM);
      cmaxv[b * L + l] = CM; csumv[b * L + l] = CS;
    }
  }
}

__device__ void d_cross(const float* S, const float* rmax, const float* rsum,
                        const float* cmaxv, const float* csumv, const int* gcnt,
                        float* wv, float* t2gcol, int bid, int tid, char* smem) {
  if (bid < 256) {
    float* rm = (float*)smem;               // 128
    float* ri = (float*)(smem + 512);       // 128
    float (*pw)[64] = (float(*)[64])(smem + 1024);
    int b = bid >> 3, ly = bid & 7;
    int w = tid >> 6, lane = tid & 63;
    if (tid < M) { rm[tid] = rmax[b * M + tid]; ri[tid] = 1.f / rsum[b * M + tid]; }
    __syncthreads();
    int l = ly * 64 + lane;
    int nb = gcnt[b];
    const float* Sb = S + (size_t)b * M * L;
    int m0 = w * 32, m1 = min(m0 + 32, nb);
    float wp = 0.f;
    for (int m = m0; m < m1; ++m)
      wp += __expf(Sb[(size_t)m * L + l] - rm[m]) * ri[m];
    pw[w][lane] = wp;
    __syncthreads();
    if (w == 0)
      wv[b * L + l] = pw[0][lane] + pw[1][lane] + pw[2][lane] + pw[3][lane];
  } else {
    float* red = (float*)smem;
    int bm = bid - 256;
    int b = bm >> 7, m = bm & 127;
    int lane = tid & 63, w = tid >> 6;
    int nb = gcnt[b];
    float acc = 0.f;
    if (m < nb) {
      const float* r = S + (size_t)bm * L;
      const float* cm = cmaxv + b * L;
      const float* cs = csumv + b * L;
      acc = __expf(r[tid] - cm[tid]) / cs[tid]
          + __expf(r[tid + 256] - cm[tid + 256]) / cs[tid + 256];
    }
#pragma unroll
    for (int o = 32; o > 0; o >>= 1) acc += __shfl_down(acc, o);
    if (lane == 0) red[w] = acc;
    __syncthreads();
    if (tid == 0) t2gcol[bm] = red[0] + red[1] + red[2] + red[3];
  }
}

__device__ void d_pooled(const float* wv, const float* t2gcol, const unsigned short* Tpk,
                         const unsigned short* xp, const int* gcnt, float* pooled,
                         int bid, int tid) {
  int b = bid & 31;
  int rest = bid >> 5;          // 0..29
  int y = rest % 3, c = rest / 3;
  int d = y * 256 + tid;
  float acc = 0.f;
  if (c < 8) {
    int l0 = c * 64;
    for (int l = l0; l < l0 + 64; ++l) {
      int p = b * 32 + (l >> 4);
      acc += wv[b * L + l] * pk_read(Tpk, p, l & 15, d);
    }
  } else {
    const unsigned short* Xb = xp + (size_t)b * M * D;
    int mm0 = (c - 8) * 64;
    for (int m = mm0; m < mm0 + 64; ++m) acc += t2gcol[b * M + m] * bf2f(Xb[(size_t)m * D + d]);
  }
  atomicAdd(&pooled[(size_t)b * D + d], acc / ((float)gcnt[b] + 512.f));
}

__device__ void d_atom(const float* xgacc, const int* gcnt, const unsigned short* AwPk,
                       float* gpre, int bid, int tid) {
  int w = tid >> 6, lane = tid & 63;
  int q = lane >> 4, t = lane & 15;
  int nbase = bid * 64 + w * 16;
  int pb = nbase >> 4;
  int n0 = gcnt[t], n1 = gcnt[16 + t];
  float inv0 = 1.f / (float)(n0 > 1 ? n0 : 1);
  float inv1 = 1.f / (float)(n1 > 1 ? n1 : 1);
  f32x4 acc[2];
  acc[0] = (f32x4){0.f, 0.f, 0.f, 0.f};
  acc[1] = (f32x4){0.f, 0.f, 0.f, 0.f};
  for (int kk = 0; kk < 24; ++kk) {
    const float* s0 = xgacc + (size_t)t * D + kk * 32 + q * 8;
    const float* s1 = xgacc + (size_t)(16 + t) * D + kk * 32 + q * 8;
    union { unsigned short v[8]; bf16x8 f; } a0, a1;
#pragma unroll
    for (int j = 0; j < 8; ++j) { a0.v[j] = f2bf(s0[j] * inv0); a1.v[j] = f2bf(s1[j] * inv1); }
    bf16x8 bv = *(const bf16x8*)(AwPk + (((size_t)(pb * 24 + kk)) << 9) + (lane << 3));
    acc[0] = mfma16(a0.f, bv, acc[0]);
    acc[1] = mfma16(a1.f, bv, acc[1]);
  }
#pragma unroll
  for (int mi = 0; mi < 2; ++mi)
#pragma unroll
    for (int r = 0; r < 4; ++r) {
      int row = mi * 16 + q * 4 + r;
      gpre[(size_t)row * D + nbase + t] = acc[mi][r];
    }
}

// ================= global kernels =================

__global__ void k_init(int* cnt, int* cursor, int* gcnt, float* pooled, float* xgacc,
                       const unsigned short* __restrict__ t,
                       const unsigned int* __restrict__ e, int* __restrict__ flags) {
  int i = blockIdx.x * 256 + threadIdx.x;
  if (i < NNODES) { cnt[i] = 0; cursor[i] = 0; }
  if (i < B) gcnt[i] = 0;
  if (i < B * D) { pooled[i] = 0.f; xgacc[i] = 0.f; }
  if (blockIdx.x == 0) {
    __shared__ int r0[256];
    __shared__ unsigned r1[256];
    int tid = threadIdx.x;
    int bad = 0;
    for (int j = tid; j < 8192; j += 256) {
      unsigned short u = t[2 * j];
      unsigned ex = (u >> 7) & 0xFF;
      if (ex >= 0xC0) bad = 1;
    }
    unsigned o = 0;
    for (int j = tid; j < NEDGES / 2; j += 256) o |= e[2 * j + 1];
    r0[tid] = bad; r1[tid] = o;
    __syncthreads();
    for (int s = 128; s > 0; s >>= 1) {
      if (tid < s) { r0[tid] |= r0[tid + s]; r1[tid] |= r1[tid + s]; }
      __syncthreads();
    }
    if (tid == 0) { flags[0] = r0[0]; flags[1] = (r1[0] == 0) ? 1 : 0; }
  }
}

// pack_in (0..1215) + wpack (1216..3231) + count (3232..3327)
__global__ __launch_bounds__(256) void k_setup2(
    const void* x_in, unsigned short* x0, unsigned short* PkA,
    const void* text, unsigned short* Tpk,
    const void* Ws, const void* Wn, const void* Aw,
    unsigned short* WsPk, unsigned short* WnPk, unsigned short* AwPk,
    const void* edst, const void* batch, int* cnt, int* gcnt,
    const int* __restrict__ flags) {
  extern __shared__ char smem[];
  int bid = blockIdx.x, tid = threadIdx.x;
  if (bid < 1216) {
    int f = flags[0];
    if (bid < NNODES / 16) d_pack_in(x_in, x0, PkA, bid, tid, f, smem);
    else d_pack_in(text, nullptr, Tpk, bid - NNODES / 16, tid, f, smem);
  } else if (bid < 3232) {
    d_wpack(Ws, Wn, Aw, flags[0], WsPk, WnPk, AwPk, bid - 1216, tid, smem);
  } else {
    d_count(edst, batch, flags[1], cnt, gcnt, (bid - 3232) * 256 + tid);
  }
}

__global__ void k_scan(const int* __restrict__ cnt, int* __restrict__ rowstart) {
  __shared__ int a[NNODES], b[NNODES];
  int tid = threadIdx.x;
  for (int i = tid; i < NNODES; i += 1024) a[i] = cnt[i];
  __syncthreads();
  int* s = a; int* d = b;
  for (int off = 1; off < NNODES; off <<= 1) {
    for (int i = tid; i < NNODES; i += 1024)
      d[i] = s[i] + (i >= off ? s[i - off] : 0);
    __syncthreads();
    int* t = s; s = d; d = t;
  }
  for (int i = tid; i < NNODES; i += 1024) rowstart[i + 1] = s[i];
  if (tid == 0) rowstart[0] = 0;
}

__global__ void k_scatter(const void* __restrict__ esrc, const void* __restrict__ edst,
                          const int* __restrict__ flags, const int* __restrict__ rowstart,
                          int* __restrict__ cursor, int* __restrict__ csr) {
  int w = flags[1];
  int i = blockIdx.x * 256 + threadIdx.x;
  if (i < NEDGES) {
    int dd = ldi(edst, i, w);
    int pos = atomicAdd(&cursor[dd], 1);
    csr[rowstart[dd] + pos] = ldi(esrc, i, w);
  }
}

__global__ __launch_bounds__(256) void k_msgp(
    const unsigned short* x, const int* cnt, const int* rowstart, const int* csr,
    unsigned short* Mpk) {
  extern __shared__ char smem[];
  d_msg(x, cnt, rowstart, csr, Mpk, blockIdx.x, threadIdx.x, smem);
}

__global__ __launch_bounds__(256) void k_gemm(
    const unsigned short* Apk, const unsigned short* Mpk,
    const unsigned short* WsPk, const unsigned short* WnPk,
    const void* bias, unsigned long bias_off, const int* flags, unsigned short* Y) {
  extern __shared__ char smem[];
  int g = blockIdx.x;
  d_gemm(Apk, Mpk, WsPk, WnPk, bias, bias_off, flags[0], Y, g % 48, g / 48,
         threadIdx.x, smem);
}

// pack (0..packN-1) + xp_pack (packN..packN+255)
__global__ __launch_bounds__(256) void k_postg(
    const unsigned short* Y, unsigned short* Npk, int packN,
    const void* pidx, const int* flags, const int* gcnt,
    unsigned short* xp, unsigned short* XpPk, float* xgacc) {
  extern __shared__ char smem[];
  int bid = blockIdx.x, tid = threadIdx.x;
  if (bid < packN) d_pack(Y, Npk, bid, tid, smem);
  else d_xp(Y, pidx, flags[1], gcnt, xp, XpPk, xgacc, bid - packN, tid, smem);
}

// scores (0..511) + msg(next) (512..512+msgN-1)
__global__ __launch_bounds__(256) void k_scmsg(
    const unsigned short* XpPk, const unsigned short* Tpk, float* S,
    int msgN, const unsigned short* x, const int* cnt, const int* rowstart,
    const int* csr, unsigned short* Mpk) {
  extern __shared__ char smem[];
  int bid = blockIdx.x, tid = threadIdx.x;
  if (bid < 512) d_scores(XpPk, Tpk, S, bid & 1, (bid >> 1) & 7, bid >> 4, tid, smem);
  else d_msg(x, cnt, rowstart, csr, Mpk, bid - 512, tid, smem);
}

// stats (0..4351) + gemm(next) (4352..4352+gemmN-1)
__global__ __launch_bounds__(256) void k_stgemm(
    const float* S, const int* gcnt, float* rmax, float* rsum, float* cmaxv, float* csumv,
    int gemmN, const unsigned short* Apk, const unsigned short* Mpk,
    const unsigned short* WsPk, const unsigned short* WnPk,
    const void* bias, unsigned long bias_off, const int* flags, unsigned short* Y) {
  extern __shared__ char smem[];
  int bid = blockIdx.x, tid = threadIdx.x;
  if (bid < 4352) d_stats(S, gcnt, rmax, rsum, cmaxv, csumv, bid, tid, smem);
  else {
    int g = bid - 4352;
    d_gemm(Apk, Mpk, WsPk, WnPk, bias, bias_off, flags[0], Y, g % 48, g / 48, tid, smem);
  }
}

// cross (0..4351) + pack(next) + xp_pack(next)
__global__ __launch_bounds__(256) void k_crpostg(
    const float* S, const float* rmax, const float* rsum, const float* cmaxv,
    const float* csumv, const int* gcnt, float* wv, float* t2gcol,
    int packN, int xpN, const unsigned short* Y, unsigned short* Npk,
    const void* pidx, const int* flags, unsigned short* xp, unsigned short* XpPk,
    float* xgacc) {
  extern __shared__ char smem[];
  int bid = blockIdx.x, tid = threadIdx.x;
  if (bid < 4352) d_cross(S, rmax, rsum, cmaxv, csumv, gcnt, wv, t2gcol, bid, tid, smem);
  else {
    int r = bid - 4352;
    if (r < packN) d_pack(Y, Npk, r, tid, smem);
    else d_xp(Y, pidx, flags[1], gcnt, xp, XpPk, xgacc, r - packN, tid, smem);
  }
}

// pooled (0..959) + scores(next) (960..960+scN-1) + msg (then msgN) + atom (then atomN)
__global__ __launch_bounds__(256) void k_plscmsg(
    const float* wv, const float* t2gcol, const unsigned short* Tpk,
    const unsigned short* xpL, const int* gcnt, float* pooled,
    int scN, const unsigned short* XpPk, float* S,
    int msgN, const unsigned short* x, const int* cnt, const int* rowstart,
    const int* csr, unsigned short* Mpk,
    int atomN, const float* xgacc, const unsigned short* AwPk, float* gpre) {
  extern __shared__ char smem[];
  int bid = blockIdx.x, tid = threadIdx.x;
  if (bid < 960) { d_pooled(wv, t2gcol, Tpk, xpL, gcnt, pooled, bid, tid); return; }
  int r = bid - 960;
  if (r < scN) { d_scores(XpPk, Tpk, S, r & 1, (r >> 1) & 7, r >> 4, tid, smem); return; }
  r -= scN;
  if (r < msgN) { d_msg(x, cnt, rowstart, csr, Mpk, r, tid, smem); return; }
  d_atom(xgacc, gcnt, AwPk, gpre, r - msgN, tid);
}

__global__ __launch_bounds__(256) void k_final(
    const unsigned short* __restrict__ Tpk, const float* __restrict__ gpre,
    const float* __restrict__ pooled, const void* __restrict__ ab,
    const void* __restrict__ dmask, const void* __restrict__ gmask,
    const void* __restrict__ remb, const int* __restrict__ flags,
    void* __restrict__ out) {
  int f = flags[0];
  int b = blockIdx.x, tid = threadIdx.x;
  float dm = ldf(dmask, b, f);
  float gm = ldf(gmask, b, f);
  float dg = dm * gm;
  size_t base = (size_t)b * 2304;
#pragma unroll
  for (int j = 0; j < 3; ++j) {
    int d = tid + j * 256;
    float z = ldf(remb, d, f);
    float tv = pk_read(Tpk, b * 32, 0, d);
    float o0 = tv * dm + (1.f - dm) * z;
    float gv = tanhf(gpre[(size_t)b * D + d] + ldf(ab, d, f));
    float o1 = gv * gm + (1.f - gm) * z;
    float p = pooled[(size_t)b * D + d] * (1.f / 3.f);
    float o2 = p * dg + (1.f - dg) * z;
    if (f) {
      float* of = (float*)out;
      of[base + d] = o0; of[base + 768 + d] = o1; of[base + 1536 + d] = o2;
    } else {
      unsigned short* ob = (unsigned short*)out;
      ob[base + d] = f2bf(o0); ob[base + 768 + d] = f2bf(o1); ob[base + 1536 + d] = f2bf(o2);
    }
  }
}

extern "C" void kernel_launch(void* const* d_in, const int* in_sizes, int n_in,
                              void* d_out, int out_size, void* d_ws, size_t ws_size,
                              hipStream_t stream) {
  const void* x_in  = d_in[0];
  const void* text  = d_in[1];
  const void* dmask = d_in[2];
  const void* gmask = d_in[3];
  const void* gws   = d_in[4];
  const void* gwn   = d_in[5];
  const void* gb    = d_in[6];
  const void* aw    = d_in[7];
  const void* ab    = d_in[8];
  const void* remb  = d_in[9];
  const void* batch = d_in[10];
  const void* pidx  = d_in[11];
  const void* esrc  = d_in[13];
  const void* edst  = d_in[14];

  char* wsp = (char*)d_ws;
  size_t off = 0;
  auto carve = [&](size_t bytes) -> void* {
    void* p = wsp + off;
    off += (bytes + 255) & ~(size_t)255;
    return p;
  };
  int* flags = (int*)carve(2 * 4);
  unsigned short* x0    = (unsigned short*)carve((size_t)NNODES * D * 2);
  unsigned short* xA    = (unsigned short*)carve((size_t)NNODES * D * 2);
  unsigned short* xB    = (unsigned short*)carve((size_t)NNODES * D * 2);
  unsigned short* PkA   = (unsigned short*)carve((size_t)NNODES * D * 2);
  unsigned short* PkB   = (unsigned short*)carve((size_t)NNODES * D * 2);
  unsigned short* Mpk   = (unsigned short*)carve((size_t)NNODES * D * 2);
  unsigned short* Tpk   = (unsigned short*)carve((size_t)B * L * D * 2);
  unsigned short* WsPk  = (unsigned short*)carve((size_t)3 * D * D * 2);
  unsigned short* WnPk  = (unsigned short*)carve((size_t)3 * D * D * 2);
  unsigned short* AwPk  = (unsigned short*)carve((size_t)D * D * 2);
  unsigned short* xpA   = (unsigned short*)carve((size_t)B * M * D * 2);
  unsigned short* xpB   = (unsigned short*)carve((size_t)B * M * D * 2);
  unsigned short* XpPkA = (unsigned short*)carve((size_t)B * M * D * 2);
  unsigned short* XpPkB = (unsigned short*)carve((size_t)B * M * D * 2);
  float* xgacc   = (float*)carve((size_t)B * D * 4);
  float* gpre    = (float*)carve((size_t)B * D * 4);
  float* S       = (float*)carve((size_t)B * M * L * 4);
  float* rmax    = (float*)carve((size_t)B * M * 4);
  float* rsum    = (float*)carve((size_t)B * M * 4);
  float* wv      = (float*)carve((size_t)B * L * 4);
  float* cmaxv   = (float*)carve((size_t)B * L * 4);
  float* csumv   = (float*)carve((size_t)B * L * 4);
  float* t2gcol  = (float*)carve((size_t)B * M * 4);
  float* pooled  = (float*)carve((size_t)B * D * 4);
  int* cnt      = (int*)carve((size_t)NNODES * 4);
  int* rowstart = (int*)carve((size_t)(NNODES + 1) * 4);
  int* cursor   = (int*)carve((size_t)NNODES * 4);
  int* gcnt     = (int*)carve((size_t)B * 4);
  int* csr      = (int*)carve((size_t)NEDGES * 4);

  const size_t DD = (size_t)D * D;

  k_init<<<96, 256, 0, stream>>>(cnt, cursor, gcnt, pooled, xgacc,
                                 (const unsigned short*)text, (const unsigned int*)edst, flags);
  k_setup2<<<3328, 256, 24576, stream>>>(x_in, x0, PkA, text, Tpk, gws, gwn, aw,
                                         WsPk, WnPk, AwPk, edst, batch, cnt, gcnt, flags);
  k_scan<<<1, 1024, 0, stream>>>(cnt, rowstart);
  k_scatter<<<96, 256, 0, stream>>>(esrc, edst, flags, rowstart, cursor, csr);

  // ---- pipelined layer schedule ----
  k_msgp<<<192, 256, 24576, stream>>>(x0, cnt, rowstart, csr, Mpk);
  k_gemm<<<576, 256, 49152, stream>>>(PkA, Mpk, WsPk, WnPk, gb, 0, flags, xA);
  k_postg<<<448, 256, 24832, stream>>>(xA, PkB, 192, pidx, flags, gcnt, xpA, XpPkA, nullptr);
  k_scmsg<<<704, 256, 49152, stream>>>(XpPkA, Tpk, S, 192, xA, cnt, rowstart, csr, Mpk);
  k_stgemm<<<4928, 256, 49152, stream>>>(S, gcnt, rmax, rsum, cmaxv, csumv,
                                         576, PkB, Mpk, WsPk + DD, WnPk + DD, gb, D, flags, xB);
  k_crpostg<<<4800, 256, 24832, stream>>>(S, rmax, rsum, cmaxv, csumv, gcnt, wv, t2gcol,
                                          192, 256, xB, PkA, pidx, flags, xpB, XpPkB, nullptr);
  k_plscmsg<<<1664, 256, 49152, stream>>>(wv, t2gcol, Tpk, xpA, gcnt, pooled,
                                          512, XpPkB, S, 192, xB, cnt, rowstart, csr, Mpk,
                                          0, nullptr, nullptr, nullptr);
  k_stgemm<<<4928, 256, 49152, stream>>>(S, gcnt, rmax, rsum, cmaxv, csumv,
                                         576, PkA, Mpk, WsPk + 2 * DD, WnPk + 2 * DD,
                                         gb, 2 * D, flags, xA);
  k_crpostg<<<4608, 256, 24832, stream>>>(S, rmax, rsum, cmaxv, csumv, gcnt, wv, t2gcol,
                                          0, 256, xA, nullptr, pidx, flags, xpA, XpPkA, xgacc);
  k_plscmsg<<<1472, 256, 49152, stream>>>(wv, t2gcol, Tpk, xpB, gcnt, pooled,
                                          512, XpPkA, S, 0, nullptr, nullptr, nullptr,
                                          nullptr, nullptr, 0, nullptr, nullptr, nullptr);
  k_stgemm<<<4352, 256, 2048, stream>>>(S, gcnt, rmax, rsum, cmaxv, csumv,
                                        0, nullptr, nullptr, nullptr, nullptr,
                                        nullptr, 0, flags, nullptr);
  k_crpostg<<<4352, 256, 2048, stream>>>(S, rmax, rsum, cmaxv, csumv, gcnt, wv, t2gcol,
                                         0, 0, nullptr, nullptr, pidx, flags,
                                         nullptr, nullptr, nullptr);
  k_plscmsg<<<972, 256, 2048, stream>>>(wv, t2gcol, Tpk, xpA, gcnt, pooled,
                                        0, nullptr, nullptr, 0, nullptr, nullptr, nullptr,
                                        nullptr, nullptr, 12, xgacc, AwPk, gpre);
  k_final<<<32, 256, 0, stream>>>(Tpk, gpre, pooled, ab, dmask, gmask, remb, flags, d_out);
}